// Round 1
// baseline (2217.119 us; speedup 1.0000x reference)
//
#include <hip/hip_runtime.h>
#include <math.h>

#define NB 8
#define HWN 1024
#define KVC 960

// ---------------------------------------------------------------------------
// Tiled f32 GEMM: C[b][m][n] = alpha * sum_k A[b][m][k] * B[b][k][n]   (NN)
// TRANS_B=1:      C[b][m][n] = alpha * sum_k A[b][m][k] * B[b][n][k]   (NT)
// M, N multiples of 64; K multiple of 16. grid = (N/64, M/64, batch).
// ---------------------------------------------------------------------------
template<int TRANS_B>
__global__ __launch_bounds__(256)
void gemm_kernel(const float* __restrict__ A, const float* __restrict__ Bm,
                 float* __restrict__ C, int M, int N, int K,
                 long sA, long sB, long sC, float alpha)
{
    __shared__ float sAt[16][68];   // [k][m], padded
    __shared__ float sBt[16][64];   // [k][n]
    const float* Ab = A + (long)blockIdx.z * sA;
    const float* Bb = Bm + (long)blockIdx.z * sB;
    float* Cb = C + (long)blockIdx.z * sC;
    const int row0 = blockIdx.y * 64, col0 = blockIdx.x * 64;
    const int t = threadIdx.x;
    const int tx = t & 15, ty = t >> 4;
    const int mA = t >> 2, kqA = (t & 3) * 4;
    float acc[4][4] = {};

    for (int k0 = 0; k0 < K; k0 += 16) {
        float4 va = *(const float4*)(Ab + (long)(row0 + mA) * K + k0 + kqA);
        sAt[kqA + 0][mA] = va.x; sAt[kqA + 1][mA] = va.y;
        sAt[kqA + 2][mA] = va.z; sAt[kqA + 3][mA] = va.w;
        if (TRANS_B) {
            float4 vb = *(const float4*)(Bb + (long)(col0 + mA) * K + k0 + kqA);
            sBt[kqA + 0][mA] = vb.x; sBt[kqA + 1][mA] = vb.y;
            sBt[kqA + 2][mA] = vb.z; sBt[kqA + 3][mA] = vb.w;
        } else {
            const int kk = t >> 4, nq = (t & 15) * 4;
            float4 vb = *(const float4*)(Bb + (long)(k0 + kk) * N + col0 + nq);
            *(float4*)&sBt[kk][nq] = vb;
        }
        __syncthreads();
        #pragma unroll
        for (int k = 0; k < 16; ++k) {
            float a[4], b[4];
            #pragma unroll
            for (int i = 0; i < 4; ++i) a[i] = sAt[k][ty * 4 + i];
            #pragma unroll
            for (int j = 0; j < 4; ++j) b[j] = sBt[k][tx * 4 + j];
            #pragma unroll
            for (int i = 0; i < 4; ++i)
                #pragma unroll
                for (int j = 0; j < 4; ++j)
                    acc[i][j] += a[i] * b[j];
        }
        __syncthreads();
    }
    #pragma unroll
    for (int i = 0; i < 4; ++i) {
        float4 v = make_float4(acc[i][0] * alpha, acc[i][1] * alpha,
                               acc[i][2] * alpha, acc[i][3] * alpha);
        *(float4*)(Cb + (long)(row0 + ty * 4 + i) * N + col0 + tx * 4) = v;
    }
}

// ---------------------------------------------------------------------------
// Depthwise 3x3 SAME conv (groups == C), w: [C][1][3][3]
// ---------------------------------------------------------------------------
__global__ __launch_bounds__(256)
void dwconv_kernel(const float* __restrict__ in, const float* __restrict__ w,
                   float* __restrict__ out, int C)
{
    long idx = (long)blockIdx.x * 256 + threadIdx.x;
    int n = (int)(idx & 1023);
    int x = n & 31, y = n >> 5;
    long bc = idx >> 10;
    int c = (int)(bc % C);
    const float* ip = in + (bc << 10);
    const float* wp = w + c * 9;
    float acc = 0.f;
    #pragma unroll
    for (int dy = 0; dy < 3; ++dy) {
        int yy = y + dy - 1;
        if ((unsigned)yy >= 32u) continue;
        #pragma unroll
        for (int dx = 0; dx < 3; ++dx) {
            int xx = x + dx - 1;
            if ((unsigned)xx >= 32u) continue;
            acc += ip[yy * 32 + xx] * wp[dy * 3 + dx];
        }
    }
    out[idx] = acc;
}

// ---------------------------------------------------------------------------
// Grouped 3x3 SAME conv, groups = C/2 (2 in / 2 out per group), w: [C][2][3][3]
// ---------------------------------------------------------------------------
__global__ __launch_bounds__(256)
void gconv_kernel(const float* __restrict__ in, const float* __restrict__ w,
                  float* __restrict__ out, int C)
{
    long idx = (long)blockIdx.x * 256 + threadIdx.x;
    int n = (int)(idx & 1023);
    int x = n & 31, y = n >> 5;
    long bo = idx >> 10;
    int o = (int)(bo % C);
    int b = (int)(bo / C);
    int g2 = o & ~1;
    const float* wp = w + o * 18;
    float acc = 0.f;
    #pragma unroll
    for (int j = 0; j < 2; ++j) {
        const float* ip = in + (((long)b * C + g2 + j) << 10);
        const float* wj = wp + j * 9;
        #pragma unroll
        for (int dy = 0; dy < 3; ++dy) {
            int yy = y + dy - 1;
            if ((unsigned)yy >= 32u) continue;
            #pragma unroll
            for (int dx = 0; dx < 3; ++dx) {
                int xx = x + dx - 1;
                if ((unsigned)xx >= 32u) continue;
                acc += ip[yy * 32 + xx] * wj[dy * 3 + dx];
            }
        }
    }
    out[idx] = acc;
}

// ---------------------------------------------------------------------------
// In-place row L2-normalize, row length 1024. One block per row.
// ---------------------------------------------------------------------------
__global__ __launch_bounds__(256)
void l2norm_kernel(float* __restrict__ x)
{
    long base = (long)blockIdx.x * 1024 + threadIdx.x * 4;
    float4 v = *(float4*)(x + base);
    float s = v.x * v.x + v.y * v.y + v.z * v.z + v.w * v.w;
    #pragma unroll
    for (int off = 32; off > 0; off >>= 1) s += __shfl_down(s, off);
    __shared__ float red[5];
    if ((threadIdx.x & 63) == 0) red[threadIdx.x >> 6] = s;
    __syncthreads();
    if (threadIdx.x == 0)
        red[4] = 1.0f / fmaxf(sqrtf(red[0] + red[1] + red[2] + red[3]), 1e-12f);
    __syncthreads();
    float inv = red[4];
    v.x *= inv; v.y *= inv; v.z *= inv; v.w *= inv;
    *(float4*)(x + base) = v;
}

// ---------------------------------------------------------------------------
// Instance-norm stats (sum, sumsq) over L elements per batch. Deterministic
// two-stage: partials per (block,batch) then reduce. grid=(64, NB), 256 thr.
// ---------------------------------------------------------------------------
__global__ __launch_bounds__(256)
void stats_partial_kernel(const float* __restrict__ x, float2* __restrict__ part, long L)
{
    const float* xb = x + (long)blockIdx.y * L;
    float s1 = 0.f, s2 = 0.f;
    for (long i = (long)blockIdx.x * 256 + threadIdx.x; i < L; i += 64L * 256) {
        float v = xb[i];
        s1 += v; s2 += v * v;
    }
    #pragma unroll
    for (int off = 32; off > 0; off >>= 1) {
        s1 += __shfl_down(s1, off);
        s2 += __shfl_down(s2, off);
    }
    __shared__ float r1[4], r2[4];
    int w = threadIdx.x >> 6;
    if ((threadIdx.x & 63) == 0) { r1[w] = s1; r2[w] = s2; }
    __syncthreads();
    if (threadIdx.x == 0)
        part[blockIdx.y * 64 + blockIdx.x] =
            make_float2(r1[0] + r1[1] + r1[2] + r1[3], r2[0] + r2[1] + r2[2] + r2[3]);
}

__global__ void stats_reduce_kernel(const float2* __restrict__ part, float2* __restrict__ stats)
{
    float2 p = part[blockIdx.x * 64 + threadIdx.x];
    float s1 = p.x, s2 = p.y;
    #pragma unroll
    for (int off = 32; off > 0; off >>= 1) {
        s1 += __shfl_down(s1, off);
        s2 += __shfl_down(s2, off);
    }
    if (threadIdx.x == 0) stats[blockIdx.x] = make_float2(s1, s2);
}

// ---------------------------------------------------------------------------
// Fused instance-norm + row softmax (row length 960), in place.
// One block per row; rows grouped rowsPerB per batch.
// ---------------------------------------------------------------------------
__global__ __launch_bounds__(256)
void instnorm_softmax_kernel(float* __restrict__ x, const float2* __restrict__ stats,
                             int rowsPerB, float invL)
{
    int row = blockIdx.x;
    int b = row / rowsPerB;
    float2 st = stats[b];
    float mean = st.x * invL;
    float var = st.y * invL - mean * mean;
    float rinv = rsqrtf(var + 1e-5f);
    float* xr = x + (long)row * 960;
    int t = threadIdx.x;
    float v[4];
    float mx = -1e30f;
    #pragma unroll
    for (int q = 0; q < 4; ++q) {
        int i = t + q * 256;
        if (i < 960) { v[q] = (xr[i] - mean) * rinv; mx = fmaxf(mx, v[q]); }
        else v[q] = -1e30f;
    }
    #pragma unroll
    for (int off = 32; off > 0; off >>= 1) mx = fmaxf(mx, __shfl_down(mx, off));
    __shared__ float rm[4];
    __shared__ float bmax, bsuminv;
    if ((t & 63) == 0) rm[t >> 6] = mx;
    __syncthreads();
    if (t == 0) bmax = fmaxf(fmaxf(rm[0], rm[1]), fmaxf(rm[2], rm[3]));
    __syncthreads();
    float mall = bmax;
    float s = 0.f;
    #pragma unroll
    for (int q = 0; q < 4; ++q) {
        int i = t + q * 256;
        if (i < 960) { v[q] = __expf(v[q] - mall); s += v[q]; }
    }
    #pragma unroll
    for (int off = 32; off > 0; off >>= 1) s += __shfl_down(s, off);
    if ((t & 63) == 0) rm[t >> 6] = s;
    __syncthreads();
    if (t == 0) bsuminv = 1.0f / (rm[0] + rm[1] + rm[2] + rm[3]);
    __syncthreads();
    float invS = bsuminv;
    #pragma unroll
    for (int q = 0; q < 4; ++q) {
        int i = t + q * 256;
        if (i < 960) xr[i] = v[q] * invS;
    }
}

// ---------------------------------------------------------------------------

extern "C" void kernel_launch(void* const* d_in, const int* in_sizes, int n_in,
                              void* d_out, int out_size, void* d_ws, size_t ws_size,
                              hipStream_t stream)
{
    const float* emb[4]  = {(const float*)d_in[0], (const float*)d_in[1],
                            (const float*)d_in[2], (const float*)d_in[3]};
    const float* emb_all = (const float*)d_in[4];
    const float* w_mh[4] = {(const float*)d_in[5], (const float*)d_in[6],
                            (const float*)d_in[7], (const float*)d_in[8]};
    const float* w_mq = (const float*)d_in[9];
    const float* w_mk = (const float*)d_in[10];
    const float* w_mv = (const float*)d_in[11];
    const float* w_q[4] = {(const float*)d_in[12], (const float*)d_in[13],
                           (const float*)d_in[14], (const float*)d_in[15]};
    const float* w_qc = (const float*)d_in[16];
    const float* w_kc = (const float*)d_in[17];
    const float* w_vc = (const float*)d_in[18];
    const float* w_proj[4] = {(const float*)d_in[19], (const float*)d_in[20],
                              (const float*)d_in[21], (const float*)d_in[22]};
    float* out = (float*)d_out;

    float* ws = (float*)d_ws;
    const long SZ = (long)NB * KVC * HWN;          // 7,864,320 floats
    float* bufA = ws;                               // staging / ctx
    float* bufB = ws + SZ;                          // Vc / q / o
    float* bufC = ws + 2 * SZ;                      // Qc / qd
    float* bufD = ws + 3 * SZ;                      // Kc
    float* bufE = ws + 4 * SZ;                      // sim / attn (8*960*960)
    float2* part  = (float2*)(ws + 4 * SZ + (long)NB * KVC * KVC);
    float2* stats = part + 64 * NB;

    const float scale = 0.0322748612183951400f;     // 1/sqrt(960)
    const long SB_ALL = (long)KVC * HWN;            // per-batch stride 983040
    const int CH[4] = {64, 128, 256, 512};
    dim3 blk(256);

    auto launch_gemm_nn = [&](const float* A, const float* Bm, float* C,
                              int M, int N, int K, long sA, long sB, long sC, float alpha) {
        dim3 g(N / 64, M / 64, NB);
        gemm_kernel<0><<<g, blk, 0, stream>>>(A, Bm, C, M, N, K, sA, sB, sC, alpha);
    };
    auto launch_gemm_nt = [&](const float* A, const float* Bm, float* C,
                              int M, int N, int K, long sA, long sB, long sC, float alpha) {
        dim3 g(N / 64, M / 64, NB);
        gemm_kernel<1><<<g, blk, 0, stream>>>(A, Bm, C, M, N, K, sA, sB, sC, alpha);
    };

    const int dwBlocks = NB * KVC * HWN / 256;      // 30720

    // ---- channel cross-attention (Qc, Kc, Vc) ----
    launch_gemm_nn(w_mv, emb_all, bufA, KVC, HWN, KVC, 0, SB_ALL, SB_ALL, 1.f);
    dwconv_kernel<<<dwBlocks, blk, 0, stream>>>(bufA, w_vc, bufB, KVC);   // Vc

    launch_gemm_nn(w_mq, emb_all, bufA, KVC, HWN, KVC, 0, SB_ALL, SB_ALL, 1.f);
    dwconv_kernel<<<dwBlocks, blk, 0, stream>>>(bufA, w_qc, bufC, KVC);   // Qc

    launch_gemm_nn(w_mk, emb_all, bufA, KVC, HWN, KVC, 0, SB_ALL, SB_ALL, 1.f);
    dwconv_kernel<<<dwBlocks, blk, 0, stream>>>(bufA, w_kc, bufD, KVC);   // Kc

    l2norm_kernel<<<NB * KVC, blk, 0, stream>>>(bufC);
    l2norm_kernel<<<NB * KVC, blk, 0, stream>>>(bufD);

    // sim = (Qc @ Kc^T) * scale  -> bufE [8][960][960]
    launch_gemm_nt(bufC, bufD, bufE, KVC, KVC, HWN, SB_ALL, SB_ALL, (long)KVC * KVC, scale);

    // softmax(instnorm(sim))
    stats_partial_kernel<<<dim3(64, NB), blk, 0, stream>>>(bufE, part, (long)KVC * KVC);
    stats_reduce_kernel<<<NB, 64, 0, stream>>>(part, stats);
    instnorm_softmax_kernel<<<NB * KVC, blk, 0, stream>>>(bufE, stats, KVC,
                                                          1.f / ((float)KVC * (float)KVC));

    // ctx = sim @ Vc -> bufA [8][960][1024]
    launch_gemm_nn(bufE, bufB, bufA, KVC, HWN, KVC, (long)KVC * KVC, SB_ALL, SB_ALL, 1.f);

    // ---- branches ----
    float* op = out;
    for (int i = 0; i < 4; ++i) {
        const int c = CH[i];
        const long sQ = (long)c * HWN;       // per-batch stride of q/o
        const long sS = (long)c * KVC;       // per-batch stride of attn
        const int cBlocks = NB * c * HWN / 256;

        launch_gemm_nn(w_mh[i], emb[i], bufB, c, HWN, c, 0, sQ, sQ, 1.f);
        gconv_kernel<<<cBlocks, blk, 0, stream>>>(bufB, w_q[i], bufC, c);
        l2norm_kernel<<<NB * c, blk, 0, stream>>>(bufC);

        // attn = (q @ ctx^T) * scale -> bufE [8][c][960]
        launch_gemm_nt(bufC, bufA, bufE, c, KVC, HWN, sQ, SB_ALL, sS, scale);

        stats_partial_kernel<<<dim3(64, NB), blk, 0, stream>>>(bufE, part, sS);
        stats_reduce_kernel<<<NB, 64, 0, stream>>>(part, stats);
        instnorm_softmax_kernel<<<NB * c, blk, 0, stream>>>(bufE, stats, c,
                                                            1.f / (float)(c * KVC));

        // o = p @ ctx -> bufB [8][c][1024]
        launch_gemm_nn(bufE, bufA, bufB, c, HWN, KVC, sS, SB_ALL, sQ, 1.f);

        // out = conv1x1(o, w_proj)
        launch_gemm_nn(w_proj[i], bufB, op, c, HWN, c, 0, sQ, sQ, 1.f);
        op += (long)NB * c * HWN;
    }
    (void)in_sizes; (void)n_in; (void)out_size; (void)ws_size;
}

// Round 2
// 862.492 us; speedup vs baseline: 2.5706x; 2.5706x over previous
//
#include <hip/hip_runtime.h>
#include <hip/hip_bf16.h>
#include <math.h>

#define NB 8
#define HWN 1024
#define KVC 960

typedef short bf16x8 __attribute__((ext_vector_type(8)));
typedef float f32x4 __attribute__((ext_vector_type(4)));
typedef unsigned short ushort_t;

__device__ inline ushort_t f2bf(float f) {
    __hip_bfloat16 h = __float2bfloat16(f);
    return *reinterpret_cast<ushort_t*>(&h);
}

// ---------------------------------------------------------------------------
// bf16 MFMA GEMM, NT: C[b][m][n] = alpha * sum_k A[b][m][k] * B[b][n][k]
// A:[M][K] bf16, B:[N][K] bf16, C f32 or bf16. M,N mult of 64, K mult of 32.
// 128x128 tile, BK=32, 4 waves (2x2), each wave 4x4 frags of 16x16x32.
// grid = (ceil(N/128), ceil(M/128), batch)
// ---------------------------------------------------------------------------
template<int OUT_BF16>
__global__ __launch_bounds__(256)
void mfma_gemm_nt(const __hip_bfloat16* __restrict__ A, const __hip_bfloat16* __restrict__ B,
                  void* __restrict__ Cout, int M, int N, int K,
                  long sA, long sB, long sC, float alpha)
{
    __shared__ __align__(16) ushort_t lA[128 * 32];
    __shared__ __align__(16) ushort_t lB[128 * 32];
    const ushort_t* Ab = (const ushort_t*)A + (long)blockIdx.z * sA;
    const ushort_t* Bb = (const ushort_t*)B + (long)blockIdx.z * sB;
    const int row0 = blockIdx.y * 128, col0 = blockIdx.x * 128;
    const int t = threadIdx.x;
    const int lane = t & 63, w = t >> 6;
    const int wr = w >> 1, wc = w & 1;

    int ar[2], br[2];
    #pragma unroll
    for (int j = 0; j < 2; ++j) {
        int r = row0 + w * 32 + j * 16 + (lane >> 2);
        ar[j] = r < M ? r : M - 1;
        int rb = col0 + w * 32 + j * 16 + (lane >> 2);
        br[j] = rb < N ? rb : N - 1;
    }
    const int kch = (lane & 3) * 8;

    f32x4 acc[4][4];
    #pragma unroll
    for (int m = 0; m < 4; ++m)
        #pragma unroll
        for (int n = 0; n < 4; ++n)
            acc[m][n] = (f32x4){0.f, 0.f, 0.f, 0.f};

    for (int k0 = 0; k0 < K; k0 += 32) {
        #pragma unroll
        for (int j = 0; j < 2; ++j) {
            const ushort_t* sa = Ab + (long)ar[j] * K + k0 + kch;
            __builtin_amdgcn_global_load_lds(
                (const __attribute__((address_space(1))) void*)sa,
                (__attribute__((address_space(3))) void*)(lA + (w * 32 + j * 16) * 32),
                16, 0, 0);
            const ushort_t* sb = Bb + (long)br[j] * K + k0 + kch;
            __builtin_amdgcn_global_load_lds(
                (const __attribute__((address_space(1))) void*)sb,
                (__attribute__((address_space(3))) void*)(lB + (w * 32 + j * 16) * 32),
                16, 0, 0);
        }
        __syncthreads();
        bf16x8 aF[4], bF[4];
        #pragma unroll
        for (int m = 0; m < 4; ++m)
            aF[m] = *(const bf16x8*)(lA + (wr * 64 + m * 16 + (lane & 15)) * 32 + (lane >> 4) * 8);
        #pragma unroll
        for (int n = 0; n < 4; ++n)
            bF[n] = *(const bf16x8*)(lB + (wc * 64 + n * 16 + (lane & 15)) * 32 + (lane >> 4) * 8);
        #pragma unroll
        for (int m = 0; m < 4; ++m)
            #pragma unroll
            for (int n = 0; n < 4; ++n)
                acc[m][n] = __builtin_amdgcn_mfma_f32_16x16x32_bf16(aF[m], bF[n], acc[m][n], 0, 0, 0);
        __syncthreads();
    }

    const int cr0 = row0 + wr * 64 + (lane >> 4) * 4;
    const int cc0 = col0 + wc * 64 + (lane & 15);
    #pragma unroll
    for (int m = 0; m < 4; ++m) {
        #pragma unroll
        for (int n = 0; n < 4; ++n) {
            int ccol = cc0 + n * 16;
            if (ccol >= N) continue;
            #pragma unroll
            for (int r = 0; r < 4; ++r) {
                int crow = cr0 + m * 16 + r;
                if (crow >= M) continue;
                float v = acc[m][n][r] * alpha;
                if (OUT_BF16)
                    ((__hip_bfloat16*)Cout + (long)blockIdx.z * sC)[(long)crow * N + ccol] = __float2bfloat16(v);
                else
                    ((float*)Cout + (long)blockIdx.z * sC)[(long)crow * N + ccol] = v;
            }
        }
    }
}

// ---------------------------------------------------------------------------
// Transpose + convert to bf16: in [R][C] (f32 or bf16) -> out [C][R] bf16.
// R, C multiples of 64. grid = (C/64, R/64, batch), 256 threads.
// ---------------------------------------------------------------------------
template<int IS_F32>
__global__ __launch_bounds__(256)
void transpose_b16_kernel(const void* __restrict__ inv, __hip_bfloat16* __restrict__ out,
                          int R, int C, long sIn, long sOut)
{
    __shared__ ushort_t tile[64][65];
    const int r0 = blockIdx.y * 64, c0 = blockIdx.x * 64;
    const int t = threadIdx.x;
    const int tr = t >> 4, tc = (t & 15) * 4;
    if (IS_F32) {
        const float* ib = (const float*)inv + (long)blockIdx.z * sIn;
        #pragma unroll
        for (int p = 0; p < 4; ++p) {
            float4 v = *(const float4*)(ib + (long)(r0 + tr + 16 * p) * C + c0 + tc);
            tile[tr + 16 * p][tc + 0] = f2bf(v.x);
            tile[tr + 16 * p][tc + 1] = f2bf(v.y);
            tile[tr + 16 * p][tc + 2] = f2bf(v.z);
            tile[tr + 16 * p][tc + 3] = f2bf(v.w);
        }
    } else {
        const ushort_t* ib = (const ushort_t*)inv + (long)blockIdx.z * sIn;
        #pragma unroll
        for (int p = 0; p < 4; ++p) {
            ushort4 v = *(const ushort4*)(ib + (long)(r0 + tr + 16 * p) * C + c0 + tc);
            tile[tr + 16 * p][tc + 0] = v.x;
            tile[tr + 16 * p][tc + 1] = v.y;
            tile[tr + 16 * p][tc + 2] = v.z;
            tile[tr + 16 * p][tc + 3] = v.w;
        }
    }
    __syncthreads();
    ushort_t* ob = (ushort_t*)out + (long)blockIdx.z * sOut;
    #pragma unroll
    for (int p = 0; p < 4; ++p) {
        ushort4 v;
        v.x = tile[tc + 0][tr + 16 * p];
        v.y = tile[tc + 1][tr + 16 * p];
        v.z = tile[tc + 2][tr + 16 * p];
        v.w = tile[tc + 3][tr + 16 * p];
        *(ushort4*)(ob + (long)(c0 + tr + 16 * p) * R + r0 + tc) = v;
    }
}

// ---------------------------------------------------------------------------
// Elementwise f32 -> bf16
// ---------------------------------------------------------------------------
__global__ void f2b_kernel(const float* __restrict__ in, __hip_bfloat16* __restrict__ out, int n)
{
    int i = blockIdx.x * 256 + threadIdx.x;
    if (i < n) out[i] = __float2bfloat16(in[i]);
}

// ---------------------------------------------------------------------------
// Depthwise 3x3 SAME conv (groups == C), w: [C][1][3][3]
// ---------------------------------------------------------------------------
__global__ __launch_bounds__(256)
void dwconv_kernel(const float* __restrict__ in, const float* __restrict__ w,
                   float* __restrict__ out, int C)
{
    long idx = (long)blockIdx.x * 256 + threadIdx.x;
    int n = (int)(idx & 1023);
    int x = n & 31, y = n >> 5;
    long bc = idx >> 10;
    int c = (int)(bc % C);
    const float* ip = in + (bc << 10);
    const float* wp = w + c * 9;
    float acc = 0.f;
    #pragma unroll
    for (int dy = 0; dy < 3; ++dy) {
        int yy = y + dy - 1;
        if ((unsigned)yy >= 32u) continue;
        #pragma unroll
        for (int dx = 0; dx < 3; ++dx) {
            int xx = x + dx - 1;
            if ((unsigned)xx >= 32u) continue;
            acc += ip[yy * 32 + xx] * wp[dy * 3 + dx];
        }
    }
    out[idx] = acc;
}

// ---------------------------------------------------------------------------
// Grouped 3x3 SAME conv, groups = C/2, w: [C][2][3][3]
// ---------------------------------------------------------------------------
__global__ __launch_bounds__(256)
void gconv_kernel(const float* __restrict__ in, const float* __restrict__ w,
                  float* __restrict__ out, int C)
{
    long idx = (long)blockIdx.x * 256 + threadIdx.x;
    int n = (int)(idx & 1023);
    int x = n & 31, y = n >> 5;
    long bo = idx >> 10;
    int o = (int)(bo % C);
    int b = (int)(bo / C);
    int g2 = o & ~1;
    const float* wp = w + o * 18;
    float acc = 0.f;
    #pragma unroll
    for (int j = 0; j < 2; ++j) {
        const float* ip = in + (((long)b * C + g2 + j) << 10);
        const float* wj = wp + j * 9;
        #pragma unroll
        for (int dy = 0; dy < 3; ++dy) {
            int yy = y + dy - 1;
            if ((unsigned)yy >= 32u) continue;
            #pragma unroll
            for (int dx = 0; dx < 3; ++dx) {
                int xx = x + dx - 1;
                if ((unsigned)xx >= 32u) continue;
                acc += ip[yy * 32 + xx] * wj[dy * 3 + dx];
            }
        }
    }
    out[idx] = acc;
}

// ---------------------------------------------------------------------------
// Row L2-normalize (row length 1024), read f32, write bf16. One block/row.
// ---------------------------------------------------------------------------
__global__ __launch_bounds__(256)
void l2norm_bf16_kernel(const float* __restrict__ x, __hip_bfloat16* __restrict__ out)
{
    long base = (long)blockIdx.x * 1024 + threadIdx.x * 4;
    float4 v = *(const float4*)(x + base);
    float s = v.x * v.x + v.y * v.y + v.z * v.z + v.w * v.w;
    #pragma unroll
    for (int off = 32; off > 0; off >>= 1) s += __shfl_down(s, off);
    __shared__ float red[5];
    if ((threadIdx.x & 63) == 0) red[threadIdx.x >> 6] = s;
    __syncthreads();
    if (threadIdx.x == 0)
        red[4] = 1.0f / fmaxf(sqrtf(red[0] + red[1] + red[2] + red[3]), 1e-12f);
    __syncthreads();
    float inv = red[4];
    ushort4 o;
    o.x = f2bf(v.x * inv); o.y = f2bf(v.y * inv);
    o.z = f2bf(v.z * inv); o.w = f2bf(v.w * inv);
    *(ushort4*)((ushort_t*)out + base) = o;
}

// ---------------------------------------------------------------------------
// Instance-norm stats (sum, sumsq) over L per batch. grid=(64, NB), 256 thr.
// ---------------------------------------------------------------------------
__global__ __launch_bounds__(256)
void stats_partial_kernel(const float* __restrict__ x, float2* __restrict__ part, long L)
{
    const float* xb = x + (long)blockIdx.y * L;
    float s1 = 0.f, s2 = 0.f;
    for (long i = (long)blockIdx.x * 256 + threadIdx.x; i < L; i += 64L * 256) {
        float v = xb[i];
        s1 += v; s2 += v * v;
    }
    #pragma unroll
    for (int off = 32; off > 0; off >>= 1) {
        s1 += __shfl_down(s1, off);
        s2 += __shfl_down(s2, off);
    }
    __shared__ float r1[4], r2[4];
    int w = threadIdx.x >> 6;
    if ((threadIdx.x & 63) == 0) { r1[w] = s1; r2[w] = s2; }
    __syncthreads();
    if (threadIdx.x == 0)
        part[blockIdx.y * 64 + blockIdx.x] =
            make_float2(r1[0] + r1[1] + r1[2] + r1[3], r2[0] + r2[1] + r2[2] + r2[3]);
}

__global__ void stats_reduce_kernel(const float2* __restrict__ part, float2* __restrict__ stats)
{
    float2 p = part[blockIdx.x * 64 + threadIdx.x];
    float s1 = p.x, s2 = p.y;
    #pragma unroll
    for (int off = 32; off > 0; off >>= 1) {
        s1 += __shfl_down(s1, off);
        s2 += __shfl_down(s2, off);
    }
    if (threadIdx.x == 0) stats[blockIdx.x] = make_float2(s1, s2);
}

// ---------------------------------------------------------------------------
// Fused instance-norm + row softmax (row length 960), f32 in -> bf16 out.
// ---------------------------------------------------------------------------
__global__ __launch_bounds__(256)
void instnorm_softmax_bf16_kernel(const float* __restrict__ x, __hip_bfloat16* __restrict__ out,
                                  const float2* __restrict__ stats, int rowsPerB, float invL)
{
    int row = blockIdx.x;
    int b = row / rowsPerB;
    float2 st = stats[b];
    float mean = st.x * invL;
    float var = st.y * invL - mean * mean;
    float rinv = rsqrtf(var + 1e-5f);
    const float* xr = x + (long)row * 960;
    ushort_t* orow = (ushort_t*)out + (long)row * 960;
    int t = threadIdx.x;
    float v[4];
    float mx = -1e30f;
    #pragma unroll
    for (int q = 0; q < 4; ++q) {
        int i = t + q * 256;
        if (i < 960) { v[q] = (xr[i] - mean) * rinv; mx = fmaxf(mx, v[q]); }
        else v[q] = -1e30f;
    }
    #pragma unroll
    for (int off = 32; off > 0; off >>= 1) mx = fmaxf(mx, __shfl_down(mx, off));
    __shared__ float rm[4];
    __shared__ float bmax, bsuminv;
    if ((t & 63) == 0) rm[t >> 6] = mx;
    __syncthreads();
    if (t == 0) bmax = fmaxf(fmaxf(rm[0], rm[1]), fmaxf(rm[2], rm[3]));
    __syncthreads();
    float mall = bmax;
    float s = 0.f;
    #pragma unroll
    for (int q = 0; q < 4; ++q) {
        int i = t + q * 256;
        if (i < 960) { v[q] = __expf(v[q] - mall); s += v[q]; }
    }
    #pragma unroll
    for (int off = 32; off > 0; off >>= 1) s += __shfl_down(s, off);
    if ((t & 63) == 0) rm[t >> 6] = s;
    __syncthreads();
    if (t == 0) bsuminv = 1.0f / (rm[0] + rm[1] + rm[2] + rm[3]);
    __syncthreads();
    float invS = bsuminv;
    #pragma unroll
    for (int q = 0; q < 4; ++q) {
        int i = t + q * 256;
        if (i < 960) orow[i] = f2bf(v[q] * invS);
    }
}

// ---------------------------------------------------------------------------

extern "C" void kernel_launch(void* const* d_in, const int* in_sizes, int n_in,
                              void* d_out, int out_size, void* d_ws, size_t ws_size,
                              hipStream_t stream)
{
    const float* emb[4]  = {(const float*)d_in[0], (const float*)d_in[1],
                            (const float*)d_in[2], (const float*)d_in[3]};
    const float* emb_all = (const float*)d_in[4];
    const float* w_mh[4] = {(const float*)d_in[5], (const float*)d_in[6],
                            (const float*)d_in[7], (const float*)d_in[8]};
    const float* w_mq = (const float*)d_in[9];
    const float* w_mk = (const float*)d_in[10];
    const float* w_mv = (const float*)d_in[11];
    const float* w_q[4] = {(const float*)d_in[12], (const float*)d_in[13],
                           (const float*)d_in[14], (const float*)d_in[15]};
    const float* w_qc = (const float*)d_in[16];
    const float* w_kc = (const float*)d_in[17];
    const float* w_vc = (const float*)d_in[18];
    const float* w_proj[4] = {(const float*)d_in[19], (const float*)d_in[20],
                              (const float*)d_in[21], (const float*)d_in[22]};
    float* out = (float*)d_out;

    // ---- workspace arena (bytes) ----
    char* W = (char*)d_ws;
    float* F1 = (float*)(W);                                   // 31,457,280 B f32 [8][960][1024]
    float* F2 = (float*)(W + 31457280);                        // 31,457,280 B
    __hip_bfloat16* X1  = (__hip_bfloat16*)(W + 62914560);     // embT_all -> ctxB
    __hip_bfloat16* X2  = (__hip_bfloat16*)(W + 78643200);     // QcB -> ctxTB
    __hip_bfloat16* X3  = (__hip_bfloat16*)(W + 94371840);     // KcB -> PbrB
    __hip_bfloat16* X4  = (__hip_bfloat16*)(W + 110100480);    // VcTB -> oTB
    __hip_bfloat16* PBr = (__hip_bfloat16*)(W + 125829120);    // P (channel) -> embT_i/qB
    __hip_bfloat16* WQb = (__hip_bfloat16*)(W + 140574720);
    __hip_bfloat16* WKb = (__hip_bfloat16*)(W + 142417920);
    __hip_bfloat16* WVb = (__hip_bfloat16*)(W + 144261120);
    __hip_bfloat16* WMHb = (__hip_bfloat16*)(W + 146104320);
    __hip_bfloat16* WPJb = (__hip_bfloat16*)(W + 146800640);
    float2* part  = (float2*)(W + 147496960);
    float2* stats = (float2*)(W + 147501056);

    const float scale = 0.0322748612183951400f;   // 1/sqrt(960)
    const long SB_ALL = (long)KVC * HWN;          // 983040
    const long SSIM = (long)KVC * KVC;            // 921600
    const int CH[4] = {64, 128, 256, 512};
    const int mhoff[4] = {0, 4096, 20480, 86016};
    const int msz[4]   = {4096, 16384, 65536, 262144};
    dim3 blk(256);

    auto gemm = [&](const __hip_bfloat16* A, const __hip_bfloat16* B, void* C,
                    int M, int N, int K, long sA, long sB, long sC, float alpha, bool obf) {
        dim3 g((N + 127) / 128, (M + 127) / 128, NB);
        if (obf) mfma_gemm_nt<1><<<g, blk, 0, stream>>>(A, B, C, M, N, K, sA, sB, sC, alpha);
        else     mfma_gemm_nt<0><<<g, blk, 0, stream>>>(A, B, C, M, N, K, sA, sB, sC, alpha);
    };

    // ---- convert weights to bf16 ----
    f2b_kernel<<<3600, blk, 0, stream>>>(w_mq, WQb, 921600);
    f2b_kernel<<<3600, blk, 0, stream>>>(w_mk, WKb, 921600);
    f2b_kernel<<<3600, blk, 0, stream>>>(w_mv, WVb, 921600);
    for (int i = 0; i < 4; ++i) {
        f2b_kernel<<<(msz[i] + 255) / 256, blk, 0, stream>>>(w_mh[i], WMHb + mhoff[i], msz[i]);
        f2b_kernel<<<(msz[i] + 255) / 256, blk, 0, stream>>>(w_proj[i], WPJb + mhoff[i], msz[i]);
    }

    // ---- embT_all: [b][960][1024] f32 -> [b][1024][960] bf16 ----
    transpose_b16_kernel<1><<<dim3(16, 15, NB), blk, 0, stream>>>(emb_all, X1, KVC, HWN, SB_ALL, SB_ALL);

    const int dwBlocks = NB * KVC * HWN / 256;

    // ---- V path: conv1x1 -> dwconv -> transposed bf16 ----
    gemm(WVb, X1, F1, KVC, HWN, KVC, 0, SB_ALL, SB_ALL, 1.f, false);
    dwconv_kernel<<<dwBlocks, blk, 0, stream>>>(F1, w_vc, F2, KVC);
    transpose_b16_kernel<1><<<dim3(16, 15, NB), blk, 0, stream>>>(F2, X4, KVC, HWN, SB_ALL, SB_ALL);

    // ---- Q path ----
    gemm(WQb, X1, F1, KVC, HWN, KVC, 0, SB_ALL, SB_ALL, 1.f, false);
    dwconv_kernel<<<dwBlocks, blk, 0, stream>>>(F1, w_qc, F2, KVC);
    l2norm_bf16_kernel<<<NB * KVC, blk, 0, stream>>>(F2, X2);

    // ---- K path ----
    gemm(WKb, X1, F1, KVC, HWN, KVC, 0, SB_ALL, SB_ALL, 1.f, false);
    dwconv_kernel<<<dwBlocks, blk, 0, stream>>>(F1, w_kc, F2, KVC);
    l2norm_bf16_kernel<<<NB * KVC, blk, 0, stream>>>(F2, X3);

    // ---- sim = Qc @ Kc^T * scale -> F1 f32 [960][960] ----
    gemm(X2, X3, F1, KVC, KVC, HWN, SB_ALL, SB_ALL, SSIM, scale, false);
    stats_partial_kernel<<<dim3(64, NB), blk, 0, stream>>>(F1, part, SSIM);
    stats_reduce_kernel<<<NB, 64, 0, stream>>>(part, stats);
    instnorm_softmax_bf16_kernel<<<NB * KVC, blk, 0, stream>>>(F1, PBr, stats, KVC,
                                                               1.f / (float)(KVC * KVC));

    // ---- ctx = P @ Vc -> ctxB bf16 (X1), then ctxT (X2) ----
    gemm(PBr, X4, X1, KVC, HWN, KVC, SSIM, SB_ALL, SB_ALL, 1.f, true);
    transpose_b16_kernel<0><<<dim3(16, 15, NB), blk, 0, stream>>>(X1, X2, KVC, HWN, SB_ALL, SB_ALL);

    // ---- branches ----
    float* op = out;
    for (int i = 0; i < 4; ++i) {
        const int c = CH[i];
        const long sQ = (long)c * HWN;
        const long sS = (long)c * KVC;
        const int cBlocks = NB * c * HWN / 256;

        // embT_i: [b][c][1024] f32 -> [b][1024][c] bf16 (PBr region)
        transpose_b16_kernel<1><<<dim3(16, c / 64, NB), blk, 0, stream>>>(emb[i], PBr, c, HWN, sQ, sQ);
        // conv1x1 -> F2 f32 [c][1024]
        gemm(WMHb + mhoff[i], PBr, F2, c, HWN, c, 0, sQ, sQ, 1.f, false);
        // grouped conv -> F1
        gconv_kernel<<<cBlocks, blk, 0, stream>>>(F2, w_q[i], F1, c);
        // l2norm -> qB bf16 (PBr, overwrites embT_i which is dead)
        l2norm_bf16_kernel<<<NB * c, blk, 0, stream>>>(F1, PBr);
        // attn = q @ ctx^T * scale -> F2 f32 [c][960]
        gemm(PBr, X1, F2, c, KVC, HWN, sQ, SB_ALL, sS, scale, false);
        // instnorm + softmax -> PbrB bf16 (X3)
        stats_partial_kernel<<<dim3(64, NB), blk, 0, stream>>>(F2, part, sS);
        stats_reduce_kernel<<<NB, 64, 0, stream>>>(part, stats);
        instnorm_softmax_bf16_kernel<<<NB * c, blk, 0, stream>>>(F2, X3, stats, c,
                                                                 1.f / (float)(c * KVC));
        // oT = ctxT(A) x Pbr(B): [1024][c] bf16 -> X4
        gemm(X2, X3, X4, HWN, c, KVC, SB_ALL, sS, (long)HWN * c, 1.f, true);
        // out = Wproj x oT: [c][1024] f32
        gemm(WPJb + mhoff[i], X4, op, c, HWN, c, 0, (long)HWN * c, sQ, 1.f, false);
        op += NB * sQ;
    }
    (void)in_sizes; (void)n_in; (void)out_size; (void)ws_size;
}

// Round 3
// 441.917 us; speedup vs baseline: 5.0170x; 1.9517x over previous
//
#include <hip/hip_runtime.h>
#include <hip/hip_bf16.h>
#include <math.h>

#define NB 8
#define HWN 1024
#define KVC 960

typedef short bf16x8 __attribute__((ext_vector_type(8)));
typedef float f32x4 __attribute__((ext_vector_type(4)));
typedef unsigned short ushort_t;

__device__ inline ushort_t f2bf(float f) {
    __hip_bfloat16 h = __float2bfloat16(f);
    return *reinterpret_cast<ushort_t*>(&h);
}
__device__ inline float bf2f(ushort_t u) {
    union { float f; unsigned int i; } x; x.i = ((unsigned int)u) << 16; return x.f;
}

// ---------------------------------------------------------------------------
// Batched f32 -> bf16 convert. Each block handles 1024 elems of one segment.
// ---------------------------------------------------------------------------
struct F2BTab {
    const float* src[12];
    long dstOff[12];     // element offset into base
    int nblk[12];
    int nseg;
};

__global__ __launch_bounds__(256)
void f2b_batched(F2BTab tab, ushort_t* base)
{
    int b = blockIdx.x, s = 0;
    while (s < tab.nseg - 1 && b >= tab.nblk[s]) { b -= tab.nblk[s]; ++s; }
    const float4* src = (const float4*)tab.src[s] + (long)b * 256 + threadIdx.x;
    float4 v = *src;
    ushort4 o = make_ushort4(f2bf(v.x), f2bf(v.y), f2bf(v.z), f2bf(v.w));
    *((ushort4*)(base + tab.dstOff[s]) + (long)b * 256 + threadIdx.x) = o;
}

// ---------------------------------------------------------------------------
// bf16 MFMA GEMM NT + fused instnorm stats partials:
// C[b][m][n] = alpha * sum_k A[b][m][k] * B[b][n][k]  (f32 out)
// part[(bz*8+by)*8+bx] = (sum v, sum v^2) over valid entries of this block.
// grid <= (8, 8, NB). 128x128 tile, BK=32, 4 waves.
// ---------------------------------------------------------------------------
__global__ __launch_bounds__(256)
void mfma_gemm_nt_stats(const ushort_t* __restrict__ A, const ushort_t* __restrict__ B,
                        float* __restrict__ C, float2* __restrict__ part,
                        int M, int N, int K, long sA, long sB, long sC, float alpha)
{
    __shared__ __align__(16) ushort_t lA[128 * 32];
    __shared__ __align__(16) ushort_t lB[128 * 32];
    const ushort_t* Ab = A + (long)blockIdx.z * sA;
    const ushort_t* Bb = B + (long)blockIdx.z * sB;
    const int row0 = blockIdx.y * 128, col0 = blockIdx.x * 128;
    const int t = threadIdx.x;
    const int lane = t & 63, w = t >> 6;
    const int wr = w >> 1, wc = w & 1;

    int ar[2], br[2];
    #pragma unroll
    for (int j = 0; j < 2; ++j) {
        int r = row0 + w * 32 + j * 16 + (lane >> 2);
        ar[j] = r < M ? r : M - 1;
        int rb = col0 + w * 32 + j * 16 + (lane >> 2);
        br[j] = rb < N ? rb : N - 1;
    }
    const int kch = (lane & 3) * 8;

    f32x4 acc[4][4];
    #pragma unroll
    for (int m = 0; m < 4; ++m)
        #pragma unroll
        for (int n = 0; n < 4; ++n)
            acc[m][n] = (f32x4){0.f, 0.f, 0.f, 0.f};

    for (int k0 = 0; k0 < K; k0 += 32) {
        #pragma unroll
        for (int j = 0; j < 2; ++j) {
            const ushort_t* sa = Ab + (long)ar[j] * K + k0 + kch;
            __builtin_amdgcn_global_load_lds(
                (const __attribute__((address_space(1))) void*)sa,
                (__attribute__((address_space(3))) void*)(lA + (w * 32 + j * 16) * 32),
                16, 0, 0);
            const ushort_t* sb = Bb + (long)br[j] * K + k0 + kch;
            __builtin_amdgcn_global_load_lds(
                (const __attribute__((address_space(1))) void*)sb,
                (__attribute__((address_space(3))) void*)(lB + (w * 32 + j * 16) * 32),
                16, 0, 0);
        }
        __syncthreads();
        bf16x8 aF[4], bF[4];
        #pragma unroll
        for (int m = 0; m < 4; ++m)
            aF[m] = *(const bf16x8*)(lA + (wr * 64 + m * 16 + (lane & 15)) * 32 + (lane >> 4) * 8);
        #pragma unroll
        for (int n = 0; n < 4; ++n)
            bF[n] = *(const bf16x8*)(lB + (wc * 64 + n * 16 + (lane & 15)) * 32 + (lane >> 4) * 8);
        #pragma unroll
        for (int m = 0; m < 4; ++m)
            #pragma unroll
            for (int n = 0; n < 4; ++n)
                acc[m][n] = __builtin_amdgcn_mfma_f32_16x16x32_bf16(aF[m], bF[n], acc[m][n], 0, 0, 0);
        __syncthreads();
    }

    const int cr0 = row0 + wr * 64 + (lane >> 4) * 4;
    const int cc0 = col0 + wc * 64 + (lane & 15);
    float* Cb = C + (long)blockIdx.z * sC;
    float s1 = 0.f, s2 = 0.f;
    #pragma unroll
    for (int m = 0; m < 4; ++m) {
        #pragma unroll
        for (int n = 0; n < 4; ++n) {
            int ccol = cc0 + n * 16;
            if (ccol >= N) continue;
            #pragma unroll
            for (int r = 0; r < 4; ++r) {
                int crow = cr0 + m * 16 + r;
                if (crow < M) {
                    float v = acc[m][n][r] * alpha;
                    Cb[(long)crow * N + ccol] = v;
                    s1 += v; s2 += v * v;
                }
            }
        }
    }
    // block reduce stats -> part
    #pragma unroll
    for (int off = 32; off > 0; off >>= 1) {
        s1 += __shfl_down(s1, off);
        s2 += __shfl_down(s2, off);
    }
    float* rbuf = (float*)lA;
    if (lane == 0) { rbuf[w] = s1; rbuf[4 + w] = s2; }
    __syncthreads();
    if (t == 0)
        part[(blockIdx.z * 8 + blockIdx.y) * 8 + blockIdx.x] =
            make_float2(rbuf[0] + rbuf[1] + rbuf[2] + rbuf[3],
                        rbuf[4] + rbuf[5] + rbuf[6] + rbuf[7]);
}

// ---------------------------------------------------------------------------
// bf16 MFMA GEMM NN: C[b][m][n] = sum_k A[b][m][k] * B[b][k][n]
// A [M][K] k-contig (global_load_lds); B [K][N] reg-staged transposed into LDS
// with XOR chunk swizzle (4-way conflict). N must be a multiple of 128.
// ---------------------------------------------------------------------------
template<int OUT_BF16>
__global__ __launch_bounds__(256)
void mfma_gemm_nn(const ushort_t* __restrict__ A, const ushort_t* __restrict__ B,
                  void* __restrict__ Cout, int M, int N, int K,
                  long sA, long sB, long sC)
{
    __shared__ __align__(16) ushort_t lA[128 * 32];
    __shared__ __align__(16) ushort_t lB[128 * 32];
    const ushort_t* Ab = A + (long)blockIdx.z * sA;
    const ushort_t* Bb = B + (long)blockIdx.z * sB;
    const int row0 = blockIdx.y * 128, col0 = blockIdx.x * 128;
    const int t = threadIdx.x;
    const int lane = t & 63, w = t >> 6;
    const int wr = w >> 1, wc = w & 1;

    int ar[2];
    #pragma unroll
    for (int j = 0; j < 2; ++j) {
        int r = row0 + w * 32 + j * 16 + (lane >> 2);
        ar[j] = r < M ? r : M - 1;
    }
    const int kch = (lane & 3) * 8;
    const int n_i = t & 31, k_i = t >> 5;
    const int nn = n_i * 4;
    const int wchunk = (((k_i >> 1) ^ (n_i & 3)) << 3) + ((k_i & 1) << 2);

    f32x4 acc[4][4];
    #pragma unroll
    for (int m = 0; m < 4; ++m)
        #pragma unroll
        for (int n = 0; n < 4; ++n)
            acc[m][n] = (f32x4){0.f, 0.f, 0.f, 0.f};

    for (int k0 = 0; k0 < K; k0 += 32) {
        #pragma unroll
        for (int j = 0; j < 2; ++j) {
            const ushort_t* sa = Ab + (long)ar[j] * K + k0 + kch;
            __builtin_amdgcn_global_load_lds(
                (const __attribute__((address_space(1))) void*)sa,
                (__attribute__((address_space(3))) void*)(lA + (w * 32 + j * 16) * 32),
                16, 0, 0);
        }
        const int gk = k0 + k_i * 4;
        ushort4 q0 = *(const ushort4*)(Bb + (long)(gk + 0) * N + col0 + nn);
        ushort4 q1 = *(const ushort4*)(Bb + (long)(gk + 1) * N + col0 + nn);
        ushort4 q2 = *(const ushort4*)(Bb + (long)(gk + 2) * N + col0 + nn);
        ushort4 q3 = *(const ushort4*)(Bb + (long)(gk + 3) * N + col0 + nn);
        // transpose 4x4 and write [n][k] with chunk swizzle
        *(ushort4*)(lB + (nn + 0) * 32 + wchunk) = make_ushort4(q0.x, q1.x, q2.x, q3.x);
        *(ushort4*)(lB + (nn + 1) * 32 + wchunk) = make_ushort4(q0.y, q1.y, q2.y, q3.y);
        *(ushort4*)(lB + (nn + 2) * 32 + wchunk) = make_ushort4(q0.z, q1.z, q2.z, q3.z);
        *(ushort4*)(lB + (nn + 3) * 32 + wchunk) = make_ushort4(q0.w, q1.w, q2.w, q3.w);
        __syncthreads();
        bf16x8 aF[4], bF[4];
        #pragma unroll
        for (int m = 0; m < 4; ++m)
            aF[m] = *(const bf16x8*)(lA + (wr * 64 + m * 16 + (lane & 15)) * 32 + (lane >> 4) * 8);
        #pragma unroll
        for (int n = 0; n < 4; ++n) {
            int nl = wc * 64 + n * 16 + (lane & 15);
            int cr = lane >> 4;
            bF[n] = *(const bf16x8*)(lB + nl * 32 + ((cr ^ ((nl >> 2) & 3)) << 3));
        }
        #pragma unroll
        for (int m = 0; m < 4; ++m)
            #pragma unroll
            for (int n = 0; n < 4; ++n)
                acc[m][n] = __builtin_amdgcn_mfma_f32_16x16x32_bf16(aF[m], bF[n], acc[m][n], 0, 0, 0);
        __syncthreads();
    }

    const int cr0 = row0 + wr * 64 + (lane >> 4) * 4;
    const int cc0 = col0 + wc * 64 + (lane & 15);
    #pragma unroll
    for (int m = 0; m < 4; ++m) {
        #pragma unroll
        for (int n = 0; n < 4; ++n) {
            int ccol = cc0 + n * 16;
            #pragma unroll
            for (int r = 0; r < 4; ++r) {
                int crow = cr0 + m * 16 + r;
                if (crow < M) {
                    float v = acc[m][n][r];
                    if (OUT_BF16)
                        ((ushort_t*)Cout + (long)blockIdx.z * sC)[(long)crow * N + ccol] = f2bf(v);
                    else
                        ((float*)Cout + (long)blockIdx.z * sC)[(long)crow * N + ccol] = v;
                }
            }
        }
    }
}

// ---------------------------------------------------------------------------
// Depthwise 3x3 SAME conv on a 32x32 plane (bf16 in/out) + optional l2norm.
// One block per (b, channel) plane. grid = NB*C.
// ---------------------------------------------------------------------------
template<int DO_L2>
__global__ __launch_bounds__(256)
void dw_kernel(const ushort_t* __restrict__ in, const float* __restrict__ wg,
               ushort_t* __restrict__ out, int C)
{
    __shared__ float pl[32 * 33];
    __shared__ float red[5];
    const int p = blockIdx.x;
    const int c = p % C;
    const ushort_t* ip = in + (long)p * 1024;
    const int t = threadIdx.x;
    const int i0 = t * 4, y = i0 >> 5, x0 = i0 & 31;
    ushort4 u = *(const ushort4*)(ip + i0);
    float* rw = pl + y * 33 + x0;
    rw[0] = bf2f(u.x); rw[1] = bf2f(u.y); rw[2] = bf2f(u.z); rw[3] = bf2f(u.w);
    __syncthreads();
    const float* wp = wg + c * 9;
    float W[9];
    #pragma unroll
    for (int q = 0; q < 9; ++q) W[q] = wp[q];
    float r[3][6];
    #pragma unroll
    for (int dy = 0; dy < 3; ++dy) {
        int yy = y + dy - 1;
        bool vy = (unsigned)yy < 32u;
        #pragma unroll
        for (int j = 0; j < 6; ++j) {
            int xx = x0 - 1 + j;
            r[dy][j] = (vy && (unsigned)xx < 32u) ? pl[yy * 33 + xx] : 0.f;
        }
    }
    float o[4];
    #pragma unroll
    for (int q = 0; q < 4; ++q)
        o[q] = r[0][q] * W[0] + r[0][q + 1] * W[1] + r[0][q + 2] * W[2]
             + r[1][q] * W[3] + r[1][q + 1] * W[4] + r[1][q + 2] * W[5]
             + r[2][q] * W[6] + r[2][q + 1] * W[7] + r[2][q + 2] * W[8];
    float inv = 1.f;
    if (DO_L2) {
        float s = o[0] * o[0] + o[1] * o[1] + o[2] * o[2] + o[3] * o[3];
        #pragma unroll
        for (int off = 32; off > 0; off >>= 1) s += __shfl_down(s, off);
        if ((t & 63) == 0) red[t >> 6] = s;
        __syncthreads();
        if (t == 0) red[4] = 1.0f / fmaxf(sqrtf(red[0] + red[1] + red[2] + red[3]), 1e-12f);
        __syncthreads();
        inv = red[4];
    }
    *(ushort4*)(out + (long)p * 1024 + i0) =
        make_ushort4(f2bf(o[0] * inv), f2bf(o[1] * inv), f2bf(o[2] * inv), f2bf(o[3] * inv));
}

// ---------------------------------------------------------------------------
// Batched grouped 3x3 conv (2-in/2-out per group) + l2norm over all branches.
// mh layout [b][1024][1024] with branch rows at {0,128,256,512}; pad planes
// [64,128) are written as zeros. grid = NB*1024.
// ---------------------------------------------------------------------------
__global__ __launch_bounds__(256)
void gconv_all_kernel(const ushort_t* __restrict__ mh,
                      const float* __restrict__ wq1, const float* __restrict__ wq2,
                      const float* __restrict__ wq3, const float* __restrict__ wq4,
                      ushort_t* __restrict__ q_all)
{
    __shared__ float p0[32 * 33];
    __shared__ float p1[32 * 33];
    __shared__ float red[5];
    const int po = blockIdx.x;
    const int o = po & 1023, b = po >> 10;
    const int t = threadIdx.x;
    ushort_t* op = q_all + (long)po * 1024;
    int off; const float* wbase;
    if (o < 64)       { off = 0;   wbase = wq1; }
    else if (o < 128) { *(ushort4*)(op + t * 4) = make_ushort4(0, 0, 0, 0); return; }
    else if (o < 256) { off = 128; wbase = wq2; }
    else if (o < 512) { off = 256; wbase = wq3; }
    else              { off = 512; wbase = wq4; }
    const int ol = o - off;
    const int g2 = ol & ~1;
    const ushort_t* ip0 = mh + ((long)(b << 10) + off + g2) * 1024;
    const ushort_t* ip1 = ip0 + 1024;
    const int i0 = t * 4, y = i0 >> 5, x0 = i0 & 31;
    ushort4 u0 = *(const ushort4*)(ip0 + i0);
    ushort4 u1 = *(const ushort4*)(ip1 + i0);
    float* r0w = p0 + y * 33 + x0;
    float* r1w = p1 + y * 33 + x0;
    r0w[0] = bf2f(u0.x); r0w[1] = bf2f(u0.y); r0w[2] = bf2f(u0.z); r0w[3] = bf2f(u0.w);
    r1w[0] = bf2f(u1.x); r1w[1] = bf2f(u1.y); r1w[2] = bf2f(u1.z); r1w[3] = bf2f(u1.w);
    __syncthreads();
    const float* wp = wbase + ol * 18;
    float W[18];
    #pragma unroll
    for (int q = 0; q < 18; ++q) W[q] = wp[q];
    float o4[4] = {0.f, 0.f, 0.f, 0.f};
    #pragma unroll
    for (int pl = 0; pl < 2; ++pl) {
        const float* src = pl ? p1 : p0;
        const float* Wp = W + pl * 9;
        float r[3][6];
        #pragma unroll
        for (int dy = 0; dy < 3; ++dy) {
            int yy = y + dy - 1;
            bool vy = (unsigned)yy < 32u;
            #pragma unroll
            for (int j = 0; j < 6; ++j) {
                int xx = x0 - 1 + j;
                r[dy][j] = (vy && (unsigned)xx < 32u) ? src[yy * 33 + xx] : 0.f;
            }
        }
        #pragma unroll
        for (int q = 0; q < 4; ++q)
            o4[q] += r[0][q] * Wp[0] + r[0][q + 1] * Wp[1] + r[0][q + 2] * Wp[2]
                   + r[1][q] * Wp[3] + r[1][q + 1] * Wp[4] + r[1][q + 2] * Wp[5]
                   + r[2][q] * Wp[6] + r[2][q + 1] * Wp[7] + r[2][q + 2] * Wp[8];
    }
    float s = o4[0] * o4[0] + o4[1] * o4[1] + o4[2] * o4[2] + o4[3] * o4[3];
    #pragma unroll
    for (int off2 = 32; off2 > 0; off2 >>= 1) s += __shfl_down(s, off2);
    if ((t & 63) == 0) red[t >> 6] = s;
    __syncthreads();
    if (t == 0) red[4] = 1.0f / fmaxf(sqrtf(red[0] + red[1] + red[2] + red[3]), 1e-12f);
    __syncthreads();
    float inv = red[4];
    *(ushort4*)(op + i0) =
        make_ushort4(f2bf(o4[0] * inv), f2bf(o4[1] * inv), f2bf(o4[2] * inv), f2bf(o4[3] * inv));
}

// ---------------------------------------------------------------------------
// Stats reduces
// ---------------------------------------------------------------------------
__global__ void reduce_sim(const float2* __restrict__ part, float2* __restrict__ stats)
{
    float2 p = part[blockIdx.x * 64 + threadIdx.x];
    float s1 = p.x, s2 = p.y;
    #pragma unroll
    for (int off = 32; off > 0; off >>= 1) {
        s1 += __shfl_down(s1, off);
        s2 += __shfl_down(s2, off);
    }
    if (threadIdx.x == 0) stats[blockIdx.x] = make_float2(s1, s2);
}

__global__ void reduce_branch(const float2* __restrict__ part, float2* __restrict__ stats)
{
    const int br = blockIdx.x & 3, b = blockIdx.x >> 2;
    const int lo4[4] = {0, 1, 2, 4}, hi4[4] = {1, 2, 4, 8};
    float s1 = 0.f, s2 = 0.f;
    if (threadIdx.x < 8) {
        for (int my = lo4[br]; my < hi4[br]; ++my) {
            float2 p = part[(b * 8 + my) * 8 + threadIdx.x];
            s1 += p.x; s2 += p.y;
        }
    }
    #pragma unroll
    for (int off = 32; off > 0; off >>= 1) {
        s1 += __shfl_down(s1, off);
        s2 += __shfl_down(s2, off);
    }
    if (threadIdx.x == 0) stats[b * 4 + br] = make_float2(s1, s2);
}

// ---------------------------------------------------------------------------
// Instance-norm + softmax (row length 960), f32 in -> bf16 out (sim path).
// ---------------------------------------------------------------------------
__global__ __launch_bounds__(256)
void instnorm_softmax_bf16(const float* __restrict__ x, ushort_t* __restrict__ out,
                           const float2* __restrict__ stats, int rowsPerB, float invL)
{
    int row = blockIdx.x;
    int b = row / rowsPerB;
    float2 st = stats[b];
    float mean = st.x * invL;
    float var = st.y * invL - mean * mean;
    float rinv = rsqrtf(var + 1e-5f);
    const float* xr = x + (long)row * 960;
    ushort_t* orow = out + (long)row * 960;
    int t = threadIdx.x;
    float v[4];
    float mx = -1e30f;
    #pragma unroll
    for (int q = 0; q < 4; ++q) {
        int i = t + q * 256;
        if (i < 960) { v[q] = (xr[i] - mean) * rinv; mx = fmaxf(mx, v[q]); }
        else v[q] = -1e30f;
    }
    #pragma unroll
    for (int off = 32; off > 0; off >>= 1) mx = fmaxf(mx, __shfl_down(mx, off));
    __shared__ float rm[4];
    __shared__ float bmax, bsuminv;
    if ((t & 63) == 0) rm[t >> 6] = mx;
    __syncthreads();
    if (t == 0) bmax = fmaxf(fmaxf(rm[0], rm[1]), fmaxf(rm[2], rm[3]));
    __syncthreads();
    float mall = bmax;
    float s = 0.f;
    #pragma unroll
    for (int q = 0; q < 4; ++q) {
        int i = t + q * 256;
        if (i < 960) { v[q] = __expf(v[q] - mall); s += v[q]; }
    }
    #pragma unroll
    for (int off = 32; off > 0; off >>= 1) s += __shfl_down(s, off);
    if ((t & 63) == 0) rm[t >> 6] = s;
    __syncthreads();
    if (t == 0) bsuminv = 1.0f / (rm[0] + rm[1] + rm[2] + rm[3]);
    __syncthreads();
    float invS = bsuminv;
    #pragma unroll
    for (int q = 0; q < 4; ++q) {
        int i = t + q * 256;
        if (i < 960) orow[i] = f2bf(v[q] * invS);
    }
}

// ---------------------------------------------------------------------------
// Batched branch instnorm+softmax: rows [b][1024][960]; pad rows -> zeros.
// ---------------------------------------------------------------------------
__global__ __launch_bounds__(256)
void softmax_attn_kernel(const float* __restrict__ x, ushort_t* __restrict__ P,
                         const float2* __restrict__ stats)
{
    const int r = blockIdx.x & 1023, b = blockIdx.x >> 10;
    const int t = threadIdx.x;
    ushort_t* orow = P + ((long)(b << 10) + r) * 960;
    int br; float cnt;
    if (r < 64)       { br = 0; cnt = 64.f; }
    else if (r < 128) {
        #pragma unroll
        for (int q = 0; q < 4; ++q) {
            int i = t + q * 256;
            if (i < 960) orow[i] = 0;
        }
        return;
    }
    else if (r < 256) { br = 1; cnt = 128.f; }
    else if (r < 512) { br = 2; cnt = 256.f; }
    else              { br = 3; cnt = 512.f; }
    float invL = 1.0f / (cnt * 960.f);
    float2 st = stats[b * 4 + br];
    float mean = st.x * invL;
    float var = st.y * invL - mean * mean;
    float rinv = rsqrtf(var + 1e-5f);
    const float* xr = x + ((long)(b << 10) + r) * 960;
    float v[4];
    float mx = -1e30f;
    #pragma unroll
    for (int q = 0; q < 4; ++q) {
        int i = t + q * 256;
        if (i < 960) { v[q] = (xr[i] - mean) * rinv; mx = fmaxf(mx, v[q]); }
        else v[q] = -1e30f;
    }
    #pragma unroll
    for (int off = 32; off > 0; off >>= 1) mx = fmaxf(mx, __shfl_down(mx, off));
    __shared__ float rm[4];
    __shared__ float bmax, bsuminv;
    if ((t & 63) == 0) rm[t >> 6] = mx;
    __syncthreads();
    if (t == 0) bmax = fmaxf(fmaxf(rm[0], rm[1]), fmaxf(rm[2], rm[3]));
    __syncthreads();
    float mall = bmax;
    float s = 0.f;
    #pragma unroll
    for (int q = 0; q < 4; ++q) {
        int i = t + q * 256;
        if (i < 960) { v[q] = __expf(v[q] - mall); s += v[q]; }
    }
    #pragma unroll
    for (int off = 32; off > 0; off >>= 1) s += __shfl_down(s, off);
    if ((t & 63) == 0) rm[t >> 6] = s;
    __syncthreads();
    if (t == 0) bsuminv = 1.0f / (rm[0] + rm[1] + rm[2] + rm[3]);
    __syncthreads();
    float invS = bsuminv;
    #pragma unroll
    for (int q = 0; q < 4; ++q) {
        int i = t + q * 256;
        if (i < 960) orow[i] = f2bf(v[q] * invS);
    }
}

// ---------------------------------------------------------------------------

extern "C" void kernel_launch(void* const* d_in, const int* in_sizes, int n_in,
                              void* d_out, int out_size, void* d_ws, size_t ws_size,
                              hipStream_t stream)
{
    const float* emb[4]  = {(const float*)d_in[0], (const float*)d_in[1],
                            (const float*)d_in[2], (const float*)d_in[3]};
    const float* emb_all = (const float*)d_in[4];
    const float* w_mh[4] = {(const float*)d_in[5], (const float*)d_in[6],
                            (const float*)d_in[7], (const float*)d_in[8]};
    const float* w_mq = (const float*)d_in[9];
    const float* w_mk = (const float*)d_in[10];
    const float* w_mv = (const float*)d_in[11];
    const float* w_q[4] = {(const float*)d_in[12], (const float*)d_in[13],
                           (const float*)d_in[14], (const float*)d_in[15]};
    const float* w_qc = (const float*)d_in[16];
    const float* w_kc = (const float*)d_in[17];
    const float* w_vc = (const float*)d_in[18];
    const float* w_proj[4] = {(const float*)d_in[19], (const float*)d_in[20],
                              (const float*)d_in[21], (const float*)d_in[22]};
    float* out = (float*)d_out;

    // ---- arena (byte offsets) ----
    char* Wb = (char*)d_ws;
    ushort_t* U = (ushort_t*)d_ws;
    const long eWQ  = 0, eWK = 921600, eWV = 1843200;          // WQKV bf16
    const long eWMH = 2764800;                                  // 348160 elems
    const long eWPJ = 3112960;                                  // 348160 elems
    const long eR1  = 3461120;   // embB_all / mh_x / o_all   (16,777,216 B)
    const long eR2  = 11849728;  // Xtmp                       (15,728,640 B)
    const long eR3  = 19714048;  // QcB / embB_1,2 / q_all     (16,777,216 B)
    const long eR4  = 28102656;  // KcB / embB_3,4             (15,728,640 B)
    const long eR5  = 35966976;  // VcB / P_all                (15,728,640 B)
    float*  F6      = (float*)(Wb + 87662592);   // simF / attnF (31,457,280 B)
    const long eR7  = 59559936;  // P bf16                     (14,745,600 B)
    const long eR8  = 66932736;  // ctx                        (15,728,640 B)
    float2* part    = (float2*)(Wb + 149594112);
    float2* stats   = (float2*)(Wb + 149598208);

    ushort_t* WQb = U + eWQ;  ushort_t* WKb = U + eWK;  ushort_t* WVb = U + eWV;
    ushort_t* WMHb = U + eWMH; ushort_t* WPJb = U + eWPJ;
    ushort_t* embB_all = U + eR1;
    ushort_t* mh_x  = U + eR1;
    ushort_t* o_all = U + eR1;
    ushort_t* Xtmp  = U + eR2;
    ushort_t* QcB   = U + eR3;
    ushort_t* q_all = U + eR3;
    ushort_t* KcB   = U + eR4;
    ushort_t* VcB   = U + eR5;
    ushort_t* P_all = U + eR5;
    ushort_t* Pc    = U + eR7;
    ushort_t* ctx   = U + eR8;
    ushort_t* embB_i[4] = {U + eR3, U + eR3 + 524288, U + eR4, U + eR4 + 2097152};

    const float scale = 0.0322748612183951400f;   // 1/sqrt(960)
    const long SB = (long)KVC * HWN;              // 983040
    const long S1024 = (long)1024 * 1024;
    const int CH[4] = {64, 128, 256, 512};
    const int mhoff[4] = {0, 4096, 20480, 86016};
    const int rowOff[4] = {0, 128, 256, 512};
    const long outOff[4] = {0, 524288, 1572864, 3670016};
    dim3 blk(256);

    // ---- f2b #1: weights + emb_all (12 segments) ----
    F2BTab t1;
    const float* s1[12] = {w_mq, w_mk, w_mv, w_mh[0], w_mh[1], w_mh[2], w_mh[3],
                           w_proj[0], w_proj[1], w_proj[2], w_proj[3], emb_all};
    long d1[12] = {eWQ, eWK, eWV, eWMH + 0, eWMH + 4096, eWMH + 20480, eWMH + 86016,
                   eWPJ + 0, eWPJ + 4096, eWPJ + 20480, eWPJ + 86016, eR1};
    int n1[12] = {900, 900, 900, 4, 16, 64, 256, 4, 16, 64, 256, 7680};
    int tot1 = 0;
    for (int i = 0; i < 12; ++i) { t1.src[i] = s1[i]; t1.dstOff[i] = d1[i]; t1.nblk[i] = n1[i]; tot1 += n1[i]; }
    t1.nseg = 12;
    f2b_batched<<<tot1, blk, 0, stream>>>(t1, U);

    auto gemm_nn = [&](const ushort_t* A, const ushort_t* B, void* C, int M, int N, int K,
                       long sA, long sB, long sC, bool obf) {
        dim3 g(N / 128, (M + 127) / 128, NB);
        if (obf) mfma_gemm_nn<1><<<g, blk, 0, stream>>>(A, B, C, M, N, K, sA, sB, sC);
        else     mfma_gemm_nn<0><<<g, blk, 0, stream>>>(A, B, C, M, N, K, sA, sB, sC);
    };

    const int dwBlocks = NB * KVC;   // 7680

    // ---- Q path ----
    gemm_nn(WQb, embB_all, Xtmp, KVC, HWN, KVC, 0, SB, SB, true);
    dw_kernel<1><<<dwBlocks, blk, 0, stream>>>(Xtmp, w_qc, QcB, KVC);
    // ---- K path ----
    gemm_nn(WKb, embB_all, Xtmp, KVC, HWN, KVC, 0, SB, SB, true);
    dw_kernel<1><<<dwBlocks, blk, 0, stream>>>(Xtmp, w_kc, KcB, KVC);
    // ---- V path ----
    gemm_nn(WVb, embB_all, Xtmp, KVC, HWN, KVC, 0, SB, SB, true);
    dw_kernel<0><<<dwBlocks, blk, 0, stream>>>(Xtmp, w_vc, VcB, KVC);

    // ---- sim = Qc @ Kc^T * scale (f32) + stats ----
    mfma_gemm_nt_stats<<<dim3(8, 8, NB), blk, 0, stream>>>(
        QcB, KcB, F6, part, KVC, KVC, HWN, SB, SB, (long)KVC * KVC, scale);
    reduce_sim<<<NB, 64, 0, stream>>>(part, stats);
    instnorm_softmax_bf16<<<NB * KVC, blk, 0, stream>>>(F6, Pc, stats, KVC,
                                                        1.f / ((float)KVC * (float)KVC));

    // ---- ctx = P @ Vc (bf16) ----
    gemm_nn(Pc, VcB, ctx, KVC, HWN, KVC, (long)KVC * KVC, SB, SB, true);

    // ---- f2b #2: emb_i -> embB_i ----
    F2BTab t2;
    int n2[4] = {512, 1024, 2048, 4096};
    long d2[4] = {eR3, eR3 + 524288, eR4, eR4 + 2097152};
    int tot2 = 0;
    for (int i = 0; i < 4; ++i) { t2.src[i] = emb[i]; t2.dstOff[i] = d2[i]; t2.nblk[i] = n2[i]; tot2 += n2[i]; }
    t2.nseg = 4;
    f2b_batched<<<tot2, blk, 0, stream>>>(t2, U);

    // ---- mhead conv1x1 per branch -> mh_x rows ----
    for (int i = 0; i < 4; ++i)
        gemm_nn(WMHb + mhoff[i], embB_i[i], mh_x + (long)rowOff[i] * 1024,
                CH[i], HWN, CH[i], 0, (long)CH[i] * 1024, S1024, true);

    // ---- grouped conv + l2norm (batched, writes zeros to pad planes) ----
    gconv_all_kernel<<<NB * 1024, blk, 0, stream>>>(mh_x, w_q[0], w_q[1], w_q[2], w_q[3], q_all);

    // ---- attn = q_all @ ctx^T * scale (f32) + stats ----
    mfma_gemm_nt_stats<<<dim3(8, 8, NB), blk, 0, stream>>>(
        q_all, ctx, F6, part, 1024, KVC, HWN, S1024, SB, SB, scale);
    reduce_branch<<<32, 64, 0, stream>>>(part, stats);
    softmax_attn_kernel<<<NB * 1024, blk, 0, stream>>>(F6, P_all, stats);

    // ---- o = P_all @ ctx (bf16) ----
    gemm_nn(P_all, ctx, o_all, 1024, HWN, KVC, SB, SB, S1024, true);

    // ---- proj per branch -> out (f32) ----
    for (int i = 0; i < 4; ++i)
        gemm_nn(WPJb + mhoff[i], o_all + (long)rowOff[i] * 1024, out + outOff[i],
                CH[i], HWN, CH[i], 0, S1024, (long)CH[i] * 1024, false);

    (void)in_sizes; (void)n_in; (void)out_size; (void)ws_size;
}

// Round 4
// 331.219 us; speedup vs baseline: 6.6938x; 1.3342x over previous
//
#include <hip/hip_runtime.h>
#include <hip/hip_bf16.h>
#include <math.h>

#define NB 8
#define HWN 1024
#define KVC 960

typedef short bf16x8 __attribute__((ext_vector_type(8)));
typedef unsigned short u16x8 __attribute__((ext_vector_type(8)));
typedef float f32x4 __attribute__((ext_vector_type(4)));
typedef unsigned short ushort_t;

__device__ inline ushort_t f2bf(float f) {
    __hip_bfloat16 h = __float2bfloat16(f);
    return *reinterpret_cast<ushort_t*>(&h);
}
__device__ inline float bf2f(ushort_t u) {
    union { float f; unsigned int i; } x; x.i = ((unsigned int)u) << 16; return x.f;
}
// B-tile chunk swizzle (chunk = 4 ushorts, 16 chunks per 64-ushort row). Even
// XOR so a 16B read (even chunk pair) stays contiguous.
__device__ inline int XB(int n) { return ((n & 7) ^ ((n >> 3) & 7)) << 1; }

__device__ inline void glds16(const ushort_t* src, ushort_t* dst) {
    __builtin_amdgcn_global_load_lds(
        (const __attribute__((address_space(1))) void*)src,
        (__attribute__((address_space(3))) void*)dst, 16, 0, 0);
}

// ---------------------------------------------------------------------------
// Batched f32 -> bf16 convert. Each block: 1024 elems of one segment.
// ---------------------------------------------------------------------------
struct F2BTab {
    const float* src[16];
    long dstOff[16];
    int nblk[16];
    int nseg;
};

__global__ __launch_bounds__(256)
void f2b_batched(F2BTab tab, ushort_t* base)
{
    int b = blockIdx.x, s = 0;
    while (s < tab.nseg - 1 && b >= tab.nblk[s]) { b -= tab.nblk[s]; ++s; }
    float4 v = *((const float4*)tab.src[s] + (long)b * 256 + threadIdx.x);
    ushort4 o = make_ushort4(f2bf(v.x), f2bf(v.y), f2bf(v.z), f2bf(v.w));
    *((ushort4*)(base + tab.dstOff[s]) + (long)b * 256 + threadIdx.x) = o;
}

// ---------------------------------------------------------------------------
// bf16 MFMA GEMM NT + fused instnorm stats partials. BK=64.
// C[b][m][n] = alpha * sum_k A[b][m][k] * B[b][n][k]  (f32 out)
// A,B k-contiguous. LDS [row][64] with chunk swizzle c_stored = c ^ (row&7)
// (chunk = 8 ushorts) applied on the global SOURCE address (linear LDS dest).
// grid (8, 8, NB), 128x128 tile, 4 waves.
// ---------------------------------------------------------------------------
__global__ __launch_bounds__(256)
void mfma_gemm_nt_stats(const ushort_t* __restrict__ A, const ushort_t* __restrict__ B,
                        float* __restrict__ C, float2* __restrict__ part,
                        int M, int N, int K, long sA, long sB, long sC, float alpha)
{
    __shared__ __align__(16) ushort_t lA[128 * 64];
    __shared__ __align__(16) ushort_t lB[128 * 64];
    const ushort_t* Ab = A + (long)blockIdx.z * sA;
    const ushort_t* Bb = B + (long)blockIdx.z * sB;
    const int row0 = blockIdx.y * 128, col0 = blockIdx.x * 128;
    const int t = threadIdx.x, lane = t & 63, w = t >> 6;
    const int wr = w >> 1, wc = w & 1;
    const int arl = lane >> 3;                       // row within 8-row group
    const int acs = ((lane & 7) ^ arl) * 8;          // swizzled source chunk
    int arow[4], brow[4];
    #pragma unroll
    for (int j = 0; j < 4; ++j) {
        int r = row0 + w * 32 + j * 8 + arl;  arow[j] = r < M ? r : M - 1;
        int rb = col0 + w * 32 + j * 8 + arl; brow[j] = rb < N ? rb : N - 1;
    }

    f32x4 acc[4][4];
    #pragma unroll
    for (int m = 0; m < 4; ++m)
        #pragma unroll
        for (int n = 0; n < 4; ++n)
            acc[m][n] = (f32x4){0.f, 0.f, 0.f, 0.f};

    for (int k0 = 0; k0 < K; k0 += 64) {
        #pragma unroll
        for (int j = 0; j < 4; ++j) {
            glds16(Ab + (long)arow[j] * K + k0 + acs, lA + (w * 32 + j * 8) * 64);
            glds16(Bb + (long)brow[j] * K + k0 + acs, lB + (w * 32 + j * 8) * 64);
        }
        __syncthreads();
        #pragma unroll
        for (int sub = 0; sub < 2; ++sub) {
            const int kc = (lane >> 4) + sub * 4;
            bf16x8 aF[4], bF[4];
            #pragma unroll
            for (int m = 0; m < 4; ++m) {
                int rl = wr * 64 + m * 16 + (lane & 15);
                aF[m] = *(const bf16x8*)(lA + rl * 64 + (kc ^ (rl & 7)) * 8);
            }
            #pragma unroll
            for (int n = 0; n < 4; ++n) {
                int rl = wc * 64 + n * 16 + (lane & 15);
                bF[n] = *(const bf16x8*)(lB + rl * 64 + (kc ^ (rl & 7)) * 8);
            }
            #pragma unroll
            for (int m = 0; m < 4; ++m)
                #pragma unroll
                for (int n = 0; n < 4; ++n)
                    acc[m][n] = __builtin_amdgcn_mfma_f32_16x16x32_bf16(aF[m], bF[n], acc[m][n], 0, 0, 0);
        }
        __syncthreads();
    }

    const int cr0 = row0 + wr * 64 + (lane >> 4) * 4;
    const int cc0 = col0 + wc * 64 + (lane & 15);
    float* Cb = C + (long)blockIdx.z * sC;
    float s1 = 0.f, s2 = 0.f;
    #pragma unroll
    for (int m = 0; m < 4; ++m) {
        #pragma unroll
        for (int n = 0; n < 4; ++n) {
            int ccol = cc0 + n * 16;
            if (ccol >= N) continue;
            #pragma unroll
            for (int r = 0; r < 4; ++r) {
                int crow = cr0 + m * 16 + r;
                if (crow < M) {
                    float v = acc[m][n][r] * alpha;
                    Cb[(long)crow * N + ccol] = v;
                    s1 += v; s2 += v * v;
                }
            }
        }
    }
    #pragma unroll
    for (int off = 32; off > 0; off >>= 1) {
        s1 += __shfl_down(s1, off);
        s2 += __shfl_down(s2, off);
    }
    float* rbuf = (float*)lA;
    if (lane == 0) { rbuf[w] = s1; rbuf[4 + w] = s2; }
    __syncthreads();
    if (t == 0)
        part[(blockIdx.z * 8 + blockIdx.y) * 8 + blockIdx.x] =
            make_float2(rbuf[0] + rbuf[1] + rbuf[2] + rbuf[3],
                        rbuf[4] + rbuf[5] + rbuf[6] + rbuf[7]);
}

// ---------------------------------------------------------------------------
// Table-driven bf16 MFMA GEMM NN, BK=64, N fixed 1024.
// C[b][m][n] = sum_k A[b][m][k] * B[b][k][n]
// A [M][K] k-contig via swizzled-source global_load_lds; B [K][1024] reg-staged
// transposed into LDS [n][64] with XB chunk swizzle. Segments along grid.y.
// ---------------------------------------------------------------------------
struct NNTab {
    const ushort_t* A[5];
    const ushort_t* B[5];
    void* C[5];
    long sA[5], sB[5], sC[5];
    int M[5], K[5], obf[5], mt0[5];
    int nseg;
};

__global__ __launch_bounds__(256)
void mfma_gemm_nn(NNTab tab)
{
    __shared__ __align__(16) ushort_t lA[128 * 64];
    __shared__ __align__(16) ushort_t lB[128 * 64];
    int si = 0;
    #pragma unroll
    for (int s = 1; s < 5; ++s)
        if (s < tab.nseg && (int)blockIdx.y >= tab.mt0[s]) si = s;
    const int M = tab.M[si], K = tab.K[si];
    const int ytile = blockIdx.y - tab.mt0[si];
    const ushort_t* Ab = tab.A[si] + (long)blockIdx.z * tab.sA[si];
    const ushort_t* Bb = tab.B[si] + (long)blockIdx.z * tab.sB[si];
    const int row0 = ytile * 128, col0 = blockIdx.x * 128;
    const int t = threadIdx.x, lane = t & 63, w = t >> 6;
    const int wr = w >> 1, wc = w & 1;
    const int arl = lane >> 3;
    const int acs = ((lane & 7) ^ arl) * 8;
    int arow[4];
    #pragma unroll
    for (int j = 0; j < 4; ++j) {
        int r = row0 + w * 32 + j * 8 + arl;
        arow[j] = r < M ? r : M - 1;
    }
    const int n_i = t & 31, k_i = t >> 5;    // B stage: 4 n-cols x 8 k-rows

    f32x4 acc[4][4];
    #pragma unroll
    for (int m = 0; m < 4; ++m)
        #pragma unroll
        for (int n = 0; n < 4; ++n)
            acc[m][n] = (f32x4){0.f, 0.f, 0.f, 0.f};

    for (int k0 = 0; k0 < K; k0 += 64) {
        #pragma unroll
        for (int j = 0; j < 4; ++j)
            glds16(Ab + (long)arow[j] * K + k0 + acs, lA + (w * 32 + j * 8) * 64);
        ushort4 q[8];
        const int gk = k0 + k_i * 8;
        #pragma unroll
        for (int kk = 0; kk < 8; ++kk)
            q[kk] = *(const ushort4*)(Bb + (long)(gk + kk) * 1024 + col0 + n_i * 4);
        #pragma unroll
        for (int i = 0; i < 4; ++i) {
            int n = n_i * 4 + i;
            int cw = (k_i * 2) ^ XB(n);
            u16x8 v;
            #pragma unroll
            for (int kk = 0; kk < 4; ++kk) {
                v[kk]     = ((const ushort_t*)&q[kk])[i];
                v[4 + kk] = ((const ushort_t*)&q[4 + kk])[i];
            }
            *(u16x8*)(lB + n * 64 + cw * 4) = v;
        }
        __syncthreads();
        #pragma unroll
        for (int sub = 0; sub < 2; ++sub) {
            const int kcA = (lane >> 4) + sub * 4;
            const int cB = (lane >> 4) * 2 + sub * 8;
            bf16x8 aF[4], bF[4];
            #pragma unroll
            for (int m = 0; m < 4; ++m) {
                int rl = wr * 64 + m * 16 + (lane & 15);
                aF[m] = *(const bf16x8*)(lA + rl * 64 + (kcA ^ (rl & 7)) * 8);
            }
            #pragma unroll
            for (int n = 0; n < 4; ++n) {
                int nl = wc * 64 + n * 16 + (lane & 15);
                bF[n] = *(const bf16x8*)(lB + nl * 64 + (cB ^ XB(nl)) * 4);
            }
            #pragma unroll
            for (int m = 0; m < 4; ++m)
                #pragma unroll
                for (int n = 0; n < 4; ++n)
                    acc[m][n] = __builtin_amdgcn_mfma_f32_16x16x32_bf16(aF[m], bF[n], acc[m][n], 0, 0, 0);
        }
        __syncthreads();
    }

    const int cr0 = row0 + wr * 64 + (lane >> 4) * 4;
    const int cc0 = col0 + wc * 64 + (lane & 15);
    const int obf = tab.obf[si];
    ushort_t* Cb_b = (ushort_t*)tab.C[si] + (long)blockIdx.z * tab.sC[si];
    float* Cb_f = (float*)tab.C[si] + (long)blockIdx.z * tab.sC[si];
    #pragma unroll
    for (int m = 0; m < 4; ++m) {
        #pragma unroll
        for (int n = 0; n < 4; ++n) {
            int ccol = cc0 + n * 16;
            #pragma unroll
            for (int r = 0; r < 4; ++r) {
                int crow = cr0 + m * 16 + r;
                if (crow < M) {
                    float v = acc[m][n][r];
                    if (obf) Cb_b[(long)crow * 1024 + ccol] = f2bf(v);
                    else     Cb_f[(long)crow * 1024 + ccol] = v;
                }
            }
        }
    }
}

// ---------------------------------------------------------------------------
// Fused stencil launch: depthwise 3x3 on Q/K/V (l2norm on Q,K) + grouped
// 3x3 conv + l2norm for all branches.
// blocks [0,23040): dw;  [23040, 31232): gconv.
// ---------------------------------------------------------------------------
__global__ __launch_bounds__(256)
void stencil_all(const ushort_t* __restrict__ Xqkv, const ushort_t* __restrict__ mh_x,
                 const float* __restrict__ w_qc, const float* __restrict__ w_kc,
                 const float* __restrict__ w_vc,
                 const float* __restrict__ wq1, const float* __restrict__ wq2,
                 const float* __restrict__ wq3, const float* __restrict__ wq4,
                 ushort_t* __restrict__ Qc, ushort_t* __restrict__ Kc,
                 ushort_t* __restrict__ Vc, ushort_t* __restrict__ q_all)
{
    __shared__ float p0[32 * 33];
    __shared__ float p1[32 * 33];
    __shared__ float red[5];
    const int bid = blockIdx.x;
    const int t = threadIdx.x;
    const int i0 = t * 4, y = i0 >> 5, x0 = i0 & 31;

    if (bid < 23040) {
        // ---- depthwise ----
        const int which = bid / 7680;
        const int p = bid - which * 7680;
        const int b = p / 960, c = p - b * 960;
        const ushort_t* ip = Xqkv + ((long)b * 2880 + which * 960 + c) * 1024;
        const float* wgt = (which == 0 ? w_qc : which == 1 ? w_kc : w_vc) + c * 9;
        ushort_t* op = (which == 0 ? Qc : which == 1 ? Kc : Vc) + (long)p * 1024;
        ushort4 u = *(const ushort4*)(ip + i0);
        float* rw = p0 + y * 33 + x0;
        rw[0] = bf2f(u.x); rw[1] = bf2f(u.y); rw[2] = bf2f(u.z); rw[3] = bf2f(u.w);
        __syncthreads();
        float W[9];
        #pragma unroll
        for (int q = 0; q < 9; ++q) W[q] = wgt[q];
        float r[3][6];
        #pragma unroll
        for (int dy = 0; dy < 3; ++dy) {
            int yy = y + dy - 1;
            bool vy = (unsigned)yy < 32u;
            #pragma unroll
            for (int j = 0; j < 6; ++j) {
                int xx = x0 - 1 + j;
                r[dy][j] = (vy && (unsigned)xx < 32u) ? p0[yy * 33 + xx] : 0.f;
            }
        }
        float o[4];
        #pragma unroll
        for (int q = 0; q < 4; ++q)
            o[q] = r[0][q] * W[0] + r[0][q + 1] * W[1] + r[0][q + 2] * W[2]
                 + r[1][q] * W[3] + r[1][q + 1] * W[4] + r[1][q + 2] * W[5]
                 + r[2][q] * W[6] + r[2][q + 1] * W[7] + r[2][q + 2] * W[8];
        float inv = 1.f;
        if (which < 2) {
            float s = o[0] * o[0] + o[1] * o[1] + o[2] * o[2] + o[3] * o[3];
            #pragma unroll
            for (int off = 32; off > 0; off >>= 1) s += __shfl_down(s, off);
            if ((t & 63) == 0) red[t >> 6] = s;
            __syncthreads();
            if (t == 0) red[4] = 1.0f / fmaxf(sqrtf(red[0] + red[1] + red[2] + red[3]), 1e-12f);
            __syncthreads();
            inv = red[4];
        }
        *(ushort4*)(op + i0) =
            make_ushort4(f2bf(o[0] * inv), f2bf(o[1] * inv), f2bf(o[2] * inv), f2bf(o[3] * inv));
        return;
    }
    // ---- grouped conv + l2norm ----
    const int po = bid - 23040;
    const int o = po & 1023, b = po >> 10;
    ushort_t* op = q_all + (long)po * 1024;
    int off; const float* wbase;
    if (o < 64)       { off = 0;   wbase = wq1; }
    else if (o < 128) { *(ushort4*)(op + i0) = make_ushort4(0, 0, 0, 0); return; }
    else if (o < 256) { off = 128; wbase = wq2; }
    else if (o < 512) { off = 256; wbase = wq3; }
    else              { off = 512; wbase = wq4; }
    const int ol = o - off;
    const int g2 = ol & ~1;
    const ushort_t* ip0 = mh_x + ((long)(b << 10) + off + g2) * 1024;
    const ushort_t* ip1 = ip0 + 1024;
    ushort4 u0 = *(const ushort4*)(ip0 + i0);
    ushort4 u1 = *(const ushort4*)(ip1 + i0);
    float* r0w = p0 + y * 33 + x0;
    float* r1w = p1 + y * 33 + x0;
    r0w[0] = bf2f(u0.x); r0w[1] = bf2f(u0.y); r0w[2] = bf2f(u0.z); r0w[3] = bf2f(u0.w);
    r1w[0] = bf2f(u1.x); r1w[1] = bf2f(u1.y); r1w[2] = bf2f(u1.z); r1w[3] = bf2f(u1.w);
    __syncthreads();
    const float* wp = wbase + ol * 18;
    float W[18];
    #pragma unroll
    for (int q = 0; q < 18; ++q) W[q] = wp[q];
    float o4[4] = {0.f, 0.f, 0.f, 0.f};
    #pragma unroll
    for (int pl = 0; pl < 2; ++pl) {
        const float* src = pl ? p1 : p0;
        const float* Wp = W + pl * 9;
        float r[3][6];
        #pragma unroll
        for (int dy = 0; dy < 3; ++dy) {
            int yy = y + dy - 1;
            bool vy = (unsigned)yy < 32u;
            #pragma unroll
            for (int j = 0; j < 6; ++j) {
                int xx = x0 - 1 + j;
                r[dy][j] = (vy && (unsigned)xx < 32u) ? src[yy * 33 + xx] : 0.f;
            }
        }
        #pragma unroll
        for (int q = 0; q < 4; ++q)
            o4[q] += r[0][q] * Wp[0] + r[0][q + 1] * Wp[1] + r[0][q + 2] * Wp[2]
                   + r[1][q] * Wp[3] + r[1][q + 1] * Wp[4] + r[1][q + 2] * Wp[5]
                   + r[2][q] * Wp[6] + r[2][q + 1] * Wp[7] + r[2][q + 2] * Wp[8];
    }
    float s = o4[0] * o4[0] + o4[1] * o4[1] + o4[2] * o4[2] + o4[3] * o4[3];
    #pragma unroll
    for (int off2 = 32; off2 > 0; off2 >>= 1) s += __shfl_down(s, off2);
    if ((t & 63) == 0) red[t >> 6] = s;
    __syncthreads();
    if (t == 0) red[4] = 1.0f / fmaxf(sqrtf(red[0] + red[1] + red[2] + red[3]), 1e-12f);
    __syncthreads();
    float inv = red[4];
    *(ushort4*)(op + i0) =
        make_ushort4(f2bf(o4[0] * inv), f2bf(o4[1] * inv), f2bf(o4[2] * inv), f2bf(o4[3] * inv));
}

// ---------------------------------------------------------------------------
// Stats reduces
// ---------------------------------------------------------------------------
__global__ void reduce_sim(const float2* __restrict__ part, float2* __restrict__ stats)
{
    float2 p = part[blockIdx.x * 64 + threadIdx.x];
    float s1 = p.x, s2 = p.y;
    #pragma unroll
    for (int off = 32; off > 0; off >>= 1) {
        s1 += __shfl_down(s1, off);
        s2 += __shfl_down(s2, off);
    }
    if (threadIdx.x == 0) stats[blockIdx.x] = make_float2(s1, s2);
}

__global__ void reduce_branch(const float2* __restrict__ part, float2* __restrict__ stats)
{
    const int br = blockIdx.x & 3, b = blockIdx.x >> 2;
    const int lo4[4] = {0, 1, 2, 4}, hi4[4] = {1, 2, 4, 8};
    float s1 = 0.f, s2 = 0.f;
    if (threadIdx.x < 8) {
        for (int my = lo4[br]; my < hi4[br]; ++my) {
            float2 p = part[(b * 8 + my) * 8 + threadIdx.x];
            s1 += p.x; s2 += p.y;
        }
    }
    #pragma unroll
    for (int off = 32; off > 0; off >>= 1) {
        s1 += __shfl_down(s1, off);
        s2 += __shfl_down(s2, off);
    }
    if (threadIdx.x == 0) stats[b * 4 + br] = make_float2(s1, s2);
}

// ---------------------------------------------------------------------------
// Instance-norm + softmax (row length 960), f32 in -> bf16 out (sim path).
// ---------------------------------------------------------------------------
__global__ __launch_bounds__(256)
void instnorm_softmax_bf16(const float* __restrict__ x, ushort_t* __restrict__ out,
                           const float2* __restrict__ stats, int rowsPerB, float invL)
{
    int row = blockIdx.x;
    int b = row / rowsPerB;
    float2 st = stats[b];
    float mean = st.x * invL;
    float var = st.y * invL - mean * mean;
    float rinv = rsqrtf(var + 1e-5f);
    const float* xr = x + (long)row * 960;
    ushort_t* orow = out + (long)row * 960;
    int t = threadIdx.x;
    float v[4];
    float mx = -1e30f;
    #pragma unroll
    for (int q = 0; q < 4; ++q) {
        int i = t + q * 256;
        if (i < 960) { v[q] = (xr[i] - mean) * rinv; mx = fmaxf(mx, v[q]); }
        else v[q] = -1e30f;
    }
    #pragma unroll
    for (int off = 32; off > 0; off >>= 1) mx = fmaxf(mx, __shfl_down(mx, off));
    __shared__ float rm[4];
    __shared__ float bmax, bsuminv;
    if ((t & 63) == 0) rm[t >> 6] = mx;
    __syncthreads();
    if (t == 0) bmax = fmaxf(fmaxf(rm[0], rm[1]), fmaxf(rm[2], rm[3]));
    __syncthreads();
    float mall = bmax;
    float s = 0.f;
    #pragma unroll
    for (int q = 0; q < 4; ++q) {
        int i = t + q * 256;
        if (i < 960) { v[q] = __expf(v[q] - mall); s += v[q]; }
    }
    #pragma unroll
    for (int off = 32; off > 0; off >>= 1) s += __shfl_down(s, off);
    if ((t & 63) == 0) rm[t >> 6] = s;
    __syncthreads();
    if (t == 0) bsuminv = 1.0f / (rm[0] + rm[1] + rm[2] + rm[3]);
    __syncthreads();
    float invS = bsuminv;
    #pragma unroll
    for (int q = 0; q < 4; ++q) {
        int i = t + q * 256;
        if (i < 960) orow[i] = f2bf(v[q] * invS);
    }
}

// ---------------------------------------------------------------------------
// Batched branch instnorm+softmax: rows [b][1024][960]; pad rows -> zeros.
// ---------------------------------------------------------------------------
__global__ __launch_bounds__(256)
void softmax_attn_kernel(const float* __restrict__ x, ushort_t* __restrict__ P,
                         const float2* __restrict__ stats)
{
    const int r = blockIdx.x & 1023, b = blockIdx.x >> 10;
    const int t = threadIdx.x;
    ushort_t* orow = P + ((long)(b << 10) + r) * 960;
    int br; float cnt;
    if (r < 64)       { br = 0; cnt = 64.f; }
    else if (r < 128) {
        #pragma unroll
        for (int q = 0; q < 4; ++q) {
            int i = t + q * 256;
            if (i < 960) orow[i] = 0;
        }
        return;
    }
    else if (r < 256) { br = 1; cnt = 128.f; }
    else if (r < 512) { br = 2; cnt = 256.f; }
    else              { br = 3; cnt = 512.f; }
    float invL = 1.0f / (cnt * 960.f);
    float2 st = stats[b * 4 + br];
    float mean = st.x * invL;
    float var = st.y * invL - mean * mean;
    float rinv = rsqrtf(var + 1e-5f);
    const float* xr = x + ((long)(b << 10) + r) * 960;
    float v[4];
    float mx = -1e30f;
    #pragma unroll
    for (int q = 0; q < 4; ++q) {
        int i = t + q * 256;
        if (i < 960) { v[q] = (xr[i] - mean) * rinv; mx = fmaxf(mx, v[q]); }
        else v[q] = -1e30f;
    }
    #pragma unroll
    for (int off = 32; off > 0; off >>= 1) mx = fmaxf(mx, __shfl_down(mx, off));
    __shared__ float rm[4];
    __shared__ float bmax, bsuminv;
    if ((t & 63) == 0) rm[t >> 6] = mx;
    __syncthreads();
    if (t == 0) bmax = fmaxf(fmaxf(rm[0], rm[1]), fmaxf(rm[2], rm[3]));
    __syncthreads();
    float mall = bmax;
    float s = 0.f;
    #pragma unroll
    for (int q = 0; q < 4; ++q) {
        int i = t + q * 256;
        if (i < 960) { v[q] = __expf(v[q] - mall); s += v[q]; }
    }
    #pragma unroll
    for (int off = 32; off > 0; off >>= 1) s += __shfl_down(s, off);
    if ((t & 63) == 0) rm[t >> 6] = s;
    __syncthreads();
    if (t == 0) bsuminv = 1.0f / (rm[0] + rm[1] + rm[2] + rm[3]);
    __syncthreads();
    float invS = bsuminv;
    #pragma unroll
    for (int q = 0; q < 4; ++q) {
        int i = t + q * 256;
        if (i < 960) orow[i] = f2bf(v[q] * invS);
    }
}

// ---------------------------------------------------------------------------

extern "C" void kernel_launch(void* const* d_in, const int* in_sizes, int n_in,
                              void* d_out, int out_size, void* d_ws, size_t ws_size,
                              hipStream_t stream)
{
    const float* emb[4]  = {(const float*)d_in[0], (const float*)d_in[1],
                            (const float*)d_in[2], (const float*)d_in[3]};
    const float* emb_all = (const float*)d_in[4];
    const float* w_mh[4] = {(const float*)d_in[5], (const float*)d_in[6],
                            (const float*)d_in[7], (const float*)d_in[8]};
    const float* w_mq = (const float*)d_in[9];
    const float* w_mk = (const float*)d_in[10];
    const float* w_mv = (const float*)d_in[11];
    const float* w_q[4] = {(const float*)d_in[12], (const float*)d_in[13],
                           (const float*)d_in[14], (const float*)d_in[15]};
    const float* w_qc = (const float*)d_in[16];
    const float* w_kc = (const float*)d_in[17];
    const float* w_vc = (const float*)d_in[18];
    const float* w_proj[4] = {(const float*)d_in[19], (const float*)d_in[20],
                              (const float*)d_in[21], (const float*)d_in[22]};
    float* out = (float*)d_out;

    // ---- arena (byte offsets) ----
    char* Wb = (char*)d_ws;
    ushort_t* U = (ushort_t*)d_ws;
    // persistent:
    const long eWQKV = 0;                 // 2,764,800 elems (WQ|WK|WV stacked)
    const long eWMH  = 2764800;           // 348,160 elems
    const long eWPJ  = 3112960;           // 348,160 elems
    const long eEmbA = 3461120;           // embB_all: 7,864,320 elems
    const long eEmbI = 11325440;          // embB_i: 7,864,320 elems total
    const long eXq   = 19189760;          // Xtmp_qkv: 23,592,960 elems (47.2MB)
    const long eMhx  = 42782720;          // mh_x: 8,388,608 elems
    const long eQc   = 51171328;          // QcB: 7,864,320
    const long eKc   = 59035648;          // KcB: 7,864,320
    const long eVc   = 66899968;          // VcB: 7,864,320
    // aliases (elem offsets into U):
    const long eF6   = eXq;                         // f32, 7,864,320 f32 = 15,728,640 ushorts
    const long ePc   = eXq + 15728640;              // Pc bf16: 7,372,800 elems
    const long eQall = eEmbA;                       // q_all: 8,388,608 elems
    const long eCtx  = eMhx;                        // ctx: 7,864,320 elems
    const long ePall = eQc;                         // P_all: 7,864,320 elems
    const long eOall = eKc;                         // o_all: 8,388,608 elems
    float2* part  = (float2*)(Wb + 149528576);
    float2* stats = (float2*)(Wb + 149533000);

    ushort_t* WQKVb = U + eWQKV;
    ushort_t* WMHb  = U + eWMH;
    ushort_t* WPJb  = U + eWPJ;
    ushort_t* embB_all = U + eEmbA;
    ushort_t* Xqkv  = U + eXq;
    ushort_t* mh_x  = U + eMhx;
    ushort_t* QcB   = U + eQc;
    ushort_t* KcB   = U + eKc;
    ushort_t* VcB   = U + eVc;
    float*    F6    = (float*)(U + eF6);
    ushort_t* Pc    = U + ePc;
    ushort_t* q_all = U + eQall;
    ushort_t* ctx   = U + eCtx;
    ushort_t* P_all = U + ePall;
    ushort_t* o_all = U + eOall;
    ushort_t* embB_i[4] = {U + eEmbI, U + eEmbI + 524288, U + eEmbI + 1572864, U + eEmbI + 3670016};

    const float scale = 0.0322748612183951400f;   // 1/sqrt(960)
    const long SB = (long)KVC * HWN;              // 983040
    const long S1024 = 1024L * 1024;
    const int CH[4] = {64, 128, 256, 512};
    const int mhoff[4] = {0, 4096, 20480, 86016};
    const int rowOff[4] = {0, 128, 256, 512};
    const long outOff[4] = {0, 524288, 1572864, 3670016};
    dim3 blk(256);

    // ---- f2b: all weights + all embeddings, one launch ----
    F2BTab tf;
    const float* fs[16] = {w_mq, w_mk, w_mv,
                           w_mh[0], w_mh[1], w_mh[2], w_mh[3],
                           w_proj[0], w_proj[1], w_proj[2], w_proj[3],
                           emb_all, emb[0], emb[1], emb[2], emb[3]};
    long fd[16] = {eWQKV, eWQKV + 921600, eWQKV + 1843200,
                   eWMH + 0, eWMH + 4096, eWMH + 20480, eWMH + 86016,
                   eWPJ + 0, eWPJ + 4096, eWPJ + 20480, eWPJ + 86016,
                   eEmbA, eEmbI, eEmbI + 524288, eEmbI + 1572864, eEmbI + 3670016};
    int fn[16] = {900, 900, 900, 4, 16, 64, 256, 4, 16, 64, 256,
                  7680, 512, 1024, 2048, 4096};
    int ftot = 0;
    for (int i = 0; i < 16; ++i) { tf.src[i] = fs[i]; tf.dstOff[i] = fd[i]; tf.nblk[i] = fn[i]; ftot += fn[i]; }
    tf.nseg = 16;
    f2b_batched<<<ftot, blk, 0, stream>>>(tf, U);

    auto nn1 = [&](const ushort_t* A, long sA, const ushort_t* B, long sB,
                   void* C, long sC, int M, int K, int obf) {
        NNTab tb;
        tb.A[0] = A; tb.B[0] = B; tb.C[0] = C;
        tb.sA[0] = sA; tb.sB[0] = sB; tb.sC[0] = sC;
        tb.M[0] = M; tb.K[0] = K; tb.obf[0] = obf; tb.mt0[0] = 0;
        for (int s = 1; s < 5; ++s) { tb.A[s] = A; tb.B[s] = B; tb.C[s] = C; tb.sA[s] = 0; tb.sB[s] = 0; tb.sC[s] = 0; tb.M[s] = M; tb.K[s] = K; tb.obf[s] = obf; tb.mt0[s] = 1 << 30; }
        tb.nseg = 1;
        dim3 g(8, (M + 127) / 128, NB);
        mfma_gemm_nn<<<g, blk, 0, stream>>>(tb);
    };

    // ---- stage 1: fused QKV (M=2880) + 4x mhead conv1x1, one launch ----
    {
        NNTab tb;
        // seg 0: QKV
        tb.A[0] = WQKVb; tb.B[0] = embB_all; tb.C[0] = Xqkv;
        tb.sA[0] = 0; tb.sB[0] = SB; tb.sC[0] = 2880L * 1024;
        tb.M[0] = 2880; tb.K[0] = 960; tb.obf[0] = 1; tb.mt0[0] = 0;
        int mt = 23;
        for (int i = 0; i < 4; ++i) {
            tb.A[1 + i] = WMHb + mhoff[i]; tb.B[1 + i] = embB_i[i];
            tb.C[1 + i] = mh_x + (long)rowOff[i] * 1024;
            tb.sA[1 + i] = 0; tb.sB[1 + i] = (long)CH[i] * 1024; tb.sC[1 + i] = S1024;
            tb.M[1 + i] = CH[i]; tb.K[1 + i] = CH[i]; tb.obf[1 + i] = 1; tb.mt0[1 + i] = mt;
            mt += (CH[i] + 127) / 128;
        }
        tb.nseg = 5;
        dim3 g(8, mt, NB);   // (8, 31, 8)
        mfma_gemm_nn<<<g, blk, 0, stream>>>(tb);
    }

    // ---- stencils: dw(Q,K,V) + gconv, one launch ----
    stencil_all<<<31232, blk, 0, stream>>>(Xqkv, mh_x, w_qc, w_kc, w_vc,
                                           w_q[0], w_q[1], w_q[2], w_q[3],
                                           QcB, KcB, VcB, q_all);

    // ---- sim = Qc @ Kc^T * scale + stats ----
    mfma_gemm_nt_stats<<<dim3(8, 8, NB), blk, 0, stream>>>(
        QcB, KcB, F6, part, KVC, KVC, HWN, SB, SB, (long)KVC * KVC, scale);
    reduce_sim<<<NB, 64, 0, stream>>>(part, stats);
    instnorm_softmax_bf16<<<NB * KVC, blk, 0, stream>>>(F6, Pc, stats, KVC,
                                                        1.f / ((float)KVC * (float)KVC));

    // ---- ctx = P @ Vc (bf16) ----
    nn1(Pc, (long)KVC * KVC, VcB, SB, ctx, SB, KVC, KVC, 1);

    // ---- attn = q_all @ ctx^T * scale + stats ----
    mfma_gemm_nt_stats<<<dim3(8, 8, NB), blk, 0, stream>>>(
        q_all, ctx, F6, part, 1024, KVC, HWN, S1024, SB, SB, scale);
    reduce_branch<<<32, 64, 0, stream>>>(part, stats);
    softmax_attn_kernel<<<NB * 1024, blk, 0, stream>>>(F6, P_all, stats);

    // ---- o = P_all @ ctx (bf16) ----
    nn1(P_all, SB, ctx, SB, o_all, S1024, 1024, KVC, 1);

    // ---- proj: 4 branches in one table launch (f32 out) ----
    {
        NNTab tb;
        int mt = 0;
        for (int i = 0; i < 4; ++i) {
            tb.A[i] = WPJb + mhoff[i]; tb.B[i] = o_all + (long)rowOff[i] * 1024;
            tb.C[i] = out + outOff[i];
            tb.sA[i] = 0; tb.sB[i] = S1024; tb.sC[i] = (long)CH[i] * 1024;
            tb.M[i] = CH[i]; tb.K[i] = CH[i]; tb.obf[i] = 0; tb.mt0[i] = mt;
            mt += (CH[i] + 127) / 128;
        }
        tb.A[4] = tb.A[3]; tb.B[4] = tb.B[3]; tb.C[4] = tb.C[3];
        tb.sA[4] = 0; tb.sB[4] = 0; tb.sC[4] = 0;
        tb.M[4] = 1; tb.K[4] = 64; tb.obf[4] = 0; tb.mt0[4] = 1 << 30;
        tb.nseg = 4;
        dim3 g(8, mt, NB);   // (8, 8, 8)
        mfma_gemm_nn<<<g, blk, 0, stream>>>(tb);
    }

    (void)in_sizes; (void)n_in; (void)out_size; (void)ws_size;
}

// Round 5
// 330.876 us; speedup vs baseline: 6.7007x; 1.0010x over previous
//
#include <hip/hip_runtime.h>
#include <hip/hip_bf16.h>
#include <math.h>

#define NB 8
#define HWN 1024
#define KVC 960

typedef short bf16x8 __attribute__((ext_vector_type(8)));
typedef float f32x4 __attribute__((ext_vector_type(4)));
typedef unsigned short ushort_t;

__device__ inline ushort_t f2bf(float f) {
    __hip_bfloat16 h = __float2bfloat16(f);
    return *reinterpret_cast<ushort_t*>(&h);
}
__device__ inline float bf2f(ushort_t u) {
    union { float f; unsigned int i; } x; x.i = ((unsigned int)u) << 16; return x.f;
}
__device__ inline void glds16(const ushort_t* src, ushort_t* dst) {
    __builtin_amdgcn_global_load_lds(
        (const __attribute__((address_space(1))) void*)src,
        (__attribute__((address_space(3))) void*)dst, 16, 0, 0);
}

// ---------------------------------------------------------------------------
// Batched f32 -> bf16 convert (no transpose). 1024 elems per block.
// ---------------------------------------------------------------------------
struct F2BTab {
    const float* src[12];
    long dstOff[12];
    int nblk[12];
    int nseg;
};

__global__ __launch_bounds__(256)
void f2b_batched(F2BTab tab, ushort_t* base)
{
    int b = blockIdx.x, s = 0;
    while (s < tab.nseg - 1 && b >= tab.nblk[s]) { b -= tab.nblk[s]; ++s; }
    float4 v = *((const float4*)tab.src[s] + (long)b * 256 + threadIdx.x);
    ushort4 o = make_ushort4(f2bf(v.x), f2bf(v.y), f2bf(v.z), f2bf(v.w));
    *((ushort4*)(base + tab.dstOff[s]) + (long)b * 256 + threadIdx.x) = o;
}

// ---------------------------------------------------------------------------
// Batched f32 -> bf16 transpose-convert: in [b][R][1024] f32 -> out [b][1024][R].
// 64x64 tiles. R multiple of 64.
// ---------------------------------------------------------------------------
struct F2TTab {
    const float* src[5];
    long dstOff[5];
    long sIn[5], sOut[5];
    int R[5];
    int nblk[5];
    int nseg;
};

__global__ __launch_bounds__(256)
void f2bt_batched(F2TTab tab, ushort_t* base)
{
    __shared__ ushort_t tile[64][65];
    int b = blockIdx.x, s = 0;
    while (s < tab.nseg - 1 && b >= tab.nblk[s]) { b -= tab.nblk[s]; ++s; }
    const int R = tab.R[s];
    const int tpb = (R >> 6) * 16;
    const int batch = b / tpb, rem = b - batch * tpb;
    const int rtile = rem >> 4, ctile = rem & 15;
    const float* ib = tab.src[s] + (long)batch * tab.sIn[s] + (long)(rtile * 64) * 1024 + ctile * 64;
    const int t = threadIdx.x, tr = t >> 4, tc = (t & 15) * 4;
    #pragma unroll
    for (int p = 0; p < 4; ++p) {
        float4 v = *(const float4*)(ib + (long)(tr + 16 * p) * 1024 + tc);
        tile[tr + 16 * p][tc + 0] = f2bf(v.x);
        tile[tr + 16 * p][tc + 1] = f2bf(v.y);
        tile[tr + 16 * p][tc + 2] = f2bf(v.z);
        tile[tr + 16 * p][tc + 3] = f2bf(v.w);
    }
    __syncthreads();
    ushort_t* ob = base + tab.dstOff[s] + (long)batch * tab.sOut[s]
                 + (long)(ctile * 64) * R + rtile * 64;
    #pragma unroll
    for (int p = 0; p < 4; ++p) {
        ushort4 v;
        v.x = tile[tc + 0][tr + 16 * p];
        v.y = tile[tc + 1][tr + 16 * p];
        v.z = tile[tc + 2][tr + 16 * p];
        v.w = tile[tc + 3][tr + 16 * p];
        *(ushort4*)(ob + (long)(tr + 16 * p) * R + tc) = v;
    }
}

// ---------------------------------------------------------------------------
// bf16 transpose: in [b][960][1024] -> out [b][1024][960]. grid (16,15,NB).
// ---------------------------------------------------------------------------
__global__ __launch_bounds__(256)
void trb_kernel(const ushort_t* __restrict__ in, ushort_t* __restrict__ out)
{
    __shared__ ushort_t tile[64][65];
    const int r0 = blockIdx.y * 64, c0 = blockIdx.x * 64;
    const long sP = (long)KVC * HWN;
    const ushort_t* ib = in + (long)blockIdx.z * sP;
    ushort_t* ob = out + (long)blockIdx.z * sP;
    const int t = threadIdx.x, tr = t >> 4, tc = (t & 15) * 4;
    #pragma unroll
    for (int p = 0; p < 4; ++p) {
        ushort4 v = *(const ushort4*)(ib + (long)(r0 + tr + 16 * p) * 1024 + c0 + tc);
        tile[tr + 16 * p][tc + 0] = v.x;
        tile[tr + 16 * p][tc + 1] = v.y;
        tile[tr + 16 * p][tc + 2] = v.z;
        tile[tr + 16 * p][tc + 3] = v.w;
    }
    __syncthreads();
    #pragma unroll
    for (int p = 0; p < 4; ++p) {
        ushort4 v;
        v.x = tile[tc + 0][tr + 16 * p];
        v.y = tile[tc + 1][tr + 16 * p];
        v.z = tile[tc + 2][tr + 16 * p];
        v.w = tile[tc + 3][tr + 16 * p];
        *(ushort4*)(ob + (long)(c0 + tr + 16 * p) * 960 + r0 + tc) = v;
    }
}

// ---------------------------------------------------------------------------
// bf16 MFMA GEMM NT + fused instnorm stats partials. BK=64.
// C[b][m][n] = alpha * sum_k A[b][m][k] * B[b][n][k]  (f32 out)
// LDS [row][64], chunk swizzle on global SOURCE (linear LDS dest, rule 21).
// ---------------------------------------------------------------------------
__global__ __launch_bounds__(256)
void mfma_gemm_nt_stats(const ushort_t* __restrict__ A, const ushort_t* __restrict__ B,
                        float* __restrict__ C, float2* __restrict__ part,
                        int M, int N, int K, long sA, long sB, long sC, float alpha)
{
    __shared__ __align__(16) ushort_t lA[128 * 64];
    __shared__ __align__(16) ushort_t lB[128 * 64];
    const ushort_t* Ab = A + (long)blockIdx.z * sA;
    const ushort_t* Bb = B + (long)blockIdx.z * sB;
    const int row0 = blockIdx.y * 128, col0 = blockIdx.x * 128;
    const int t = threadIdx.x, lane = t & 63, w = t >> 6;
    const int wr = w >> 1, wc = w & 1;
    const int arl = lane >> 3;
    const int acs = ((lane & 7) ^ arl) * 8;
    int arow[4], brow[4];
    #pragma unroll
    for (int j = 0; j < 4; ++j) {
        int r = row0 + w * 32 + j * 8 + arl;  arow[j] = r < M ? r : M - 1;
        int rb = col0 + w * 32 + j * 8 + arl; brow[j] = rb < N ? rb : N - 1;
    }

    f32x4 acc[4][4];
    #pragma unroll
    for (int m = 0; m < 4; ++m)
        #pragma unroll
        for (int n = 0; n < 4; ++n)
            acc[m][n] = (f32x4){0.f, 0.f, 0.f, 0.f};

    for (int k0 = 0; k0 < K; k0 += 64) {
        #pragma unroll
        for (int j = 0; j < 4; ++j) {
            glds16(Ab + (long)arow[j] * K + k0 + acs, lA + (w * 32 + j * 8) * 64);
            glds16(Bb + (long)brow[j] * K + k0 + acs, lB + (w * 32 + j * 8) * 64);
        }
        __syncthreads();
        #pragma unroll
        for (int sub = 0; sub < 2; ++sub) {
            const int kc = (lane >> 4) + sub * 4;
            bf16x8 aF[4], bF[4];
            #pragma unroll
            for (int m = 0; m < 4; ++m) {
                int rl = wr * 64 + m * 16 + (lane & 15);
                aF[m] = *(const bf16x8*)(lA + rl * 64 + (kc ^ (rl & 7)) * 8);
            }
            #pragma unroll
            for (int n = 0; n < 4; ++n) {
                int rl = wc * 64 + n * 16 + (lane & 15);
                bF[n] = *(const bf16x8*)(lB + rl * 64 + (kc ^ (rl & 7)) * 8);
            }
            #pragma unroll
            for (int m = 0; m < 4; ++m)
                #pragma unroll
                for (int n = 0; n < 4; ++n)
                    acc[m][n] = __builtin_amdgcn_mfma_f32_16x16x32_bf16(aF[m], bF[n], acc[m][n], 0, 0, 0);
        }
        __syncthreads();
    }

    const int cr0 = row0 + wr * 64 + (lane >> 4) * 4;
    const int cc0 = col0 + wc * 64 + (lane & 15);
    float* Cb = C + (long)blockIdx.z * sC;
    float s1 = 0.f, s2 = 0.f;
    #pragma unroll
    for (int m = 0; m < 4; ++m) {
        #pragma unroll
        for (int n = 0; n < 4; ++n) {
            int ccol = cc0 + n * 16;
            if (ccol >= N) continue;
            #pragma unroll
            for (int r = 0; r < 4; ++r) {
                int crow = cr0 + m * 16 + r;
                if (crow < M) {
                    float v = acc[m][n][r] * alpha;
                    Cb[(long)crow * N + ccol] = v;
                    s1 += v; s2 += v * v;
                }
            }
        }
    }
    #pragma unroll
    for (int off = 32; off > 0; off >>= 1) {
        s1 += __shfl_down(s1, off);
        s2 += __shfl_down(s2, off);
    }
    float* rbuf = (float*)lA;
    if (lane == 0) { rbuf[w] = s1; rbuf[4 + w] = s2; }
    __syncthreads();
    if (t == 0)
        part[(blockIdx.z * 8 + blockIdx.y) * 8 + blockIdx.x] =
            make_float2(rbuf[0] + rbuf[1] + rbuf[2] + rbuf[3],
                        rbuf[4] + rbuf[5] + rbuf[6] + rbuf[7]);
}

// ---------------------------------------------------------------------------
// Table-driven bf16 MFMA GEMM NT, BK=64, N fixed 1024 (grid.x = 8).
// C[b][m][n] = sum_k A[b][m][k] * B[b][n][k];  A lda=K, B ldb per segment.
// ---------------------------------------------------------------------------
struct NTTab {
    const ushort_t* A[5];
    const ushort_t* B[5];
    void* C[5];
    long sA[5], sB[5], sC[5], ldb[5];
    int M[5], K[5], obf[5], mt0[5];
    int nseg;
};

__global__ __launch_bounds__(256)
void mfma_gemm_nt_tab(NTTab tab)
{
    __shared__ __align__(16) ushort_t lA[128 * 64];
    __shared__ __align__(16) ushort_t lB[128 * 64];
    int si = 0;
    #pragma unroll
    for (int s = 1; s < 5; ++s)
        if (s < tab.nseg && (int)blockIdx.y >= tab.mt0[s]) si = s;
    const int M = tab.M[si], K = tab.K[si];
    const long ldb = tab.ldb[si];
    const ushort_t* Ab = tab.A[si] + (long)blockIdx.z * tab.sA[si];
    const ushort_t* Bb = tab.B[si] + (long)blockIdx.z * tab.sB[si];
    const int row0 = (blockIdx.y - tab.mt0[si]) * 128, col0 = blockIdx.x * 128;
    const int t = threadIdx.x, lane = t & 63, w = t >> 6;
    const int wr = w >> 1, wc = w & 1;
    const int arl = lane >> 3;
    const int acs = ((lane & 7) ^ arl) * 8;
    int arow[4], brow[4];
    #pragma unroll
    for (int j = 0; j < 4; ++j) {
        int r = row0 + w * 32 + j * 8 + arl;
        arow[j] = r < M ? r : M - 1;
        brow[j] = col0 + w * 32 + j * 8 + arl;   // N=1024, always valid
    }

    f32x4 acc[4][4];
    #pragma unroll
    for (int m = 0; m < 4; ++m)
        #pragma unroll
        for (int n = 0; n < 4; ++n)
            acc[m][n] = (f32x4){0.f, 0.f, 0.f, 0.f};

    for (int k0 = 0; k0 < K; k0 += 64) {
        #pragma unroll
        for (int j = 0; j < 4; ++j) {
            glds16(Ab + (long)arow[j] * K + k0 + acs, lA + (w * 32 + j * 8) * 64);
            glds16(Bb + (long)brow[j] * ldb + k0 + acs, lB + (w * 32 + j * 8) * 64);
        }
        __syncthreads();
        #pragma unroll
        for (int sub = 0; sub < 2; ++sub) {
            const int kc = (lane >> 4) + sub * 4;
            bf16x8 aF[4], bF[4];
            #pragma unroll
            for (int m = 0; m < 4; ++m) {
                int rl = wr * 64 + m * 16 + (lane & 15);
                aF[m] = *(const bf16x8*)(lA + rl * 64 + (kc ^ (rl & 7)) * 8);
            }
            #pragma unroll
            for (int n = 0; n < 4; ++n) {
                int rl = wc * 64 + n * 16 + (lane & 15);
                bF[n] = *(const bf16x8*)(lB + rl * 64 + (kc ^ (rl & 7)) * 8);
            }
            #pragma unroll
            for (int m = 0; m < 4; ++m)
                #pragma unroll
                for (int n = 0; n < 4; ++n)
                    acc[m][n] = __builtin_amdgcn_mfma_f32_16x16x32_bf16(aF[m], bF[n], acc[m][n], 0, 0, 0);
        }
        __syncthreads();
    }

    const int cr0 = row0 + wr * 64 + (lane >> 4) * 4;
    const int cc0 = col0 + wc * 64 + (lane & 15);
    const int obf = tab.obf[si];
    ushort_t* Cb_b = (ushort_t*)tab.C[si] + (long)blockIdx.z * tab.sC[si];
    float* Cb_f = (float*)tab.C[si] + (long)blockIdx.z * tab.sC[si];
    #pragma unroll
    for (int m = 0; m < 4; ++m) {
        #pragma unroll
        for (int n = 0; n < 4; ++n) {
            int ccol = cc0 + n * 16;
            #pragma unroll
            for (int r = 0; r < 4; ++r) {
                int crow = cr0 + m * 16 + r;
                if (crow < M) {
                    float v = acc[m][n][r];
                    if (obf) Cb_b[(long)crow * 1024 + ccol] = f2bf(v);
                    else     Cb_f[(long)crow * 1024 + ccol] = v;
                }
            }
        }
    }
}

// ---------------------------------------------------------------------------
// Fused stencil launch: depthwise 3x3 on Q/K/V (l2norm on Q,K) + grouped
// 3x3 conv + l2norm for all branches.
// ---------------------------------------------------------------------------
__global__ __launch_bounds__(256)
void stencil_all(const ushort_t* __restrict__ Xqkv, const ushort_t* __restrict__ mh_x,
                 const float* __restrict__ w_qc, const float* __restrict__ w_kc,
                 const float* __restrict__ w_vc,
                 const float* __restrict__ wq1, const float* __restrict__ wq2,
                 const float* __restrict__ wq3, const float* __restrict__ wq4,
                 ushort_t* __restrict__ Qc, ushort_t* __restrict__ Kc,
                 ushort_t* __restrict__ Vc, ushort_t* __restrict__ q_all)
{
    __shared__ float p0[32 * 33];
    __shared__ float p1[32 * 33];
    __shared__ float red[5];
    const int bid = blockIdx.x;
    const int t = threadIdx.x;
    const int i0 = t * 4, y = i0 >> 5, x0 = i0 & 31;

    if (bid < 23040) {
        const int which = bid / 7680;
        const int p = bid - which * 7680;
        const int b = p / 960, c = p - b * 960;
        const ushort_t* ip = Xqkv + ((long)b * 2880 + which * 960 + c) * 1024;
        const float* wgt = (which == 0 ? w_qc : which == 1 ? w_kc : w_vc) + c * 9;
        ushort_t* op = (which == 0 ? Qc : which == 1 ? Kc : Vc) + (long)p * 1024;
        ushort4 u = *(const ushort4*)(ip + i0);
        float* rw = p0 + y * 33 + x0;
        rw[0] = bf2f(u.x); rw[1] = bf2f(u.y); rw[2] = bf2f(u.z); rw[3] = bf2f(u.w);
        __syncthreads();
        float W[9];
        #pragma unroll
        for (int q = 0; q < 9; ++q) W[q] = wgt[q];
        float r[3][6];
        #pragma unroll
        for (int dy = 0; dy < 3; ++dy) {
            int yy = y + dy - 1;
            bool vy = (unsigned)yy < 32u;
            #pragma unroll
            for (int j = 0; j < 6; ++j) {
                int xx = x0 - 1 + j;
                r[dy][j] = (vy && (unsigned)xx < 32u) ? p0[yy * 33 + xx] : 0.f;
            }
        }
        float o[4];
        #pragma unroll
        for (int q = 0; q < 4; ++q)
            o[q] = r[0][q] * W[0] + r[0][q + 1] * W[1] + r[0][q + 2] * W[2]
                 + r[1][q] * W[3] + r[1][q + 1] * W[4] + r[1][q + 2] * W[5]
                 + r[2][q] * W[6] + r[2][q + 1] * W[7] + r[2][q + 2] * W[8];
        float inv = 1.f;
        if (which < 2) {
            float s = o[0] * o[0] + o[1] * o[1] + o[2] * o[2] + o[3] * o[3];
            #pragma unroll
            for (int off = 32; off > 0; off >>= 1) s += __shfl_down(s, off);
            if ((t & 63) == 0) red[t >> 6] = s;
            __syncthreads();
            if (t == 0) red[4] = 1.0f / fmaxf(sqrtf(red[0] + red[1] + red[2] + red[3]), 1e-12f);
            __syncthreads();
            inv = red[4];
        }
        *(ushort4*)(op + i0) =
            make_ushort4(f2bf(o[0] * inv), f2bf(o[1] * inv), f2bf(o[2] * inv), f2bf(o[3] * inv));
        return;
    }
    const int po = bid - 23040;
    const int o = po & 1023, b = po >> 10;
    ushort_t* op = q_all + (long)po * 1024;
    int off; const float* wbase;
    if (o < 64)       { off = 0;   wbase = wq1; }
    else if (o < 128) { *(ushort4*)(op + i0) = make_ushort4(0, 0, 0, 0); return; }
    else if (o < 256) { off = 128; wbase = wq2; }
    else if (o < 512) { off = 256; wbase = wq3; }
    else              { off = 512; wbase = wq4; }
    const int ol = o - off;
    const int g2 = ol & ~1;
    const ushort_t* ip0 = mh_x + ((long)(b << 10) + off + g2) * 1024;
    const ushort_t* ip1 = ip0 + 1024;
    ushort4 u0 = *(const ushort4*)(ip0 + i0);
    ushort4 u1 = *(const ushort4*)(ip1 + i0);
    float* r0w = p0 + y * 33 + x0;
    float* r1w = p1 + y * 33 + x0;
    r0w[0] = bf2f(u0.x); r0w[1] = bf2f(u0.y); r0w[2] = bf2f(u0.z); r0w[3] = bf2f(u0.w);
    r1w[0] = bf2f(u1.x); r1w[1] = bf2f(u1.y); r1w[2] = bf2f(u1.z); r1w[3] = bf2f(u1.w);
    __syncthreads();
    const float* wp = wbase + ol * 18;
    float W[18];
    #pragma unroll
    for (int q = 0; q < 18; ++q) W[q] = wp[q];
    float o4[4] = {0.f, 0.f, 0.f, 0.f};
    #pragma unroll
    for (int pl = 0; pl < 2; ++pl) {
        const float* src = pl ? p1 : p0;
        const float* Wp = W + pl * 9;
        float r[3][6];
        #pragma unroll
        for (int dy = 0; dy < 3; ++dy) {
            int yy = y + dy - 1;
            bool vy = (unsigned)yy < 32u;
            #pragma unroll
            for (int j = 0; j < 6; ++j) {
                int xx = x0 - 1 + j;
                r[dy][j] = (vy && (unsigned)xx < 32u) ? src[yy * 33 + xx] : 0.f;
            }
        }
        #pragma unroll
        for (int q = 0; q < 4; ++q)
            o4[q] += r[0][q] * Wp[0] + r[0][q + 1] * Wp[1] + r[0][q + 2] * Wp[2]
                   + r[1][q] * Wp[3] + r[1][q + 1] * Wp[4] + r[1][q + 2] * Wp[5]
                   + r[2][q] * Wp[6] + r[2][q + 1] * Wp[7] + r[2][q + 2] * Wp[8];
    }
    float s = o4[0] * o4[0] + o4[1] * o4[1] + o4[2] * o4[2] + o4[3] * o4[3];
    #pragma unroll
    for (int off2 = 32; off2 > 0; off2 >>= 1) s += __shfl_down(s, off2);
    if ((t & 63) == 0) red[t >> 6] = s;
    __syncthreads();
    if (t == 0) red[4] = 1.0f / fmaxf(sqrtf(red[0] + red[1] + red[2] + red[3]), 1e-12f);
    __syncthreads();
    float inv = red[4];
    *(ushort4*)(op + i0) =
        make_ushort4(f2bf(o4[0] * inv), f2bf(o4[1] * inv), f2bf(o4[2] * inv), f2bf(o4[3] * inv));
}

// ---------------------------------------------------------------------------
// Stats reduces
// ---------------------------------------------------------------------------
__global__ void reduce_sim(const float2* __restrict__ part, float2* __restrict__ stats)
{
    float2 p = part[blockIdx.x * 64 + threadIdx.x];
    float s1 = p.x, s2 = p.y;
    #pragma unroll
    for (int off = 32; off > 0; off >>= 1) {
        s1 += __shfl_down(s1, off);
        s2 += __shfl_down(s2, off);
    }
    if (threadIdx.x == 0) stats[blockIdx.x] = make_float2(s1, s2);
}

__global__ void reduce_branch(const float2* __restrict__ part, float2* __restrict__ stats)
{
    const int br = blockIdx.x & 3, b = blockIdx.x >> 2;
    const int lo4[4] = {0, 1, 2, 4}, hi4[4] = {1, 2, 4, 8};
    float s1 = 0.f, s2 = 0.f;
    if (threadIdx.x < 8) {
        for (int my = lo4[br]; my < hi4[br]; ++my) {
            float2 p = part[(b * 8 + my) * 8 + threadIdx.x];
            s1 += p.x; s2 += p.y;
        }
    }
    #pragma unroll
    for (int off = 32; off > 0; off >>= 1) {
        s1 += __shfl_down(s1, off);
        s2 += __shfl_down(s2, off);
    }
    if (threadIdx.x == 0) stats[b * 4 + br] = make_float2(s1, s2);
}

// ---------------------------------------------------------------------------
// Instance-norm + softmax (row length 960), f32 in -> bf16 out (sim path).
// ---------------------------------------------------------------------------
__global__ __launch_bounds__(256)
void instnorm_softmax_bf16(const float* __restrict__ x, ushort_t* __restrict__ out,
                           const float2* __restrict__ stats, int rowsPerB, float invL)
{
    int row = blockIdx.x;
    int b = row / rowsPerB;
    float2 st = stats[b];
    float mean = st.x * invL;
    float var = st.y * invL - mean * mean;
    float rinv = rsqrtf(var + 1e-5f);
    const float* xr = x + (long)row * 960;
    ushort_t* orow = out + (long)row * 960;
    int t = threadIdx.x;
    float v[4];
    float mx = -1e30f;
    #pragma unroll
    for (int q = 0; q < 4; ++q) {
        int i = t + q * 256;
        if (i < 960) { v[q] = (xr[i] - mean) * rinv; mx = fmaxf(mx, v[q]); }
        else v[q] = -1e30f;
    }
    #pragma unroll
    for (int off = 32; off > 0; off >>= 1) mx = fmaxf(mx, __shfl_down(mx, off));
    __shared__ float rm[4];
    __shared__ float bmax, bsuminv;
    if ((t & 63) == 0) rm[t >> 6] = mx;
    __syncthreads();
    if (t == 0) bmax = fmaxf(fmaxf(rm[0], rm[1]), fmaxf(rm[2], rm[3]));
    __syncthreads();
    float mall = bmax;
    float s = 0.f;
    #pragma unroll
    for (int q = 0; q < 4; ++q) {
        int i = t + q * 256;
        if (i < 960) { v[q] = __expf(v[q] - mall); s += v[q]; }
    }
    #pragma unroll
    for (int off = 32; off > 0; off >>= 1) s += __shfl_down(s, off);
    if ((t & 63) == 0) rm[t >> 6] = s;
    __syncthreads();
    if (t == 0) bsuminv = 1.0f / (rm[0] + rm[1] + rm[2] + rm[3]);
    __syncthreads();
    float invS = bsuminv;
    #pragma unroll
    for (int q = 0; q < 4; ++q) {
        int i = t + q * 256;
        if (i < 960) orow[i] = f2bf(v[q] * invS);
    }
}

// ---------------------------------------------------------------------------
// Batched branch instnorm+softmax: rows [b][1024][960]; pad rows -> zeros.
// ---------------------------------------------------------------------------
__global__ __launch_bounds__(256)
void softmax_attn_kernel(const float* __restrict__ x, ushort_t* __restrict__ P,
                         const float2* __restrict__ stats)
{
    const int r = blockIdx.x & 1023, b = blockIdx.x >> 10;
    const int t = threadIdx.x;
    ushort_t* orow = P + ((long)(b << 10) + r) * 960;
    int br; float cnt;
    if (r < 64)       { br = 0; cnt = 64.f; }
    else if (r < 128) {
        #pragma unroll
        for (int q = 0; q < 4; ++q) {
            int i = t + q * 256;
            if (i < 960) orow[i] = 0;
        }
        return;
    }
    else if (r < 256) { br = 1; cnt = 128.f; }
    else if (r < 512) { br = 2; cnt = 256.f; }
    else              { br = 3; cnt = 512.f; }
    float invL = 1.0f / (cnt * 960.f);
    float2 st = stats[b * 4 + br];
    float mean = st.x * invL;
    float var = st.y * invL - mean * mean;
    float rinv = rsqrtf(var + 1e-5f);
    const float* xr = x + ((long)(b << 10) + r) * 960;
    float v[4];
    float mx = -1e30f;
    #pragma unroll
    for (int q = 0; q < 4; ++q) {
        int i = t + q * 256;
        if (i < 960) { v[q] = (xr[i] - mean) * rinv; mx = fmaxf(mx, v[q]); }
        else v[q] = -1e30f;
    }
    #pragma unroll
    for (int off = 32; off > 0; off >>= 1) mx = fmaxf(mx, __shfl_down(mx, off));
    __shared__ float rm[4];
    __shared__ float bmax, bsuminv;
    if ((t & 63) == 0) rm[t >> 6] = mx;
    __syncthreads();
    if (t == 0) bmax = fmaxf(fmaxf(rm[0], rm[1]), fmaxf(rm[2], rm[3]));
    __syncthreads();
    float mall = bmax;
    float s = 0.f;
    #pragma unroll
    for (int q = 0; q < 4; ++q) {
        int i = t + q * 256;
        if (i < 960) { v[q] = __expf(v[q] - mall); s += v[q]; }
    }
    #pragma unroll
    for (int off = 32; off > 0; off >>= 1) s += __shfl_down(s, off);
    if ((t & 63) == 0) rm[t >> 6] = s;
    __syncthreads();
    if (t == 0) bsuminv = 1.0f / (rm[0] + rm[1] + rm[2] + rm[3]);
    __syncthreads();
    float invS = bsuminv;
    #pragma unroll
    for (int q = 0; q < 4; ++q) {
        int i = t + q * 256;
        if (i < 960) orow[i] = f2bf(v[q] * invS);
    }
}

// ---------------------------------------------------------------------------

extern "C" void kernel_launch(void* const* d_in, const int* in_sizes, int n_in,
                              void* d_out, int out_size, void* d_ws, size_t ws_size,
                              hipStream_t stream)
{
    const float* emb[4]  = {(const float*)d_in[0], (const float*)d_in[1],
                            (const float*)d_in[2], (const float*)d_in[3]};
    const float* emb_all = (const float*)d_in[4];
    const float* w_mh[4] = {(const float*)d_in[5], (const float*)d_in[6],
                            (const float*)d_in[7], (const float*)d_in[8]};
    const float* w_mq = (const float*)d_in[9];
    const float* w_mk = (const float*)d_in[10];
    const float* w_mv = (const float*)d_in[11];
    const float* w_q[4] = {(const float*)d_in[12], (const float*)d_in[13],
                           (const float*)d_in[14], (const float*)d_in[15]};
    const float* w_qc = (const float*)d_in[16];
    const float* w_kc = (const float*)d_in[17];
    const float* w_vc = (const float*)d_in[18];
    const float* w_proj[4] = {(const float*)d_in[19], (const float*)d_in[20],
                              (const float*)d_in[21], (const float*)d_in[22]};
    float* out = (float*)d_out;

    // ---- arena (element offsets into ushort_t* U) ----
    ushort_t* U = (ushort_t*)d_ws;
    const long eWQKV = 0;          // 2,764,800  (WQ|WK|WV, k-contig rows)
    const long eWMH  = 2764800;    // 348,160
    const long eWPJ  = 3112960;    // 348,160
    const long eR1   = 3461120;    // embT_all -> Vc -> ctx       (7,864,320)
    const long eR2   = 11325440;   // embT_i  -> VcT -> ctxT      (7,864,320)
    const long eR3   = 19189760;   // Xqkv (23,592,960) -> S6 f32(15,728,640 us) + Pc -> oT
    const long ePc   = 34918400;   // Pc (7,372,800) ends 42,291,200
    const long eR4   = 42782720;   // mh_x -> P_all               (8,388,608)
    const long eQc   = 51171328;   // Qc (7,864,320)
    const long eKc   = 59035648;   // Kc (7,864,320)
    const long eQall = 66899968;   // q_all (8,388,608) ends 75,288,576
    float2* part  = (float2*)(U + 75288576);
    float2* stats = part + 512;

    ushort_t* WQKVb = U + eWQKV;
    ushort_t* WMHb  = U + eWMH;
    ushort_t* WPJb  = U + eWPJ;
    ushort_t* embT_all = U + eR1;
    ushort_t* Vc    = U + eR1;
    ushort_t* ctx   = U + eR1;
    ushort_t* VcT   = U + eR2;
    ushort_t* ctxT  = U + eR2;
    ushort_t* Xqkv  = U + eR3;
    float*    S6    = (float*)(U + eR3);
    ushort_t* oT    = U + eR3;
    ushort_t* Pc    = U + ePc;
    ushort_t* mh_x  = U + eR4;
    ushort_t* P_all = U + eR4;
    ushort_t* QcB   = U + eQc;
    ushort_t* KcB   = U + eKc;
    ushort_t* q_all = U + eQall;
    ushort_t* embT_i[4] = {U + eR2, U + eR2 + 524288, U + eR2 + 1572864, U + eR2 + 3670016};

    const float scale = 0.0322748612183951400f;   // 1/sqrt(960)
    const long SB = (long)KVC * HWN;              // 983040
    const long S1024 = 1024L * 1024;
    const int CH[4] = {64, 128, 256, 512};
    const int mhoff[4] = {0, 4096, 20480, 86016};
    const int rowOff[4] = {0, 128, 256, 512};
    const long outOff[4] = {0, 524288, 1572864, 3670016};
    dim3 blk(256);

    // ---- f2b weights (plain) ----
    {
        F2BTab tf;
        const float* fs[11] = {w_mq, w_mk, w_mv, w_mh[0], w_mh[1], w_mh[2], w_mh[3],
                               w_proj[0], w_proj[1], w_proj[2], w_proj[3]};
        long fd[11] = {eWQKV, eWQKV + 921600, eWQKV + 1843200,
                       eWMH + 0, eWMH + 4096, eWMH + 20480, eWMH + 86016,
                       eWPJ + 0, eWPJ + 4096, eWPJ + 20480, eWPJ + 86016};
        int fn[11] = {900, 900, 900, 4, 16, 64, 256, 4, 16, 64, 256};
        int ftot = 0;
        for (int i = 0; i < 11; ++i) { tf.src[i] = fs[i]; tf.dstOff[i] = fd[i]; tf.nblk[i] = fn[i]; ftot += fn[i]; }
        tf.nseg = 11;
        f2b_batched<<<ftot, blk, 0, stream>>>(tf, U);
    }
    // ---- f2bT embeddings (transpose-convert) ----
    {
        F2TTab tt;
        const float* ts[5] = {emb_all, emb[0], emb[1], emb[2], emb[3]};
        long td[5] = {eR1, eR2, eR2 + 524288, eR2 + 1572864, eR2 + 3670016};
        int tR[5] = {960, 64, 128, 256, 512};
        int tn[5];
        long tsi[5], tso[5];
        int ttot = 0;
        for (int i = 0; i < 5; ++i) {
            tsi[i] = (long)tR[i] * 1024; tso[i] = tsi[i];
            tn[i] = NB * (tR[i] / 64) * 16; ttot += tn[i];
            tt.src[i] = ts[i]; tt.dstOff[i] = td[i]; tt.R[i] = tR[i];
            tt.sIn[i] = tsi[i]; tt.sOut[i] = tso[i]; tt.nblk[i] = tn[i];
        }
        tt.nseg = 5;
        f2bt_batched<<<ttot, blk, 0, stream>>>(tt, U);
    }

    auto nt1 = [&](const ushort_t* A, long sA, const ushort_t* B, long sB, long ldb,
                   void* C, long sC, int M, int K, int obf) {
        NTTab tb;
        for (int s = 0; s < 5; ++s) {
            tb.A[s] = A; tb.B[s] = B; tb.C[s] = C;
            tb.sA[s] = sA; tb.sB[s] = sB; tb.sC[s] = sC; tb.ldb[s] = ldb;
            tb.M[s] = M; tb.K[s] = K; tb.obf[s] = obf; tb.mt0[s] = (s == 0) ? 0 : (1 << 30);
        }
        tb.nseg = 1;
        dim3 g(8, (M + 127) / 128, NB);
        mfma_gemm_nt_tab<<<g, blk, 0, stream>>>(tb);
    };

    // ---- stage 1: QKV (M=2880) + 4x mhead conv1x1, one NT launch ----
    {
        NTTab tb;
        tb.A[0] = WQKVb; tb.B[0] = embT_all; tb.C[0] = Xqkv;
        tb.sA[0] = 0; tb.sB[0] = SB; tb.sC[0] = 2880L * 1024; tb.ldb[0] = 960;
        tb.M[0] = 2880; tb.K[0] = 960; tb.obf[0] = 1; tb.mt0[0] = 0;
        int mt = 23;
        for (int i = 0; i < 4; ++i) {
            tb.A[1 + i] = WMHb + mhoff[i]; tb.B[1 + i] = embT_i[i];
            tb.C[1 + i] = mh_x + (long)rowOff[i] * 1024;
            tb.sA[1 + i] = 0; tb.sB[1 + i] = (long)CH[i] * 1024; tb.sC[1 + i] = S1024;
            tb.ldb[1 + i] = CH[i];
            tb.M[1 + i] = CH[i]; tb.K[1 + i] = CH[i]; tb.obf[1 + i] = 1; tb.mt0[1 + i] = mt;
            mt += (CH[i] + 127) / 128;
        }
        tb.nseg = 5;
        dim3 g(8, mt, NB);   // (8, 31, 8)
        mfma_gemm_nt_tab<<<g, blk, 0, stream>>>(tb);
    }

    // ---- stencils: dw(Q,K,V) + gconv, one launch ----
    stencil_all<<<31232, blk, 0, stream>>>(Xqkv, mh_x, w_qc, w_kc, w_vc,
                                           w_q[0], w_q[1], w_q[2], w_q[3],
                                           QcB, KcB, Vc, q_all);

    // ---- Vc -> VcT ----
    trb_kernel<<<dim3(16, 15, NB), blk, 0, stream>>>(Vc, VcT);

    // ---- sim = Qc @ Kc^T * scale + stats ----
    mfma_gemm_nt_stats<<<dim3(8, 8, NB), blk, 0, stream>>>(
        QcB, KcB, S6, part, KVC, KVC, HWN, SB, SB, (long)KVC * KVC, scale);
    reduce_sim<<<NB, 64, 0, stream>>>(part, stats);
    instnorm_softmax_bf16<<<NB * KVC, blk, 0, stream>>>(S6, Pc, stats, KVC,
                                                        1.f / ((float)KVC * (float)KVC));

    // ---- ctx = NT(Pc, VcT) -> [960][1024] bf16 ----
    nt1(Pc, (long)KVC * KVC, VcT, SB, 960, ctx, SB, KVC, KVC, 1);

    // ---- ctx -> ctxT ----
    trb_kernel<<<dim3(16, 15, NB), blk, 0, stream>>>(ctx, ctxT);

    // ---- attn = q_all @ ctx^T * scale + stats ----
    mfma_gemm_nt_stats<<<dim3(8, 8, NB), blk, 0, stream>>>(
        q_all, ctx, S6, part, 1024, KVC, HWN, S1024, SB, SB, scale);
    reduce_branch<<<32, 64, 0, stream>>>(part, stats);
    softmax_attn_kernel<<<NB * 1024, blk, 0, stream>>>(S6, P_all, stats);

    // ---- oT = NT(ctxT, P_all) -> [1024 hw][1024 ch] bf16 ----
    nt1(ctxT, SB, P_all, SB, 960, oT, S1024, 1024, KVC, 1);

    // ---- proj: 4 branches, one NT table launch (f32 out) ----
    {
        NTTab tb;
        int mt = 0;
        for (int i = 0; i < 4; ++i) {
            tb.A[i] = WPJb + mhoff[i]; tb.B[i] = oT + rowOff[i];
            tb.C[i] = out + outOff[i];
            tb.sA[i] = 0; tb.sB[i] = S1024; tb.sC[i] = (long)CH[i] * 1024;
            tb.ldb[i] = 1024;
            tb.M[i] = CH[i]; tb.K[i] = CH[i]; tb.obf[i] = 0; tb.mt0[i] = mt;
            mt += (CH[i] + 127) / 128;
        }
        tb.A[4] = tb.A[3]; tb.B[4] = tb.B[3]; tb.C[4] = tb.C[3];
        tb.sA[4] = 0; tb.sB[4] = 0; tb.sC[4] = 0; tb.ldb[4] = 1024;
        tb.M[4] = 1; tb.K[4] = 64; tb.obf[4] = 0; tb.mt0[4] = 1 << 30;
        tb.nseg = 4;
        dim3 g(8, mt, NB);   // (8, 8, 8)
        mfma_gemm_nt_tab<<<g, blk, 0, stream>>>(tb);
    }

    (void)in_sizes; (void)n_in; (void)out_size; (void)ws_size;
}

// Round 6
// 320.507 us; speedup vs baseline: 6.9175x; 1.0324x over previous
//
#include <hip/hip_runtime.h>
#include <hip/hip_bf16.h>
#include <math.h>

#define NB 8
#define HWN 1024
#define KVC 960

typedef short bf16x8 __attribute__((ext_vector_type(8)));
typedef float f32x4 __attribute__((ext_vector_type(4)));
typedef unsigned short ushort_t;

__device__ inline ushort_t f2bf(float f) {
    __hip_bfloat16 h = __float2bfloat16(f);
    return *reinterpret_cast<ushort_t*>(&h);
}
__device__ inline float bf2f(ushort_t u) {
    union { float f; unsigned int i; } x; x.i = ((unsigned int)u) << 16; return x.f;
}
__device__ inline void glds16(const ushort_t* src, ushort_t* dst) {
    __builtin_amdgcn_global_load_lds(
        (const __attribute__((address_space(1))) void*)src,
        (__attribute__((address_space(3))) void*)dst, 16, 0, 0);
}

// ---------------------------------------------------------------------------
// Batched f32 -> bf16 convert (no transpose). 1024 elems per block.
// ---------------------------------------------------------------------------
struct F2BTab {
    const float* src[12];
    long dstOff[12];
    int nblk[12];
    int nseg;
};

__global__ __launch_bounds__(256)
void f2b_batched(F2BTab tab, ushort_t* base)
{
    int b = blockIdx.x, s = 0;
    while (s < tab.nseg - 1 && b >= tab.nblk[s]) { b -= tab.nblk[s]; ++s; }
    float4 v = *((const float4*)tab.src[s] + (long)b * 256 + threadIdx.x);
    ushort4 o = make_ushort4(f2bf(v.x), f2bf(v.y), f2bf(v.z), f2bf(v.w));
    *((ushort4*)(base + tab.dstOff[s]) + (long)b * 256 + threadIdx.x) = o;
}

// ---------------------------------------------------------------------------
// Batched f32 -> bf16 transpose-convert: in [b][R][1024] f32 -> out [b][1024][R].
// ---------------------------------------------------------------------------
struct F2TTab {
    const float* src[5];
    long dstOff[5];
    long sIn[5], sOut[5];
    int R[5];
    int nblk[5];
    int nseg;
};

__global__ __launch_bounds__(256)
void f2bt_batched(F2TTab tab, ushort_t* base)
{
    __shared__ ushort_t tile[64][65];
    int b = blockIdx.x, s = 0;
    while (s < tab.nseg - 1 && b >= tab.nblk[s]) { b -= tab.nblk[s]; ++s; }
    const int R = tab.R[s];
    const int tpb = (R >> 6) * 16;
    const int batch = b / tpb, rem = b - batch * tpb;
    const int rtile = rem >> 4, ctile = rem & 15;
    const float* ib = tab.src[s] + (long)batch * tab.sIn[s] + (long)(rtile * 64) * 1024 + ctile * 64;
    const int t = threadIdx.x, tr = t >> 4, tc = (t & 15) * 4;
    #pragma unroll
    for (int p = 0; p < 4; ++p) {
        float4 v = *(const float4*)(ib + (long)(tr + 16 * p) * 1024 + tc);
        tile[tr + 16 * p][tc + 0] = f2bf(v.x);
        tile[tr + 16 * p][tc + 1] = f2bf(v.y);
        tile[tr + 16 * p][tc + 2] = f2bf(v.z);
        tile[tr + 16 * p][tc + 3] = f2bf(v.w);
    }
    __syncthreads();
    ushort_t* ob = base + tab.dstOff[s] + (long)batch * tab.sOut[s]
                 + (long)(ctile * 64) * R + rtile * 64;
    #pragma unroll
    for (int p = 0; p < 4; ++p) {
        ushort4 v;
        v.x = tile[tc + 0][tr + 16 * p];
        v.y = tile[tc + 1][tr + 16 * p];
        v.z = tile[tc + 2][tr + 16 * p];
        v.w = tile[tc + 3][tr + 16 * p];
        *(ushort4*)(ob + (long)(tr + 16 * p) * R + tc) = v;
    }
}

// ---------------------------------------------------------------------------
// bf16 transpose: in [b][960][1024] -> out [b][1024][960]. grid (16,15,NB).
// ---------------------------------------------------------------------------
__global__ __launch_bounds__(256)
void trb_kernel(const ushort_t* __restrict__ in, ushort_t* __restrict__ out)
{
    __shared__ ushort_t tile[64][65];
    const int r0 = blockIdx.y * 64, c0 = blockIdx.x * 64;
    const long sP = (long)KVC * HWN;
    const ushort_t* ib = in + (long)blockIdx.z * sP;
    ushort_t* ob = out + (long)blockIdx.z * sP;
    const int t = threadIdx.x, tr = t >> 4, tc = (t & 15) * 4;
    #pragma unroll
    for (int p = 0; p < 4; ++p) {
        ushort4 v = *(const ushort4*)(ib + (long)(r0 + tr + 16 * p) * 1024 + c0 + tc);
        tile[tr + 16 * p][tc + 0] = v.x;
        tile[tr + 16 * p][tc + 1] = v.y;
        tile[tr + 16 * p][tc + 2] = v.z;
        tile[tr + 16 * p][tc + 3] = v.w;
    }
    __syncthreads();
    #pragma unroll
    for (int p = 0; p < 4; ++p) {
        ushort4 v;
        v.x = tile[tc + 0][tr + 16 * p];
        v.y = tile[tc + 1][tr + 16 * p];
        v.z = tile[tc + 2][tr + 16 * p];
        v.w = tile[tc + 3][tr + 16 * p];
        *(ushort4*)(ob + (long)(c0 + tr + 16 * p) * 960 + r0 + tc) = v;
    }
}

// ---------------------------------------------------------------------------
// bf16 MFMA GEMM NT + fused instnorm stats partials. BK=64.
// XCD-affinity grid: blockIdx.x = BATCH (linear%8 -> XCD), y = M-tile,
// z = N-tile. grid (NB, 8, 8).
// ---------------------------------------------------------------------------
__global__ __launch_bounds__(256)
void mfma_gemm_nt_stats(const ushort_t* __restrict__ A, const ushort_t* __restrict__ B,
                        float* __restrict__ C, float2* __restrict__ part,
                        int M, int N, int K, long sA, long sB, long sC, float alpha)
{
    __shared__ __align__(16) ushort_t lA[128 * 64];
    __shared__ __align__(16) ushort_t lB[128 * 64];
    const int bb = blockIdx.x;           // batch -> XCD
    const int by = blockIdx.y, bx = blockIdx.z;
    const ushort_t* Ab = A + (long)bb * sA;
    const ushort_t* Bb = B + (long)bb * sB;
    const int row0 = by * 128, col0 = bx * 128;
    const int t = threadIdx.x, lane = t & 63, w = t >> 6;
    const int wr = w >> 1, wc = w & 1;
    const int arl = lane >> 3;
    const int acs = ((lane & 7) ^ arl) * 8;
    int arow[4], brow[4];
    #pragma unroll
    for (int j = 0; j < 4; ++j) {
        int r = row0 + w * 32 + j * 8 + arl;  arow[j] = r < M ? r : M - 1;
        int rb = col0 + w * 32 + j * 8 + arl; brow[j] = rb < N ? rb : N - 1;
    }

    f32x4 acc[4][4];
    #pragma unroll
    for (int m = 0; m < 4; ++m)
        #pragma unroll
        for (int n = 0; n < 4; ++n)
            acc[m][n] = (f32x4){0.f, 0.f, 0.f, 0.f};

    for (int k0 = 0; k0 < K; k0 += 64) {
        #pragma unroll
        for (int j = 0; j < 4; ++j) {
            glds16(Ab + (long)arow[j] * K + k0 + acs, lA + (w * 32 + j * 8) * 64);
            glds16(Bb + (long)brow[j] * K + k0 + acs, lB + (w * 32 + j * 8) * 64);
        }
        __syncthreads();
        #pragma unroll
        for (int sub = 0; sub < 2; ++sub) {
            const int kc = (lane >> 4) + sub * 4;
            bf16x8 aF[4], bF[4];
            #pragma unroll
            for (int m = 0; m < 4; ++m) {
                int rl = wr * 64 + m * 16 + (lane & 15);
                aF[m] = *(const bf16x8*)(lA + rl * 64 + (kc ^ (rl & 7)) * 8);
            }
            #pragma unroll
            for (int n = 0; n < 4; ++n) {
                int rl = wc * 64 + n * 16 + (lane & 15);
                bF[n] = *(const bf16x8*)(lB + rl * 64 + (kc ^ (rl & 7)) * 8);
            }
            #pragma unroll
            for (int m = 0; m < 4; ++m)
                #pragma unroll
                for (int n = 0; n < 4; ++n)
                    acc[m][n] = __builtin_amdgcn_mfma_f32_16x16x32_bf16(aF[m], bF[n], acc[m][n], 0, 0, 0);
        }
        __syncthreads();
    }

    const int cr0 = row0 + wr * 64 + (lane >> 4) * 4;
    const int cc0 = col0 + wc * 64 + (lane & 15);
    float* Cb = C + (long)bb * sC;
    float s1 = 0.f, s2 = 0.f;
    #pragma unroll
    for (int m = 0; m < 4; ++m) {
        #pragma unroll
        for (int n = 0; n < 4; ++n) {
            int ccol = cc0 + n * 16;
            if (ccol >= N) continue;
            #pragma unroll
            for (int r = 0; r < 4; ++r) {
                int crow = cr0 + m * 16 + r;
                if (crow < M) {
                    float v = acc[m][n][r] * alpha;
                    Cb[(long)crow * N + ccol] = v;
                    s1 += v; s2 += v * v;
                }
            }
        }
    }
    #pragma unroll
    for (int off = 32; off > 0; off >>= 1) {
        s1 += __shfl_down(s1, off);
        s2 += __shfl_down(s2, off);
    }
    float* rbuf = (float*)lA;
    if (lane == 0) { rbuf[w] = s1; rbuf[4 + w] = s2; }
    __syncthreads();
    if (t == 0)
        part[(bb * 8 + by) * 8 + bx] =
            make_float2(rbuf[0] + rbuf[1] + rbuf[2] + rbuf[3],
                        rbuf[4] + rbuf[5] + rbuf[6] + rbuf[7]);
}

// ---------------------------------------------------------------------------
// Table-driven bf16 MFMA GEMM NT, BK=64, N fixed 1024.
// XCD-affinity grid: blockIdx.x = BATCH, y = segmented M-tile, z = N-tile(8).
// ---------------------------------------------------------------------------
struct NTTab {
    const ushort_t* A[5];
    const ushort_t* B[5];
    void* C[5];
    long sA[5], sB[5], sC[5], ldb[5];
    int M[5], K[5], obf[5], mt0[5];
    int nseg;
};

__global__ __launch_bounds__(256)
void mfma_gemm_nt_tab(NTTab tab)
{
    __shared__ __align__(16) ushort_t lA[128 * 64];
    __shared__ __align__(16) ushort_t lB[128 * 64];
    const int bb = blockIdx.x;           // batch -> XCD
    int si = 0;
    #pragma unroll
    for (int s = 1; s < 5; ++s)
        if (s < tab.nseg && (int)blockIdx.y >= tab.mt0[s]) si = s;
    const int M = tab.M[si], K = tab.K[si];
    const long ldb = tab.ldb[si];
    const ushort_t* Ab = tab.A[si] + (long)bb * tab.sA[si];
    const ushort_t* Bb = tab.B[si] + (long)bb * tab.sB[si];
    const int row0 = (blockIdx.y - tab.mt0[si]) * 128, col0 = blockIdx.z * 128;
    const int t = threadIdx.x, lane = t & 63, w = t >> 6;
    const int wr = w >> 1, wc = w & 1;
    const int arl = lane >> 3;
    const int acs = ((lane & 7) ^ arl) * 8;
    int arow[4], brow[4];
    #pragma unroll
    for (int j = 0; j < 4; ++j) {
        int r = row0 + w * 32 + j * 8 + arl;
        arow[j] = r < M ? r : M - 1;
        brow[j] = col0 + w * 32 + j * 8 + arl;   // N=1024, always valid
    }

    f32x4 acc[4][4];
    #pragma unroll
    for (int m = 0; m < 4; ++m)
        #pragma unroll
        for (int n = 0; n < 4; ++n)
            acc[m][n] = (f32x4){0.f, 0.f, 0.f, 0.f};

    for (int k0 = 0; k0 < K; k0 += 64) {
        #pragma unroll
        for (int j = 0; j < 4; ++j) {
            glds16(Ab + (long)arow[j] * K + k0 + acs, lA + (w * 32 + j * 8) * 64);
            glds16(Bb + (long)brow[j] * ldb + k0 + acs, lB + (w * 32 + j * 8) * 64);
        }
        __syncthreads();
        #pragma unroll
        for (int sub = 0; sub < 2; ++sub) {
            const int kc = (lane >> 4) + sub * 4;
            bf16x8 aF[4], bF[4];
            #pragma unroll
            for (int m = 0; m < 4; ++m) {
                int rl = wr * 64 + m * 16 + (lane & 15);
                aF[m] = *(const bf16x8*)(lA + rl * 64 + (kc ^ (rl & 7)) * 8);
            }
            #pragma unroll
            for (int n = 0; n < 4; ++n) {
                int rl = wc * 64 + n * 16 + (lane & 15);
                bF[n] = *(const bf16x8*)(lB + rl * 64 + (kc ^ (rl & 7)) * 8);
            }
            #pragma unroll
            for (int m = 0; m < 4; ++m)
                #pragma unroll
                for (int n = 0; n < 4; ++n)
                    acc[m][n] = __builtin_amdgcn_mfma_f32_16x16x32_bf16(aF[m], bF[n], acc[m][n], 0, 0, 0);
        }
        __syncthreads();
    }

    const int cr0 = row0 + wr * 64 + (lane >> 4) * 4;
    const int cc0 = col0 + wc * 64 + (lane & 15);
    const int obf = tab.obf[si];
    ushort_t* Cb_b = (ushort_t*)tab.C[si] + (long)bb * tab.sC[si];
    float* Cb_f = (float*)tab.C[si] + (long)bb * tab.sC[si];
    #pragma unroll
    for (int m = 0; m < 4; ++m) {
        #pragma unroll
        for (int n = 0; n < 4; ++n) {
            int ccol = cc0 + n * 16;
            #pragma unroll
            for (int r = 0; r < 4; ++r) {
                int crow = cr0 + m * 16 + r;
                if (crow < M) {
                    float v = acc[m][n][r];
                    if (obf) Cb_b[(long)crow * 1024 + ccol] = f2bf(v);
                    else     Cb_f[(long)crow * 1024 + ccol] = v;
                }
            }
        }
    }
}

// ---------------------------------------------------------------------------
// Fused stencil launch: depthwise 3x3 on Q/K/V (l2norm on Q,K) + grouped
// 3x3 conv + l2norm for all branches.
// ---------------------------------------------------------------------------
__global__ __launch_bounds__(256)
void stencil_all(const ushort_t* __restrict__ Xqkv, const ushort_t* __restrict__ mh_x,
                 const float* __restrict__ w_qc, const float* __restrict__ w_kc,
                 const float* __restrict__ w_vc,
                 const float* __restrict__ wq1, const float* __restrict__ wq2,
                 const float* __restrict__ wq3, const float* __restrict__ wq4,
                 ushort_t* __restrict__ Qc, ushort_t* __restrict__ Kc,
                 ushort_t* __restrict__ Vc, ushort_t* __restrict__ q_all)
{
    __shared__ float p0[32 * 33];
    __shared__ float p1[32 * 33];
    __shared__ float red[5];
    const int bid = blockIdx.x;
    const int t = threadIdx.x;
    const int i0 = t * 4, y = i0 >> 5, x0 = i0 & 31;

    if (bid < 23040) {
        const int which = bid / 7680;
        const int p = bid - which * 7680;
        const int b = p / 960, c = p - b * 960;
        const ushort_t* ip = Xqkv + ((long)b * 2880 + which * 960 + c) * 1024;
        const float* wgt = (which == 0 ? w_qc : which == 1 ? w_kc : w_vc) + c * 9;
        ushort_t* op = (which == 0 ? Qc : which == 1 ? Kc : Vc) + (long)p * 1024;
        ushort4 u = *(const ushort4*)(ip + i0);
        float* rw = p0 + y * 33 + x0;
        rw[0] = bf2f(u.x); rw[1] = bf2f(u.y); rw[2] = bf2f(u.z); rw[3] = bf2f(u.w);
        __syncthreads();
        float W[9];
        #pragma unroll
        for (int q = 0; q < 9; ++q) W[q] = wgt[q];
        float r[3][6];
        #pragma unroll
        for (int dy = 0; dy < 3; ++dy) {
            int yy = y + dy - 1;
            bool vy = (unsigned)yy < 32u;
            #pragma unroll
            for (int j = 0; j < 6; ++j) {
                int xx = x0 - 1 + j;
                r[dy][j] = (vy && (unsigned)xx < 32u) ? p0[yy * 33 + xx] : 0.f;
            }
        }
        float o[4];
        #pragma unroll
        for (int q = 0; q < 4; ++q)
            o[q] = r[0][q] * W[0] + r[0][q + 1] * W[1] + r[0][q + 2] * W[2]
                 + r[1][q] * W[3] + r[1][q + 1] * W[4] + r[1][q + 2] * W[5]
                 + r[2][q] * W[6] + r[2][q + 1] * W[7] + r[2][q + 2] * W[8];
        float inv = 1.f;
        if (which < 2) {
            float s = o[0] * o[0] + o[1] * o[1] + o[2] * o[2] + o[3] * o[3];
            #pragma unroll
            for (int off = 32; off > 0; off >>= 1) s += __shfl_down(s, off);
            if ((t & 63) == 0) red[t >> 6] = s;
            __syncthreads();
            if (t == 0) red[4] = 1.0f / fmaxf(sqrtf(red[0] + red[1] + red[2] + red[3]), 1e-12f);
            __syncthreads();
            inv = red[4];
        }
        *(ushort4*)(op + i0) =
            make_ushort4(f2bf(o[0] * inv), f2bf(o[1] * inv), f2bf(o[2] * inv), f2bf(o[3] * inv));
        return;
    }
    const int po = bid - 23040;
    const int o = po & 1023, b = po >> 10;
    ushort_t* op = q_all + (long)po * 1024;
    int off; const float* wbase;
    if (o < 64)       { off = 0;   wbase = wq1; }
    else if (o < 128) { *(ushort4*)(op + i0) = make_ushort4(0, 0, 0, 0); return; }
    else if (o < 256) { off = 128; wbase = wq2; }
    else if (o < 512) { off = 256; wbase = wq3; }
    else              { off = 512; wbase = wq4; }
    const int ol = o - off;
    const int g2 = ol & ~1;
    const ushort_t* ip0 = mh_x + ((long)(b << 10) + off + g2) * 1024;
    const ushort_t* ip1 = ip0 + 1024;
    ushort4 u0 = *(const ushort4*)(ip0 + i0);
    ushort4 u1 = *(const ushort4*)(ip1 + i0);
    float* r0w = p0 + y * 33 + x0;
    float* r1w = p1 + y * 33 + x0;
    r0w[0] = bf2f(u0.x); r0w[1] = bf2f(u0.y); r0w[2] = bf2f(u0.z); r0w[3] = bf2f(u0.w);
    r1w[0] = bf2f(u1.x); r1w[1] = bf2f(u1.y); r1w[2] = bf2f(u1.z); r1w[3] = bf2f(u1.w);
    __syncthreads();
    const float* wp = wbase + ol * 18;
    float W[18];
    #pragma unroll
    for (int q = 0; q < 18; ++q) W[q] = wp[q];
    float o4[4] = {0.f, 0.f, 0.f, 0.f};
    #pragma unroll
    for (int pl = 0; pl < 2; ++pl) {
        const float* src = pl ? p1 : p0;
        const float* Wp = W + pl * 9;
        float r[3][6];
        #pragma unroll
        for (int dy = 0; dy < 3; ++dy) {
            int yy = y + dy - 1;
            bool vy = (unsigned)yy < 32u;
            #pragma unroll
            for (int j = 0; j < 6; ++j) {
                int xx = x0 - 1 + j;
                r[dy][j] = (vy && (unsigned)xx < 32u) ? src[yy * 33 + xx] : 0.f;
            }
        }
        #pragma unroll
        for (int q = 0; q < 4; ++q)
            o4[q] += r[0][q] * Wp[0] + r[0][q + 1] * Wp[1] + r[0][q + 2] * Wp[2]
                   + r[1][q] * Wp[3] + r[1][q + 1] * Wp[4] + r[1][q + 2] * Wp[5]
                   + r[2][q] * Wp[6] + r[2][q + 1] * Wp[7] + r[2][q + 2] * Wp[8];
    }
    float s = o4[0] * o4[0] + o4[1] * o4[1] + o4[2] * o4[2] + o4[3] * o4[3];
    #pragma unroll
    for (int off2 = 32; off2 > 0; off2 >>= 1) s += __shfl_down(s, off2);
    if ((t & 63) == 0) red[t >> 6] = s;
    __syncthreads();
    if (t == 0) red[4] = 1.0f / fmaxf(sqrtf(red[0] + red[1] + red[2] + red[3]), 1e-12f);
    __syncthreads();
    float inv = red[4];
    *(ushort4*)(op + i0) =
        make_ushort4(f2bf(o4[0] * inv), f2bf(o4[1] * inv), f2bf(o4[2] * inv), f2bf(o4[3] * inv));
}

// ---------------------------------------------------------------------------
// Stats reduces
// ---------------------------------------------------------------------------
__global__ void reduce_sim(const float2* __restrict__ part, float2* __restrict__ stats)
{
    float2 p = part[blockIdx.x * 64 + threadIdx.x];
    float s1 = p.x, s2 = p.y;
    #pragma unroll
    for (int off = 32; off > 0; off >>= 1) {
        s1 += __shfl_down(s1, off);
        s2 += __shfl_down(s2, off);
    }
    if (threadIdx.x == 0) stats[blockIdx.x] = make_float2(s1, s2);
}

__global__ void reduce_branch(const float2* __restrict__ part, float2* __restrict__ stats)
{
    const int br = blockIdx.x & 3, b = blockIdx.x >> 2;
    const int lo4[4] = {0, 1, 2, 4}, hi4[4] = {1, 2, 4, 8};
    float s1 = 0.f, s2 = 0.f;
    if (threadIdx.x < 8) {
        for (int my = lo4[br]; my < hi4[br]; ++my) {
            float2 p = part[(b * 8 + my) * 8 + threadIdx.x];
            s1 += p.x; s2 += p.y;
        }
    }
    #pragma unroll
    for (int off = 32; off > 0; off >>= 1) {
        s1 += __shfl_down(s1, off);
        s2 += __shfl_down(s2, off);
    }
    if (threadIdx.x == 0) stats[b * 4 + br] = make_float2(s1, s2);
}

// ---------------------------------------------------------------------------
// Instance-norm + softmax (row length 960), f32 in -> bf16 out (sim path).
// ---------------------------------------------------------------------------
__global__ __launch_bounds__(256)
void instnorm_softmax_bf16(const float* __restrict__ x, ushort_t* __restrict__ out,
                           const float2* __restrict__ stats, int rowsPerB, float invL)
{
    int row = blockIdx.x;
    int b = row / rowsPerB;
    float2 st = stats[b];
    float mean = st.x * invL;
    float var = st.y * invL - mean * mean;
    float rinv = rsqrtf(var + 1e-5f);
    const float* xr = x + (long)row * 960;
    ushort_t* orow = out + (long)row * 960;
    int t = threadIdx.x;
    float v[4];
    float mx = -1e30f;
    #pragma unroll
    for (int q = 0; q < 4; ++q) {
        int i = t + q * 256;
        if (i < 960) { v[q] = (xr[i] - mean) * rinv; mx = fmaxf(mx, v[q]); }
        else v[q] = -1e30f;
    }
    #pragma unroll
    for (int off = 32; off > 0; off >>= 1) mx = fmaxf(mx, __shfl_down(mx, off));
    __shared__ float rm[4];
    __shared__ float bmax, bsuminv;
    if ((t & 63) == 0) rm[t >> 6] = mx;
    __syncthreads();
    if (t == 0) bmax = fmaxf(fmaxf(rm[0], rm[1]), fmaxf(rm[2], rm[3]));
    __syncthreads();
    float mall = bmax;
    float s = 0.f;
    #pragma unroll
    for (int q = 0; q < 4; ++q) {
        int i = t + q * 256;
        if (i < 960) { v[q] = __expf(v[q] - mall); s += v[q]; }
    }
    #pragma unroll
    for (int off = 32; off > 0; off >>= 1) s += __shfl_down(s, off);
    if ((t & 63) == 0) rm[t >> 6] = s;
    __syncthreads();
    if (t == 0) bsuminv = 1.0f / (rm[0] + rm[1] + rm[2] + rm[3]);
    __syncthreads();
    float invS = bsuminv;
    #pragma unroll
    for (int q = 0; q < 4; ++q) {
        int i = t + q * 256;
        if (i < 960) orow[i] = f2bf(v[q] * invS);
    }
}

// ---------------------------------------------------------------------------
// Batched branch instnorm+softmax: rows [b][1024][960]; pad rows -> zeros.
// ---------------------------------------------------------------------------
__global__ __launch_bounds__(256)
void softmax_attn_kernel(const float* __restrict__ x, ushort_t* __restrict__ P,
                         const float2* __restrict__ stats)
{
    const int r = blockIdx.x & 1023, b = blockIdx.x >> 10;
    const int t = threadIdx.x;
    ushort_t* orow = P + ((long)(b << 10) + r) * 960;
    int br; float cnt;
    if (r < 64)       { br = 0; cnt = 64.f; }
    else if (r < 128) {
        #pragma unroll
        for (int q = 0; q < 4; ++q) {
            int i = t + q * 256;
            if (i < 960) orow[i] = 0;
        }
        return;
    }
    else if (r < 256) { br = 1; cnt = 128.f; }
    else if (r < 512) { br = 2; cnt = 256.f; }
    else              { br = 3; cnt = 512.f; }
    float invL = 1.0f / (cnt * 960.f);
    float2 st = stats[b * 4 + br];
    float mean = st.x * invL;
    float var = st.y * invL - mean * mean;
    float rinv = rsqrtf(var + 1e-5f);
    const float* xr = x + ((long)(b << 10) + r) * 960;
    float v[4];
    float mx = -1e30f;
    #pragma unroll
    for (int q = 0; q < 4; ++q) {
        int i = t + q * 256;
        if (i < 960) { v[q] = (xr[i] - mean) * rinv; mx = fmaxf(mx, v[q]); }
        else v[q] = -1e30f;
    }
    #pragma unroll
    for (int off = 32; off > 0; off >>= 1) mx = fmaxf(mx, __shfl_down(mx, off));
    __shared__ float rm[4];
    __shared__ float bmax, bsuminv;
    if ((t & 63) == 0) rm[t >> 6] = mx;
    __syncthreads();
    if (t == 0) bmax = fmaxf(fmaxf(rm[0], rm[1]), fmaxf(rm[2], rm[3]));
    __syncthreads();
    float mall = bmax;
    float s = 0.f;
    #pragma unroll
    for (int q = 0; q < 4; ++q) {
        int i = t + q * 256;
        if (i < 960) { v[q] = __expf(v[q] - mall); s += v[q]; }
    }
    #pragma unroll
    for (int off = 32; off > 0; off >>= 1) s += __shfl_down(s, off);
    if ((t & 63) == 0) rm[t >> 6] = s;
    __syncthreads();
    if (t == 0) bsuminv = 1.0f / (rm[0] + rm[1] + rm[2] + rm[3]);
    __syncthreads();
    float invS = bsuminv;
    #pragma unroll
    for (int q = 0; q < 4; ++q) {
        int i = t + q * 256;
        if (i < 960) orow[i] = f2bf(v[q] * invS);
    }
}

// ---------------------------------------------------------------------------

extern "C" void kernel_launch(void* const* d_in, const int* in_sizes, int n_in,
                              void* d_out, int out_size, void* d_ws, size_t ws_size,
                              hipStream_t stream)
{
    const float* emb[4]  = {(const float*)d_in[0], (const float*)d_in[1],
                            (const float*)d_in[2], (const float*)d_in[3]};
    const float* emb_all = (const float*)d_in[4];
    const float* w_mh[4] = {(const float*)d_in[5], (const float*)d_in[6],
                            (const float*)d_in[7], (const float*)d_in[8]};
    const float* w_mq = (const float*)d_in[9];
    const float* w_mk = (const float*)d_in[10];
    const float* w_mv = (const float*)d_in[11];
    const float* w_q[4] = {(const float*)d_in[12], (const float*)d_in[13],
                           (const float*)d_in[14], (const float*)d_in[15]};
    const float* w_qc = (const float*)d_in[16];
    const float* w_kc = (const float*)d_in[17];
    const float* w_vc = (const float*)d_in[18];
    const float* w_proj[4] = {(const float*)d_in[19], (const float*)d_in[20],
                              (const float*)d_in[21], (const float*)d_in[22]};
    float* out = (float*)d_out;

    // ---- arena (element offsets into ushort_t* U) ----
    ushort_t* U = (ushort_t*)d_ws;
    const long eWQKV = 0;          // 2,764,800  (WQ|WK|WV, k-contig rows)
    const long eWMH  = 2764800;    // 348,160
    const long eWPJ  = 3112960;    // 348,160
    const long eR1   = 3461120;    // embT_all -> Vc -> ctx       (7,864,320)
    const long eR2   = 11325440;   // embT_i  -> VcT -> ctxT      (7,864,320)
    const long eR3   = 19189760;   // Xqkv (23,592,960) -> S6 f32(15,728,640 us) + Pc -> oT
    const long ePc   = 34918400;   // Pc (7,372,800) ends 42,291,200
    const long eR4   = 42782720;   // mh_x -> P_all               (8,388,608)
    const long eQc   = 51171328;   // Qc (7,864,320)
    const long eKc   = 59035648;   // Kc (7,864,320)
    const long eQall = 66899968;   // q_all (8,388,608) ends 75,288,576
    float2* part  = (float2*)(U + 75288576);
    float2* stats = part + 512;

    ushort_t* WQKVb = U + eWQKV;
    ushort_t* WMHb  = U + eWMH;
    ushort_t* WPJb  = U + eWPJ;
    ushort_t* embT_all = U + eR1;
    ushort_t* Vc    = U + eR1;
    ushort_t* ctx   = U + eR1;
    ushort_t* VcT   = U + eR2;
    ushort_t* ctxT  = U + eR2;
    ushort_t* Xqkv  = U + eR3;
    float*    S6    = (float*)(U + eR3);
    ushort_t* oT    = U + eR3;
    ushort_t* Pc    = U + ePc;
    ushort_t* mh_x  = U + eR4;
    ushort_t* P_all = U + eR4;
    ushort_t* QcB   = U + eQc;
    ushort_t* KcB   = U + eKc;
    ushort_t* q_all = U + eQall;
    ushort_t* embT_i[4] = {U + eR2, U + eR2 + 524288, U + eR2 + 1572864, U + eR2 + 3670016};

    const float scale = 0.0322748612183951400f;   // 1/sqrt(960)
    const long SB = (long)KVC * HWN;              // 983040
    const long S1024 = 1024L * 1024;
    const int CH[4] = {64, 128, 256, 512};
    const int mhoff[4] = {0, 4096, 20480, 86016};
    const int rowOff[4] = {0, 128, 256, 512};
    const long outOff[4] = {0, 524288, 1572864, 3670016};
    dim3 blk(256);

    // ---- f2b weights (plain) ----
    {
        F2BTab tf;
        const float* fs[11] = {w_mq, w_mk, w_mv, w_mh[0], w_mh[1], w_mh[2], w_mh[3],
                               w_proj[0], w_proj[1], w_proj[2], w_proj[3]};
        long fd[11] = {eWQKV, eWQKV + 921600, eWQKV + 1843200,
                       eWMH + 0, eWMH + 4096, eWMH + 20480, eWMH + 86016,
                       eWPJ + 0, eWPJ + 4096, eWPJ + 20480, eWPJ + 86016};
        int fn[11] = {900, 900, 900, 4, 16, 64, 256, 4, 16, 64, 256};
        int ftot = 0;
        for (int i = 0; i < 11; ++i) { tf.src[i] = fs[i]; tf.dstOff[i] = fd[i]; tf.nblk[i] = fn[i]; ftot += fn[i]; }
        tf.nseg = 11;
        f2b_batched<<<ftot, blk, 0, stream>>>(tf, U);
    }
    // ---- f2bT embeddings (transpose-convert) ----
    {
        F2TTab tt;
        const float* ts[5] = {emb_all, emb[0], emb[1], emb[2], emb[3]};
        long td[5] = {eR1, eR2, eR2 + 524288, eR2 + 1572864, eR2 + 3670016};
        int tR[5] = {960, 64, 128, 256, 512};
        int tn[5];
        long tsi[5], tso[5];
        int ttot = 0;
        for (int i = 0; i < 5; ++i) {
            tsi[i] = (long)tR[i] * 1024; tso[i] = tsi[i];
            tn[i] = NB * (tR[i] / 64) * 16; ttot += tn[i];
            tt.src[i] = ts[i]; tt.dstOff[i] = td[i]; tt.R[i] = tR[i];
            tt.sIn[i] = tsi[i]; tt.sOut[i] = tso[i]; tt.nblk[i] = tn[i];
        }
        tt.nseg = 5;
        f2bt_batched<<<ttot, blk, 0, stream>>>(tt, U);
    }

    auto nt1 = [&](const ushort_t* A, long sA, const ushort_t* B, long sB, long ldb,
                   void* C, long sC, int M, int K, int obf) {
        NTTab tb;
        for (int s = 0; s < 5; ++s) {
            tb.A[s] = A; tb.B[s] = B; tb.C[s] = C;
            tb.sA[s] = sA; tb.sB[s] = sB; tb.sC[s] = sC; tb.ldb[s] = ldb;
            tb.M[s] = M; tb.K[s] = K; tb.obf[s] = obf; tb.mt0[s] = (s == 0) ? 0 : (1 << 30);
        }
        tb.nseg = 1;
        dim3 g(NB, (M + 127) / 128, 8);
        mfma_gemm_nt_tab<<<g, blk, 0, stream>>>(tb);
    };

    // ---- stage 1: QKV (M=2880) + 4x mhead conv1x1, one NT launch ----
    {
        NTTab tb;
        tb.A[0] = WQKVb; tb.B[0] = embT_all; tb.C[0] = Xqkv;
        tb.sA[0] = 0; tb.sB[0] = SB; tb.sC[0] = 2880L * 1024; tb.ldb[0] = 960;
        tb.M[0] = 2880; tb.K[0] = 960; tb.obf[0] = 1; tb.mt0[0] = 0;
        int mt = 23;
        for (int i = 0; i < 4; ++i) {
            tb.A[1 + i] = WMHb + mhoff[i]; tb.B[1 + i] = embT_i[i];
            tb.C[1 + i] = mh_x + (long)rowOff[i] * 1024;
            tb.sA[1 + i] = 0; tb.sB[1 + i] = (long)CH[i] * 1024; tb.sC[1 + i] = S1024;
            tb.ldb[1 + i] = CH[i];
            tb.M[1 + i] = CH[i]; tb.K[1 + i] = CH[i]; tb.obf[1 + i] = 1; tb.mt0[1 + i] = mt;
            mt += (CH[i] + 127) / 128;
        }
        tb.nseg = 5;
        dim3 g(NB, mt, 8);   // (8, 31, 8): x = batch -> XCD
        mfma_gemm_nt_tab<<<g, blk, 0, stream>>>(tb);
    }

    // ---- stencils: dw(Q,K,V) + gconv, one launch ----
    stencil_all<<<31232, blk, 0, stream>>>(Xqkv, mh_x, w_qc, w_kc, w_vc,
                                           w_q[0], w_q[1], w_q[2], w_q[3],
                                           QcB, KcB, Vc, q_all);

    // ---- Vc -> VcT ----
    trb_kernel<<<dim3(16, 15, NB), blk, 0, stream>>>(Vc, VcT);

    // ---- sim = Qc @ Kc^T * scale + stats ----
    mfma_gemm_nt_stats<<<dim3(NB, 8, 8), blk, 0, stream>>>(
        QcB, KcB, S6, part, KVC, KVC, HWN, SB, SB, (long)KVC * KVC, scale);
    reduce_sim<<<NB, 64, 0, stream>>>(part, stats);
    instnorm_softmax_bf16<<<NB * KVC, blk, 0, stream>>>(S6, Pc, stats, KVC,
                                                        1.f / ((float)KVC * (float)KVC));

    // ---- ctx = NT(Pc, VcT) -> [960][1024] bf16 ----
    nt1(Pc, (long)KVC * KVC, VcT, SB, 960, ctx, SB, KVC, KVC, 1);

    // ---- ctx -> ctxT ----
    trb_kernel<<<dim3(16, 15, NB), blk, 0, stream>>>(ctx, ctxT);

    // ---- attn = q_all @ ctx^T * scale + stats ----
    mfma_gemm_nt_stats<<<dim3(NB, 8, 8), blk, 0, stream>>>(
        q_all, ctx, S6, part, 1024, KVC, HWN, S1024, SB, SB, scale);
    reduce_branch<<<32, 64, 0, stream>>>(part, stats);
    softmax_attn_kernel<<<NB * 1024, blk, 0, stream>>>(S6, P_all, stats);

    // ---- oT = NT(ctxT, P_all) -> [1024 hw][1024 ch] bf16 ----
    nt1(ctxT, SB, P_all, SB, 960, oT, S1024, 1024, KVC, 1);

    // ---- proj: 4 branches, one NT table launch (f32 out) ----
    {
        NTTab tb;
        int mt = 0;
        for (int i = 0; i < 4; ++i) {
            tb.A[i] = WPJb + mhoff[i]; tb.B[i] = oT + rowOff[i];
            tb.C[i] = out + outOff[i];
            tb.sA[i] = 0; tb.sB[i] = S1024; tb.sC[i] = (long)CH[i] * 1024;
            tb.ldb[i] = 1024;
            tb.M[i] = CH[i]; tb.K[i] = CH[i]; tb.obf[i] = 0; tb.mt0[i] = mt;
            mt += (CH[i] + 127) / 128;
        }
        tb.A[4] = tb.A[3]; tb.B[4] = tb.B[3]; tb.C[4] = tb.C[3];
        tb.sA[4] = 0; tb.sB[4] = 0; tb.sC[4] = 0; tb.ldb[4] = 1024;
        tb.M[4] = 1; tb.K[4] = 64; tb.obf[4] = 0; tb.mt0[4] = 1 << 30;
        tb.nseg = 4;
        dim3 g(NB, mt, 8);   // (8, 8, 8)
        mfma_gemm_nt_tab<<<g, blk, 0, stream>>>(tb);
    }

    (void)in_sizes; (void)n_in; (void)out_size; (void)ws_size;
}

// Round 7
// 303.756 us; speedup vs baseline: 7.2990x; 1.0551x over previous
//
#include <hip/hip_runtime.h>
#include <hip/hip_bf16.h>
#include <math.h>

#define NB 8
#define HWN 1024
#define KVC 960

typedef short bf16x8 __attribute__((ext_vector_type(8)));
typedef float f32x4 __attribute__((ext_vector_type(4)));
typedef unsigned short ushort_t;

__device__ inline ushort_t f2bf(float f) {
    __hip_bfloat16 h = __float2bfloat16(f);
    return *reinterpret_cast<ushort_t*>(&h);
}
__device__ inline float bf2f(ushort_t u) {
    union { float f; unsigned int i; } x; x.i = ((unsigned int)u) << 16; return x.f;
}
__device__ inline void glds16(const ushort_t* src, ushort_t* dst) {
    __builtin_amdgcn_global_load_lds(
        (const __attribute__((address_space(1))) void*)src,
        (__attribute__((address_space(3))) void*)dst, 16, 0, 0);
}

// ---------------------------------------------------------------------------
// Batched f32 -> bf16 convert (no transpose). 1024 elems per block.
// ---------------------------------------------------------------------------
struct F2BTab {
    const float* src[12];
    long dstOff[12];
    int nblk[12];
    int nseg;
};

__global__ __launch_bounds__(256)
void f2b_batched(F2BTab tab, ushort_t* base)
{
    int b = blockIdx.x, s = 0;
    while (s < tab.nseg - 1 && b >= tab.nblk[s]) { b -= tab.nblk[s]; ++s; }
    float4 v = *((const float4*)tab.src[s] + (long)b * 256 + threadIdx.x);
    ushort4 o = make_ushort4(f2bf(v.x), f2bf(v.y), f2bf(v.z), f2bf(v.w));
    *((ushort4*)(base + tab.dstOff[s]) + (long)b * 256 + threadIdx.x) = o;
}

// ---------------------------------------------------------------------------
// Batched f32 -> bf16 transpose-convert: in [b][R][1024] f32 -> out [b][1024][R].
// ---------------------------------------------------------------------------
struct F2TTab {
    const float* src[5];
    long dstOff[5];
    long sIn[5], sOut[5];
    int R[5];
    int nblk[5];
    int nseg;
};

__global__ __launch_bounds__(256)
void f2bt_batched(F2TTab tab, ushort_t* base)
{
    __shared__ ushort_t tile[64][65];
    int b = blockIdx.x, s = 0;
    while (s < tab.nseg - 1 && b >= tab.nblk[s]) { b -= tab.nblk[s]; ++s; }
    const int R = tab.R[s];
    const int tpb = (R >> 6) * 16;
    const int batch = b / tpb, rem = b - batch * tpb;
    const int rtile = rem >> 4, ctile = rem & 15;
    const float* ib = tab.src[s] + (long)batch * tab.sIn[s] + (long)(rtile * 64) * 1024 + ctile * 64;
    const int t = threadIdx.x, tr = t >> 4, tc = (t & 15) * 4;
    #pragma unroll
    for (int p = 0; p < 4; ++p) {
        float4 v = *(const float4*)(ib + (long)(tr + 16 * p) * 1024 + tc);
        tile[tr + 16 * p][tc + 0] = f2bf(v.x);
        tile[tr + 16 * p][tc + 1] = f2bf(v.y);
        tile[tr + 16 * p][tc + 2] = f2bf(v.z);
        tile[tr + 16 * p][tc + 3] = f2bf(v.w);
    }
    __syncthreads();
    ushort_t* ob = base + tab.dstOff[s] + (long)batch * tab.sOut[s]
                 + (long)(ctile * 64) * R + rtile * 64;
    #pragma unroll
    for (int p = 0; p < 4; ++p) {
        ushort4 v;
        v.x = tile[tc + 0][tr + 16 * p];
        v.y = tile[tc + 1][tr + 16 * p];
        v.z = tile[tc + 2][tr + 16 * p];
        v.w = tile[tc + 3][tr + 16 * p];
        *(ushort4*)(ob + (long)(tr + 16 * p) * R + tc) = v;
    }
}

// ---------------------------------------------------------------------------
// bf16 transpose: in [b][960][1024] -> out [b][1024][960]. grid (16,15,NB).
// ---------------------------------------------------------------------------
__global__ __launch_bounds__(256)
void trb_kernel(const ushort_t* __restrict__ in, ushort_t* __restrict__ out)
{
    __shared__ ushort_t tile[64][65];
    const int r0 = blockIdx.y * 64, c0 = blockIdx.x * 64;
    const long sP = (long)KVC * HWN;
    const ushort_t* ib = in + (long)blockIdx.z * sP;
    ushort_t* ob = out + (long)blockIdx.z * sP;
    const int t = threadIdx.x, tr = t >> 4, tc = (t & 15) * 4;
    #pragma unroll
    for (int p = 0; p < 4; ++p) {
        ushort4 v = *(const ushort4*)(ib + (long)(r0 + tr + 16 * p) * 1024 + c0 + tc);
        tile[tr + 16 * p][tc + 0] = v.x;
        tile[tr + 16 * p][tc + 1] = v.y;
        tile[tr + 16 * p][tc + 2] = v.z;
        tile[tr + 16 * p][tc + 3] = v.w;
    }
    __syncthreads();
    #pragma unroll
    for (int p = 0; p < 4; ++p) {
        ushort4 v;
        v.x = tile[tc + 0][tr + 16 * p];
        v.y = tile[tc + 1][tr + 16 * p];
        v.z = tile[tc + 2][tr + 16 * p];
        v.w = tile[tc + 3][tr + 16 * p];
        *(ushort4*)(ob + (long)(c0 + tr + 16 * p) * 960 + r0 + tc) = v;
    }
}

// ---------------------------------------------------------------------------
// bf16 MFMA GEMM NT + fused instnorm stats partials. BK=64, 2-phase
// double-buffered pipeline with counted vmcnt(8) (never drain in loop).
// grid (NB, 8, 8): x = batch.
// ---------------------------------------------------------------------------
__global__ __launch_bounds__(256)
void mfma_gemm_nt_stats(const ushort_t* __restrict__ A, const ushort_t* __restrict__ B,
                        float* __restrict__ C, float2* __restrict__ part,
                        int M, int N, int K, long sA, long sB, long sC, float alpha)
{
    __shared__ __align__(16) ushort_t lA[2][128 * 64];
    __shared__ __align__(16) ushort_t lB[2][128 * 64];
    const int bb = blockIdx.x;
    const int by = blockIdx.y, bx = blockIdx.z;
    const ushort_t* Ab = A + (long)bb * sA;
    const ushort_t* Bb = B + (long)bb * sB;
    const int row0 = by * 128, col0 = bx * 128;
    const int t = threadIdx.x, lane = t & 63, w = t >> 6;
    const int wr = w >> 1, wc = w & 1;
    const int arl = lane >> 3;
    const int acs = ((lane & 7) ^ arl) * 8;
    int arow[4], brow[4];
    #pragma unroll
    for (int j = 0; j < 4; ++j) {
        int r = row0 + w * 32 + j * 8 + arl;  arow[j] = r < M ? r : M - 1;
        int rb = col0 + w * 32 + j * 8 + arl; brow[j] = rb < N ? rb : N - 1;
    }

    f32x4 acc[4][4];
    #pragma unroll
    for (int m = 0; m < 4; ++m)
        #pragma unroll
        for (int n = 0; n < 4; ++n)
            acc[m][n] = (f32x4){0.f, 0.f, 0.f, 0.f};

    auto stage = [&](int buf, int k0) {
        #pragma unroll
        for (int j = 0; j < 4; ++j) {
            glds16(Ab + (long)arow[j] * K + k0 + acs, lA[buf] + (w * 32 + j * 8) * 64);
            glds16(Bb + (long)brow[j] * K + k0 + acs, lB[buf] + (w * 32 + j * 8) * 64);
        }
    };
    auto compute = [&](int buf) {
        __builtin_amdgcn_s_setprio(1);
        #pragma unroll
        for (int sub = 0; sub < 2; ++sub) {
            const int kc = (lane >> 4) + sub * 4;
            bf16x8 aF[4], bF[4];
            #pragma unroll
            for (int m = 0; m < 4; ++m) {
                int rl = wr * 64 + m * 16 + (lane & 15);
                aF[m] = *(const bf16x8*)(lA[buf] + rl * 64 + (kc ^ (rl & 7)) * 8);
            }
            #pragma unroll
            for (int n = 0; n < 4; ++n) {
                int rl = wc * 64 + n * 16 + (lane & 15);
                bF[n] = *(const bf16x8*)(lB[buf] + rl * 64 + (kc ^ (rl & 7)) * 8);
            }
            #pragma unroll
            for (int m = 0; m < 4; ++m)
                #pragma unroll
                for (int n = 0; n < 4; ++n)
                    acc[m][n] = __builtin_amdgcn_mfma_f32_16x16x32_bf16(aF[m], bF[n], acc[m][n], 0, 0, 0);
        }
        __builtin_amdgcn_s_setprio(0);
    };

    stage(0, 0);
    int cur = 0;
    for (int k0 = 64; k0 < K; k0 += 64) {
        stage(cur ^ 1, k0);
        asm volatile("s_waitcnt vmcnt(8)" ::: "memory");
        __builtin_amdgcn_sched_barrier(0);
        __builtin_amdgcn_s_barrier();
        compute(cur);
        __builtin_amdgcn_s_barrier();
        cur ^= 1;
    }
    asm volatile("s_waitcnt vmcnt(0)" ::: "memory");
    __builtin_amdgcn_sched_barrier(0);
    __builtin_amdgcn_s_barrier();
    compute(cur);

    const int cr0 = row0 + wr * 64 + (lane >> 4) * 4;
    const int cc0 = col0 + wc * 64 + (lane & 15);
    float* Cb = C + (long)bb * sC;
    float s1 = 0.f, s2 = 0.f;
    #pragma unroll
    for (int m = 0; m < 4; ++m) {
        #pragma unroll
        for (int n = 0; n < 4; ++n) {
            int ccol = cc0 + n * 16;
            if (ccol >= N) continue;
            #pragma unroll
            for (int r = 0; r < 4; ++r) {
                int crow = cr0 + m * 16 + r;
                if (crow < M) {
                    float v = acc[m][n][r] * alpha;
                    Cb[(long)crow * N + ccol] = v;
                    s1 += v; s2 += v * v;
                }
            }
        }
    }
    #pragma unroll
    for (int off = 32; off > 0; off >>= 1) {
        s1 += __shfl_down(s1, off);
        s2 += __shfl_down(s2, off);
    }
    __syncthreads();               // all ds_reads of lA done before aliasing
    float* rbuf = (float*)lA;
    if (lane == 0) { rbuf[w] = s1; rbuf[4 + w] = s2; }
    __syncthreads();
    if (t == 0)
        part[(bb * 8 + by) * 8 + bx] =
            make_float2(rbuf[0] + rbuf[1] + rbuf[2] + rbuf[3],
                        rbuf[4] + rbuf[5] + rbuf[6] + rbuf[7]);
}

// ---------------------------------------------------------------------------
// Table-driven bf16 MFMA GEMM NT, BK=64, N fixed 1024; 2-phase pipeline.
// grid (NB, mt, 8): x = batch.
// ---------------------------------------------------------------------------
struct NTTab {
    const ushort_t* A[5];
    const ushort_t* B[5];
    void* C[5];
    long sA[5], sB[5], sC[5], ldb[5];
    int M[5], K[5], obf[5], mt0[5];
    int nseg;
};

__global__ __launch_bounds__(256)
void mfma_gemm_nt_tab(NTTab tab)
{
    __shared__ __align__(16) ushort_t lA[2][128 * 64];
    __shared__ __align__(16) ushort_t lB[2][128 * 64];
    const int bb = blockIdx.x;
    int si = 0;
    #pragma unroll
    for (int s = 1; s < 5; ++s)
        if (s < tab.nseg && (int)blockIdx.y >= tab.mt0[s]) si = s;
    const int M = tab.M[si], K = tab.K[si];
    const long ldb = tab.ldb[si];
    const ushort_t* Ab = tab.A[si] + (long)bb * tab.sA[si];
    const ushort_t* Bb = tab.B[si] + (long)bb * tab.sB[si];
    const int row0 = (blockIdx.y - tab.mt0[si]) * 128, col0 = blockIdx.z * 128;
    const int t = threadIdx.x, lane = t & 63, w = t >> 6;
    const int wr = w >> 1, wc = w & 1;
    const int arl = lane >> 3;
    const int acs = ((lane & 7) ^ arl) * 8;
    int arow[4], brow[4];
    #pragma unroll
    for (int j = 0; j < 4; ++j) {
        int r = row0 + w * 32 + j * 8 + arl;
        arow[j] = r < M ? r : M - 1;
        brow[j] = col0 + w * 32 + j * 8 + arl;   // N=1024, always valid
    }

    f32x4 acc[4][4];
    #pragma unroll
    for (int m = 0; m < 4; ++m)
        #pragma unroll
        for (int n = 0; n < 4; ++n)
            acc[m][n] = (f32x4){0.f, 0.f, 0.f, 0.f};

    auto stage = [&](int buf, int k0) {
        #pragma unroll
        for (int j = 0; j < 4; ++j) {
            glds16(Ab + (long)arow[j] * K + k0 + acs, lA[buf] + (w * 32 + j * 8) * 64);
            glds16(Bb + (long)brow[j] * ldb + k0 + acs, lB[buf] + (w * 32 + j * 8) * 64);
        }
    };
    auto compute = [&](int buf) {
        __builtin_amdgcn_s_setprio(1);
        #pragma unroll
        for (int sub = 0; sub < 2; ++sub) {
            const int kc = (lane >> 4) + sub * 4;
            bf16x8 aF[4], bF[4];
            #pragma unroll
            for (int m = 0; m < 4; ++m) {
                int rl = wr * 64 + m * 16 + (lane & 15);
                aF[m] = *(const bf16x8*)(lA[buf] + rl * 64 + (kc ^ (rl & 7)) * 8);
            }
            #pragma unroll
            for (int n = 0; n < 4; ++n) {
                int rl = wc * 64 + n * 16 + (lane & 15);
                bF[n] = *(const bf16x8*)(lB[buf] + rl * 64 + (kc ^ (rl & 7)) * 8);
            }
            #pragma unroll
            for (int m = 0; m < 4; ++m)
                #pragma unroll
                for (int n = 0; n < 4; ++n)
                    acc[m][n] = __builtin_amdgcn_mfma_f32_16x16x32_bf16(aF[m], bF[n], acc[m][n], 0, 0, 0);
        }
        __builtin_amdgcn_s_setprio(0);
    };

    stage(0, 0);
    int cur = 0;
    for (int k0 = 64; k0 < K; k0 += 64) {
        stage(cur ^ 1, k0);
        asm volatile("s_waitcnt vmcnt(8)" ::: "memory");
        __builtin_amdgcn_sched_barrier(0);
        __builtin_amdgcn_s_barrier();
        compute(cur);
        __builtin_amdgcn_s_barrier();
        cur ^= 1;
    }
    asm volatile("s_waitcnt vmcnt(0)" ::: "memory");
    __builtin_amdgcn_sched_barrier(0);
    __builtin_amdgcn_s_barrier();
    compute(cur);

    const int cr0 = row0 + wr * 64 + (lane >> 4) * 4;
    const int cc0 = col0 + wc * 64 + (lane & 15);
    const int obf = tab.obf[si];
    ushort_t* Cb_b = (ushort_t*)tab.C[si] + (long)bb * tab.sC[si];
    float* Cb_f = (float*)tab.C[si] + (long)bb * tab.sC[si];
    #pragma unroll
    for (int m = 0; m < 4; ++m) {
        #pragma unroll
        for (int n = 0; n < 4; ++n) {
            int ccol = cc0 + n * 16;
            #pragma unroll
            for (int r = 0; r < 4; ++r) {
                int crow = cr0 + m * 16 + r;
                if (crow < M) {
                    float v = acc[m][n][r];
                    if (obf) Cb_b[(long)crow * 1024 + ccol] = f2bf(v);
                    else     Cb_f[(long)crow * 1024 + ccol] = v;
                }
            }
        }
    }
}

// ---------------------------------------------------------------------------
// Fused stencil launch: depthwise 3x3 on Q/K/V (l2norm on Q,K) + grouped
// 3x3 conv + l2norm for all branches.
// ---------------------------------------------------------------------------
__global__ __launch_bounds__(256)
void stencil_all(const ushort_t* __restrict__ Xqkv, const ushort_t* __restrict__ mh_x,
                 const float* __restrict__ w_qc, const float* __restrict__ w_kc,
                 const float* __restrict__ w_vc,
                 const float* __restrict__ wq1, const float* __restrict__ wq2,
                 const float* __restrict__ wq3, const float* __restrict__ wq4,
                 ushort_t* __restrict__ Qc, ushort_t* __restrict__ Kc,
                 ushort_t* __restrict__ Vc, ushort_t* __restrict__ q_all)
{
    __shared__ float p0[32 * 33];
    __shared__ float p1[32 * 33];
    __shared__ float red[5];
    const int bid = blockIdx.x;
    const int t = threadIdx.x;
    const int i0 = t * 4, y = i0 >> 5, x0 = i0 & 31;

    if (bid < 23040) {
        const int which = bid / 7680;
        const int p = bid - which * 7680;
        const int b = p / 960, c = p - b * 960;
        const ushort_t* ip = Xqkv + ((long)b * 2880 + which * 960 + c) * 1024;
        const float* wgt = (which == 0 ? w_qc : which == 1 ? w_kc : w_vc) + c * 9;
        ushort_t* op = (which == 0 ? Qc : which == 1 ? Kc : Vc) + (long)p * 1024;
        ushort4 u = *(const ushort4*)(ip + i0);
        float* rw = p0 + y * 33 + x0;
        rw[0] = bf2f(u.x); rw[1] = bf2f(u.y); rw[2] = bf2f(u.z); rw[3] = bf2f(u.w);
        __syncthreads();
        float W[9];
        #pragma unroll
        for (int q = 0; q < 9; ++q) W[q] = wgt[q];
        float r[3][6];
        #pragma unroll
        for (int dy = 0; dy < 3; ++dy) {
            int yy = y + dy - 1;
            bool vy = (unsigned)yy < 32u;
            #pragma unroll
            for (int j = 0; j < 6; ++j) {
                int xx = x0 - 1 + j;
                r[dy][j] = (vy && (unsigned)xx < 32u) ? p0[yy * 33 + xx] : 0.f;
            }
        }
        float o[4];
        #pragma unroll
        for (int q = 0; q < 4; ++q)
            o[q] = r[0][q] * W[0] + r[0][q + 1] * W[1] + r[0][q + 2] * W[2]
                 + r[1][q] * W[3] + r[1][q + 1] * W[4] + r[1][q + 2] * W[5]
                 + r[2][q] * W[6] + r[2][q + 1] * W[7] + r[2][q + 2] * W[8];
        float inv = 1.f;
        if (which < 2) {
            float s = o[0] * o[0] + o[1] * o[1] + o[2] * o[2] + o[3] * o[3];
            #pragma unroll
            for (int off = 32; off > 0; off >>= 1) s += __shfl_down(s, off);
            if ((t & 63) == 0) red[t >> 6] = s;
            __syncthreads();
            if (t == 0) red[4] = 1.0f / fmaxf(sqrtf(red[0] + red[1] + red[2] + red[3]), 1e-12f);
            __syncthreads();
            inv = red[4];
        }
        *(ushort4*)(op + i0) =
            make_ushort4(f2bf(o[0] * inv), f2bf(o[1] * inv), f2bf(o[2] * inv), f2bf(o[3] * inv));
        return;
    }
    const int po = bid - 23040;
    const int o = po & 1023, b = po >> 10;
    ushort_t* op = q_all + (long)po * 1024;
    int off; const float* wbase;
    if (o < 64)       { off = 0;   wbase = wq1; }
    else if (o < 128) { *(ushort4*)(op + i0) = make_ushort4(0, 0, 0, 0); return; }
    else if (o < 256) { off = 128; wbase = wq2; }
    else if (o < 512) { off = 256; wbase = wq3; }
    else              { off = 512; wbase = wq4; }
    const int ol = o - off;
    const int g2 = ol & ~1;
    const ushort_t* ip0 = mh_x + ((long)(b << 10) + off + g2) * 1024;
    const ushort_t* ip1 = ip0 + 1024;
    ushort4 u0 = *(const ushort4*)(ip0 + i0);
    ushort4 u1 = *(const ushort4*)(ip1 + i0);
    float* r0w = p0 + y * 33 + x0;
    float* r1w = p1 + y * 33 + x0;
    r0w[0] = bf2f(u0.x); r0w[1] = bf2f(u0.y); r0w[2] = bf2f(u0.z); r0w[3] = bf2f(u0.w);
    r1w[0] = bf2f(u1.x); r1w[1] = bf2f(u1.y); r1w[2] = bf2f(u1.z); r1w[3] = bf2f(u1.w);
    __syncthreads();
    const float* wp = wbase + ol * 18;
    float W[18];
    #pragma unroll
    for (int q = 0; q < 18; ++q) W[q] = wp[q];
    float o4[4] = {0.f, 0.f, 0.f, 0.f};
    #pragma unroll
    for (int pl = 0; pl < 2; ++pl) {
        const float* src = pl ? p1 : p0;
        const float* Wp = W + pl * 9;
        float r[3][6];
        #pragma unroll
        for (int dy = 0; dy < 3; ++dy) {
            int yy = y + dy - 1;
            bool vy = (unsigned)yy < 32u;
            #pragma unroll
            for (int j = 0; j < 6; ++j) {
                int xx = x0 - 1 + j;
                r[dy][j] = (vy && (unsigned)xx < 32u) ? src[yy * 33 + xx] : 0.f;
            }
        }
        #pragma unroll
        for (int q = 0; q < 4; ++q)
            o4[q] += r[0][q] * Wp[0] + r[0][q + 1] * Wp[1] + r[0][q + 2] * Wp[2]
                   + r[1][q] * Wp[3] + r[1][q + 1] * Wp[4] + r[1][q + 2] * Wp[5]
                   + r[2][q] * Wp[6] + r[2][q + 1] * Wp[7] + r[2][q + 2] * Wp[8];
    }
    float s = o4[0] * o4[0] + o4[1] * o4[1] + o4[2] * o4[2] + o4[3] * o4[3];
    #pragma unroll
    for (int off2 = 32; off2 > 0; off2 >>= 1) s += __shfl_down(s, off2);
    if ((t & 63) == 0) red[t >> 6] = s;
    __syncthreads();
    if (t == 0) red[4] = 1.0f / fmaxf(sqrtf(red[0] + red[1] + red[2] + red[3]), 1e-12f);
    __syncthreads();
    float inv = red[4];
    *(ushort4*)(op + i0) =
        make_ushort4(f2bf(o4[0] * inv), f2bf(o4[1] * inv), f2bf(o4[2] * inv), f2bf(o4[3] * inv));
}

// ---------------------------------------------------------------------------
// Stats reduces
// ---------------------------------------------------------------------------
__global__ void reduce_sim(const float2* __restrict__ part, float2* __restrict__ stats)
{
    float2 p = part[blockIdx.x * 64 + threadIdx.x];
    float s1 = p.x, s2 = p.y;
    #pragma unroll
    for (int off = 32; off > 0; off >>= 1) {
        s1 += __shfl_down(s1, off);
        s2 += __shfl_down(s2, off);
    }
    if (threadIdx.x == 0) stats[blockIdx.x] = make_float2(s1, s2);
}

__global__ void reduce_branch(const float2* __restrict__ part, float2* __restrict__ stats)
{
    const int br = blockIdx.x & 3, b = blockIdx.x >> 2;
    const int lo4[4] = {0, 1, 2, 4}, hi4[4] = {1, 2, 4, 8};
    float s1 = 0.f, s2 = 0.f;
    if (threadIdx.x < 8) {
        for (int my = lo4[br]; my < hi4[br]; ++my) {
            float2 p = part[(b * 8 + my) * 8 + threadIdx.x];
            s1 += p.x; s2 += p.y;
        }
    }
    #pragma unroll
    for (int off = 32; off > 0; off >>= 1) {
        s1 += __shfl_down(s1, off);
        s2 += __shfl_down(s2, off);
    }
    if (threadIdx.x == 0) stats[b * 4 + br] = make_float2(s1, s2);
}

// ---------------------------------------------------------------------------
// Instance-norm + softmax (row length 960), f32 in -> bf16 out (sim path).
// ---------------------------------------------------------------------------
__global__ __launch_bounds__(256)
void instnorm_softmax_bf16(const float* __restrict__ x, ushort_t* __restrict__ out,
                           const float2* __restrict__ stats, int rowsPerB, float invL)
{
    int row = blockIdx.x;
    int b = row / rowsPerB;
    float2 st = stats[b];
    float mean = st.x * invL;
    float var = st.y * invL - mean * mean;
    float rinv = rsqrtf(var + 1e-5f);
    const float* xr = x + (long)row * 960;
    ushort_t* orow = out + (long)row * 960;
    int t = threadIdx.x;
    float v[4];
    float mx = -1e30f;
    #pragma unroll
    for (int q = 0; q < 4; ++q) {
        int i = t + q * 256;
        if (i < 960) { v[q] = (xr[i] - mean) * rinv; mx = fmaxf(mx, v[q]); }
        else v[q] = -1e30f;
    }
    #pragma unroll
    for (int off = 32; off > 0; off >>= 1) mx = fmaxf(mx, __shfl_down(mx, off));
    __shared__ float rm[4];
    __shared__ float bmax, bsuminv;
    if ((t & 63) == 0) rm[t >> 6] = mx;
    __syncthreads();
    if (t == 0) bmax = fmaxf(fmaxf(rm[0], rm[1]), fmaxf(rm[2], rm[3]));
    __syncthreads();
    float mall = bmax;
    float s = 0.f;
    #pragma unroll
    for (int q = 0; q < 4; ++q) {
        int i = t + q * 256;
        if (i < 960) { v[q] = __expf(v[q] - mall); s += v[q]; }
    }
    #pragma unroll
    for (int off = 32; off > 0; off >>= 1) s += __shfl_down(s, off);
    if ((t & 63) == 0) rm[t >> 6] = s;
    __syncthreads();
    if (t == 0) bsuminv = 1.0f / (rm[0] + rm[1] + rm[2] + rm[3]);
    __syncthreads();
    float invS = bsuminv;
    #pragma unroll
    for (int q = 0; q < 4; ++q) {
        int i = t + q * 256;
        if (i < 960) orow[i] = f2bf(v[q] * invS);
    }
}

// ---------------------------------------------------------------------------
// Batched branch instnorm+softmax: rows [b][1024][960]; pad rows -> zeros.
// ---------------------------------------------------------------------------
__global__ __launch_bounds__(256)
void softmax_attn_kernel(const float* __restrict__ x, ushort_t* __restrict__ P,
                         const float2* __restrict__ stats)
{
    const int r = blockIdx.x & 1023, b = blockIdx.x >> 10;
    const int t = threadIdx.x;
    ushort_t* orow = P + ((long)(b << 10) + r) * 960;
    int br; float cnt;
    if (r < 64)       { br = 0; cnt = 64.f; }
    else if (r < 128) {
        #pragma unroll
        for (int q = 0; q < 4; ++q) {
            int i = t + q * 256;
            if (i < 960) orow[i] = 0;
        }
        return;
    }
    else if (r < 256) { br = 1; cnt = 128.f; }
    else if (r < 512) { br = 2; cnt = 256.f; }
    else              { br = 3; cnt = 512.f; }
    float invL = 1.0f / (cnt * 960.f);
    float2 st = stats[b * 4 + br];
    float mean = st.x * invL;
    float var = st.y * invL - mean * mean;
    float rinv = rsqrtf(var + 1e-5f);
    const float* xr = x + ((long)(b << 10) + r) * 960;
    float v[4];
    float mx = -1e30f;
    #pragma unroll
    for (int q = 0; q < 4; ++q) {
        int i = t + q * 256;
        if (i < 960) { v[q] = (xr[i] - mean) * rinv; mx = fmaxf(mx, v[q]); }
        else v[q] = -1e30f;
    }
    #pragma unroll
    for (int off = 32; off > 0; off >>= 1) mx = fmaxf(mx, __shfl_down(mx, off));
    __shared__ float rm[4];
    __shared__ float bmax, bsuminv;
    if ((t & 63) == 0) rm[t >> 6] = mx;
    __syncthreads();
    if (t == 0) bmax = fmaxf(fmaxf(rm[0], rm[1]), fmaxf(rm[2], rm[3]));
    __syncthreads();
    float mall = bmax;
    float s = 0.f;
    #pragma unroll
    for (int q = 0; q < 4; ++q) {
        int i = t + q * 256;
        if (i < 960) { v[q] = __expf(v[q] - mall); s += v[q]; }
    }
    #pragma unroll
    for (int off = 32; off > 0; off >>= 1) s += __shfl_down(s, off);
    if ((t & 63) == 0) rm[t >> 6] = s;
    __syncthreads();
    if (t == 0) bsuminv = 1.0f / (rm[0] + rm[1] + rm[2] + rm[3]);
    __syncthreads();
    float invS = bsuminv;
    #pragma unroll
    for (int q = 0; q < 4; ++q) {
        int i = t + q * 256;
        if (i < 960) orow[i] = f2bf(v[q] * invS);
    }
}

// ---------------------------------------------------------------------------

extern "C" void kernel_launch(void* const* d_in, const int* in_sizes, int n_in,
                              void* d_out, int out_size, void* d_ws, size_t ws_size,
                              hipStream_t stream)
{
    const float* emb[4]  = {(const float*)d_in[0], (const float*)d_in[1],
                            (const float*)d_in[2], (const float*)d_in[3]};
    const float* emb_all = (const float*)d_in[4];
    const float* w_mh[4] = {(const float*)d_in[5], (const float*)d_in[6],
                            (const float*)d_in[7], (const float*)d_in[8]};
    const float* w_mq = (const float*)d_in[9];
    const float* w_mk = (const float*)d_in[10];
    const float* w_mv = (const float*)d_in[11];
    const float* w_q[4] = {(const float*)d_in[12], (const float*)d_in[13],
                           (const float*)d_in[14], (const float*)d_in[15]};
    const float* w_qc = (const float*)d_in[16];
    const float* w_kc = (const float*)d_in[17];
    const float* w_vc = (const float*)d_in[18];
    const float* w_proj[4] = {(const float*)d_in[19], (const float*)d_in[20],
                              (const float*)d_in[21], (const float*)d_in[22]};
    float* out = (float*)d_out;

    // ---- arena (element offsets into ushort_t* U) ----
    ushort_t* U = (ushort_t*)d_ws;
    const long eWQKV = 0;          // 2,764,800  (WQ|WK|WV, k-contig rows)
    const long eWMH  = 2764800;    // 348,160
    const long eWPJ  = 3112960;    // 348,160
    const long eR1   = 3461120;    // embT_all -> Vc -> ctx       (7,864,320)
    const long eR2   = 11325440;   // embT_i  -> VcT -> ctxT      (7,864,320)
    const long eR3   = 19189760;   // Xqkv (23,592,960) -> S6 f32(15,728,640 us) + Pc -> oT
    const long ePc   = 34918400;   // Pc (7,372,800) ends 42,291,200
    const long eR4   = 42782720;   // mh_x -> P_all               (8,388,608)
    const long eQc   = 51171328;   // Qc (7,864,320)
    const long eKc   = 59035648;   // Kc (7,864,320)
    const long eQall = 66899968;   // q_all (8,388,608) ends 75,288,576
    float2* part  = (float2*)(U + 75288576);
    float2* stats = part + 512;

    ushort_t* WQKVb = U + eWQKV;
    ushort_t* WMHb  = U + eWMH;
    ushort_t* WPJb  = U + eWPJ;
    ushort_t* embT_all = U + eR1;
    ushort_t* Vc    = U + eR1;
    ushort_t* ctx   = U + eR1;
    ushort_t* VcT   = U + eR2;
    ushort_t* ctxT  = U + eR2;
    ushort_t* Xqkv  = U + eR3;
    float*    S6    = (float*)(U + eR3);
    ushort_t* oT    = U + eR3;
    ushort_t* Pc    = U + ePc;
    ushort_t* mh_x  = U + eR4;
    ushort_t* P_all = U + eR4;
    ushort_t* QcB   = U + eQc;
    ushort_t* KcB   = U + eKc;
    ushort_t* q_all = U + eQall;
    ushort_t* embT_i[4] = {U + eR2, U + eR2 + 524288, U + eR2 + 1572864, U + eR2 + 3670016};

    const float scale = 0.0322748612183951400f;   // 1/sqrt(960)
    const long SB = (long)KVC * HWN;              // 983040
    const long S1024 = 1024L * 1024;
    const int CH[4] = {64, 128, 256, 512};
    const int mhoff[4] = {0, 4096, 20480, 86016};
    const int rowOff[4] = {0, 128, 256, 512};
    const long outOff[4] = {0, 524288, 1572864, 3670016};
    dim3 blk(256);

    // ---- f2b weights (plain) ----
    {
        F2BTab tf;
        const float* fs[11] = {w_mq, w_mk, w_mv, w_mh[0], w_mh[1], w_mh[2], w_mh[3],
                               w_proj[0], w_proj[1], w_proj[2], w_proj[3]};
        long fd[11] = {eWQKV, eWQKV + 921600, eWQKV + 1843200,
                       eWMH + 0, eWMH + 4096, eWMH + 20480, eWMH + 86016,
                       eWPJ + 0, eWPJ + 4096, eWPJ + 20480, eWPJ + 86016};
        int fn[11] = {900, 900, 900, 4, 16, 64, 256, 4, 16, 64, 256};
        int ftot = 0;
        for (int i = 0; i < 11; ++i) { tf.src[i] = fs[i]; tf.dstOff[i] = fd[i]; tf.nblk[i] = fn[i]; ftot += fn[i]; }
        tf.nseg = 11;
        f2b_batched<<<ftot, blk, 0, stream>>>(tf, U);
    }
    // ---- f2bT embeddings (transpose-convert) ----
    {
        F2TTab tt;
        const float* ts[5] = {emb_all, emb[0], emb[1], emb[2], emb[3]};
        long td[5] = {eR1, eR2, eR2 + 524288, eR2 + 1572864, eR2 + 3670016};
        int tR[5] = {960, 64, 128, 256, 512};
        int tn[5];
        long tsi[5], tso[5];
        int ttot = 0;
        for (int i = 0; i < 5; ++i) {
            tsi[i] = (long)tR[i] * 1024; tso[i] = tsi[i];
            tn[i] = NB * (tR[i] / 64) * 16; ttot += tn[i];
            tt.src[i] = ts[i]; tt.dstOff[i] = td[i]; tt.R[i] = tR[i];
            tt.sIn[i] = tsi[i]; tt.sOut[i] = tso[i]; tt.nblk[i] = tn[i];
        }
        tt.nseg = 5;
        f2bt_batched<<<ttot, blk, 0, stream>>>(tt, U);
    }

    auto nt1 = [&](const ushort_t* A, long sA, const ushort_t* B, long sB, long ldb,
                   void* C, long sC, int M, int K, int obf) {
        NTTab tb;
        for (int s = 0; s < 5; ++s) {
            tb.A[s] = A; tb.B[s] = B; tb.C[s] = C;
            tb.sA[s] = sA; tb.sB[s] = sB; tb.sC[s] = sC; tb.ldb[s] = ldb;
            tb.M[s] = M; tb.K[s] = K; tb.obf[s] = obf; tb.mt0[s] = (s == 0) ? 0 : (1 << 30);
        }
        tb.nseg = 1;
        dim3 g(NB, (M + 127) / 128, 8);
        mfma_gemm_nt_tab<<<g, blk, 0, stream>>>(tb);
    };

    // ---- stage 1: QKV (M=2880) + 4x mhead conv1x1, one NT launch ----
    {
        NTTab tb;
        tb.A[0] = WQKVb; tb.B[0] = embT_all; tb.C[0] = Xqkv;
        tb.sA[0] = 0; tb.sB[0] = SB; tb.sC[0] = 2880L * 1024; tb.ldb[0] = 960;
        tb.M[0] = 2880; tb.K[0] = 960; tb.obf[0] = 1; tb.mt0[0] = 0;
        int mt = 23;
        for (int i = 0; i < 4; ++i) {
            tb.A[1 + i] = WMHb + mhoff[i]; tb.B[1 + i] = embT_i[i];
            tb.C[1 + i] = mh_x + (long)rowOff[i] * 1024;
            tb.sA[1 + i] = 0; tb.sB[1 + i] = (long)CH[i] * 1024; tb.sC[1 + i] = S1024;
            tb.ldb[1 + i] = CH[i];
            tb.M[1 + i] = CH[i]; tb.K[1 + i] = CH[i]; tb.obf[1 + i] = 1; tb.mt0[1 + i] = mt;
            mt += (CH[i] + 127) / 128;
        }
        tb.nseg = 5;
        dim3 g(NB, mt, 8);   // (8, 31, 8): x = batch -> XCD
        mfma_gemm_nt_tab<<<g, blk, 0, stream>>>(tb);
    }

    // ---- stencils: dw(Q,K,V) + gconv, one launch ----
    stencil_all<<<31232, blk, 0, stream>>>(Xqkv, mh_x, w_qc, w_kc, w_vc,
                                           w_q[0], w_q[1], w_q[2], w_q[3],
                                           QcB, KcB, Vc, q_all);

    // ---- Vc -> VcT ----
    trb_kernel<<<dim3(16, 15, NB), blk, 0, stream>>>(Vc, VcT);

    // ---- sim = Qc @ Kc^T * scale + stats ----
    mfma_gemm_nt_stats<<<dim3(NB, 8, 8), blk, 0, stream>>>(
        QcB, KcB, S6, part, KVC, KVC, HWN, SB, SB, (long)KVC * KVC, scale);
    reduce_sim<<<NB, 64, 0, stream>>>(part, stats);
    instnorm_softmax_bf16<<<NB * KVC, blk, 0, stream>>>(S6, Pc, stats, KVC,
                                                        1.f / ((float)KVC * (float)KVC));

    // ---- ctx = NT(Pc, VcT) -> [960][1024] bf16 ----
    nt1(Pc, (long)KVC * KVC, VcT, SB, 960, ctx, SB, KVC, KVC, 1);

    // ---- ctx -> ctxT ----
    trb_kernel<<<dim3(16, 15, NB), blk, 0, stream>>>(ctx, ctxT);

    // ---- attn = q_all @ ctx^T * scale + stats ----
    mfma_gemm_nt_stats<<<dim3(NB, 8, 8), blk, 0, stream>>>(
        q_all, ctx, S6, part, 1024, KVC, HWN, S1024, SB, SB, scale);
    reduce_branch<<<32, 64, 0, stream>>>(part, stats);
    softmax_attn_kernel<<<NB * 1024, blk, 0, stream>>>(S6, P_all, stats);

    // ---- oT = NT(ctxT, P_all) -> [1024 hw][1024 ch] bf16 ----
    nt1(ctxT, SB, P_all, SB, 960, oT, S1024, 1024, KVC, 1);

    // ---- proj: 4 branches, one NT table launch (f32 out) ----
    {
        NTTab tb;
        int mt = 0;
        for (int i = 0; i < 4; ++i) {
            tb.A[i] = WPJb + mhoff[i]; tb.B[i] = oT + rowOff[i];
            tb.C[i] = out + outOff[i];
            tb.sA[i] = 0; tb.sB[i] = S1024; tb.sC[i] = (long)CH[i] * 1024;
            tb.ldb[i] = 1024;
            tb.M[i] = CH[i]; tb.K[i] = CH[i]; tb.obf[i] = 0; tb.mt0[i] = mt;
            mt += (CH[i] + 127) / 128;
        }
        tb.A[4] = tb.A[3]; tb.B[4] = tb.B[3]; tb.C[4] = tb.C[3];
        tb.sA[4] = 0; tb.sB[4] = 0; tb.sC[4] = 0; tb.ldb[4] = 1024;
        tb.M[4] = 1; tb.K[4] = 64; tb.obf[4] = 0; tb.mt0[4] = 1 << 30;
        tb.nseg = 4;
        dim3 g(NB, mt, 8);   // (8, 8, 8)
        mfma_gemm_nt_tab<<<g, blk, 0, stream>>>(tb);
    }

    (void)in_sizes; (void)n_in; (void)out_size; (void)ws_size;
}

// Round 8
// 281.000 us; speedup vs baseline: 7.8901x; 1.0810x over previous
//
#include <hip/hip_runtime.h>
#include <hip/hip_bf16.h>
#include <math.h>

#define NB 8
#define HWN 1024
#define KVC 960

typedef short bf16x8 __attribute__((ext_vector_type(8)));
typedef float f32x4 __attribute__((ext_vector_type(4)));
typedef unsigned short ushort_t;

__device__ inline ushort_t f2bf(float f) {
    __hip_bfloat16 h = __float2bfloat16(f);
    return *reinterpret_cast<ushort_t*>(&h);
}
__device__ inline float bf2f(ushort_t u) {
    union { float f; unsigned int i; } x; x.i = ((unsigned int)u) << 16; return x.f;
}
__device__ inline void glds16(const ushort_t* src, ushort_t* dst) {
    __builtin_amdgcn_global_load_lds(
        (const __attribute__((address_space(1))) void*)src,
        (__attribute__((address_space(3))) void*)dst, 16, 0, 0);
}

// ---------------------------------------------------------------------------
// Batched f32 -> bf16 convert (no transpose). 1024 elems per block.
// ---------------------------------------------------------------------------
struct F2BTab {
    const float* src[12];
    long dstOff[12];
    int nblk[12];
    int nseg;
};

__global__ __launch_bounds__(256)
void f2b_batched(F2BTab tab, ushort_t* base)
{
    int b = blockIdx.x, s = 0;
    while (s < tab.nseg - 1 && b >= tab.nblk[s]) { b -= tab.nblk[s]; ++s; }
    float4 v = *((const float4*)tab.src[s] + (long)b * 256 + threadIdx.x);
    ushort4 o = make_ushort4(f2bf(v.x), f2bf(v.y), f2bf(v.z), f2bf(v.w));
    *((ushort4*)(base + tab.dstOff[s]) + (long)b * 256 + threadIdx.x) = o;
}

// ---------------------------------------------------------------------------
// Batched f32 -> bf16 transpose-convert: in [b][R][1024] f32 -> out [b][1024][R].
// ---------------------------------------------------------------------------
struct F2TTab {
    const float* src[5];
    long dstOff[5];
    long sIn[5], sOut[5];
    int R[5];
    int nblk[5];
    int nseg;
};

__global__ __launch_bounds__(256)
void f2bt_batched(F2TTab tab, ushort_t* base)
{
    __shared__ ushort_t tile[64][65];
    int b = blockIdx.x, s = 0;
    while (s < tab.nseg - 1 && b >= tab.nblk[s]) { b -= tab.nblk[s]; ++s; }
    const int R = tab.R[s];
    const int tpb = (R >> 6) * 16;
    const int batch = b / tpb, rem = b - batch * tpb;
    const int rtile = rem >> 4, ctile = rem & 15;
    const float* ib = tab.src[s] + (long)batch * tab.sIn[s] + (long)(rtile * 64) * 1024 + ctile * 64;
    const int t = threadIdx.x, tr = t >> 4, tc = (t & 15) * 4;
    #pragma unroll
    for (int p = 0; p < 4; ++p) {
        float4 v = *(const float4*)(ib + (long)(tr + 16 * p) * 1024 + tc);
        tile[tr + 16 * p][tc + 0] = f2bf(v.x);
        tile[tr + 16 * p][tc + 1] = f2bf(v.y);
        tile[tr + 16 * p][tc + 2] = f2bf(v.z);
        tile[tr + 16 * p][tc + 3] = f2bf(v.w);
    }
    __syncthreads();
    ushort_t* ob = base + tab.dstOff[s] + (long)batch * tab.sOut[s]
                 + (long)(ctile * 64) * R + rtile * 64;
    #pragma unroll
    for (int p = 0; p < 4; ++p) {
        ushort4 v;
        v.x = tile[tc + 0][tr + 16 * p];
        v.y = tile[tc + 1][tr + 16 * p];
        v.z = tile[tc + 2][tr + 16 * p];
        v.w = tile[tc + 3][tr + 16 * p];
        *(ushort4*)(ob + (long)(tr + 16 * p) * R + tc) = v;
    }
}

// ---------------------------------------------------------------------------
// bf16 transpose: in [b][960][1024] -> out [b][1024][960]. grid (16,15,NB).
// ---------------------------------------------------------------------------
__global__ __launch_bounds__(256)
void trb_kernel(const ushort_t* __restrict__ in, ushort_t* __restrict__ out)
{
    __shared__ ushort_t tile[64][65];
    const int r0 = blockIdx.y * 64, c0 = blockIdx.x * 64;
    const long sP = (long)KVC * HWN;
    const ushort_t* ib = in + (long)blockIdx.z * sP;
    ushort_t* ob = out + (long)blockIdx.z * sP;
    const int t = threadIdx.x, tr = t >> 4, tc = (t & 15) * 4;
    #pragma unroll
    for (int p = 0; p < 4; ++p) {
        ushort4 v = *(const ushort4*)(ib + (long)(r0 + tr + 16 * p) * 1024 + c0 + tc);
        tile[tr + 16 * p][tc + 0] = v.x;
        tile[tr + 16 * p][tc + 1] = v.y;
        tile[tr + 16 * p][tc + 2] = v.z;
        tile[tr + 16 * p][tc + 3] = v.w;
    }
    __syncthreads();
    #pragma unroll
    for (int p = 0; p < 4; ++p) {
        ushort4 v;
        v.x = tile[tc + 0][tr + 16 * p];
        v.y = tile[tc + 1][tr + 16 * p];
        v.z = tile[tc + 2][tr + 16 * p];
        v.w = tile[tc + 3][tr + 16 * p];
        *(ushort4*)(ob + (long)(c0 + tr + 16 * p) * 960 + r0 + tc) = v;
    }
}

// ---------------------------------------------------------------------------
// bf16 MFMA GEMM NT + fused instnorm stats. BK=64, 2-phase dbuf, counted
// vmcnt(4). 512 threads / 8 waves (wave tile 32x64). Grid (NB, N/128, M/128):
// x = batch -> XCD, y = N-tile (inner, L2-reuses A-panel), z = M-tile.
// ---------------------------------------------------------------------------
__global__ __launch_bounds__(512)
void mfma_gemm_nt_stats(const ushort_t* __restrict__ A, const ushort_t* __restrict__ B,
                        float* __restrict__ C, float2* __restrict__ part,
                        int M, int N, int K, long sA, long sB, long sC, float alpha)
{
    __shared__ __align__(16) ushort_t lA[2][128 * 64];
    __shared__ __align__(16) ushort_t lB[2][128 * 64];
    const int bb = blockIdx.x;
    const int by = blockIdx.z, bx = blockIdx.y;   // by = M-tile, bx = N-tile
    const ushort_t* Ab = A + (long)bb * sA;
    const ushort_t* Bb = B + (long)bb * sB;
    const int row0 = by * 128, col0 = bx * 128;
    const int t = threadIdx.x, lane = t & 63, w = t >> 6;
    const int wr = w >> 1, wc = w & 1;
    const int arl = lane >> 3;
    const int acs = ((lane & 7) ^ arl) * 8;
    int arow[2], brow[2];
    #pragma unroll
    for (int j = 0; j < 2; ++j) {
        int r = row0 + w * 16 + j * 8 + arl;  arow[j] = r < M ? r : M - 1;
        int rb = col0 + w * 16 + j * 8 + arl; brow[j] = rb < N ? rb : N - 1;
    }

    f32x4 acc[2][4];
    #pragma unroll
    for (int m = 0; m < 2; ++m)
        #pragma unroll
        for (int n = 0; n < 4; ++n)
            acc[m][n] = (f32x4){0.f, 0.f, 0.f, 0.f};

    auto stage = [&](int buf, int k0) {
        #pragma unroll
        for (int j = 0; j < 2; ++j) {
            glds16(Ab + (long)arow[j] * K + k0 + acs, lA[buf] + (w * 16 + j * 8) * 64);
            glds16(Bb + (long)brow[j] * K + k0 + acs, lB[buf] + (w * 16 + j * 8) * 64);
        }
    };
    auto compute = [&](int buf) {
        __builtin_amdgcn_s_setprio(1);
        #pragma unroll
        for (int sub = 0; sub < 2; ++sub) {
            const int kc = (lane >> 4) + sub * 4;
            bf16x8 aF[2], bF[4];
            #pragma unroll
            for (int m = 0; m < 2; ++m) {
                int rl = wr * 32 + m * 16 + (lane & 15);
                aF[m] = *(const bf16x8*)(lA[buf] + rl * 64 + (kc ^ (rl & 7)) * 8);
            }
            #pragma unroll
            for (int n = 0; n < 4; ++n) {
                int rl = wc * 64 + n * 16 + (lane & 15);
                bF[n] = *(const bf16x8*)(lB[buf] + rl * 64 + (kc ^ (rl & 7)) * 8);
            }
            #pragma unroll
            for (int m = 0; m < 2; ++m)
                #pragma unroll
                for (int n = 0; n < 4; ++n)
                    acc[m][n] = __builtin_amdgcn_mfma_f32_16x16x32_bf16(aF[m], bF[n], acc[m][n], 0, 0, 0);
        }
        __builtin_amdgcn_s_setprio(0);
    };

    stage(0, 0);
    int cur = 0;
    for (int k0 = 64; k0 < K; k0 += 64) {
        stage(cur ^ 1, k0);
        asm volatile("s_waitcnt vmcnt(4)" ::: "memory");
        __builtin_amdgcn_sched_barrier(0);
        __builtin_amdgcn_s_barrier();
        compute(cur);
        __builtin_amdgcn_s_barrier();
        cur ^= 1;
    }
    asm volatile("s_waitcnt vmcnt(0)" ::: "memory");
    __builtin_amdgcn_sched_barrier(0);
    __builtin_amdgcn_s_barrier();
    compute(cur);

    const int cr0 = row0 + wr * 32 + (lane >> 4) * 4;
    const int cc0 = col0 + wc * 64 + (lane & 15);
    float* Cb = C + (long)bb * sC;
    float s1 = 0.f, s2 = 0.f;
    #pragma unroll
    for (int m = 0; m < 2; ++m) {
        #pragma unroll
        for (int n = 0; n < 4; ++n) {
            int ccol = cc0 + n * 16;
            if (ccol >= N) continue;
            #pragma unroll
            for (int r = 0; r < 4; ++r) {
                int crow = cr0 + m * 16 + r;
                if (crow < M) {
                    float v = acc[m][n][r] * alpha;
                    Cb[(long)crow * N + ccol] = v;
                    s1 += v; s2 += v * v;
                }
            }
        }
    }
    #pragma unroll
    for (int off = 32; off > 0; off >>= 1) {
        s1 += __shfl_down(s1, off);
        s2 += __shfl_down(s2, off);
    }
    __syncthreads();               // all ds_reads of lA done before aliasing
    float* rbuf = (float*)lA;
    if (lane == 0) { rbuf[w] = s1; rbuf[8 + w] = s2; }
    __syncthreads();
    if (t == 0) {
        float a1 = 0.f, a2 = 0.f;
        #pragma unroll
        for (int q = 0; q < 8; ++q) { a1 += rbuf[q]; a2 += rbuf[8 + q]; }
        part[((long)bb * 8 + by) * 8 + bx] = make_float2(a1, a2);
    }
}

// ---------------------------------------------------------------------------
// Table-driven bf16 MFMA GEMM NT, BK=64, N fixed 1024, 512 thr / 8 waves.
// Grid (NB, 8, mt): x = batch, y = N-tile (inner), z = segmented M-tile.
// ---------------------------------------------------------------------------
struct NTTab {
    const ushort_t* A[5];
    const ushort_t* B[5];
    void* C[5];
    long sA[5], sB[5], sC[5], ldb[5];
    int M[5], K[5], obf[5], mt0[5];
    int nseg;
};

__global__ __launch_bounds__(512)
void mfma_gemm_nt_tab(NTTab tab)
{
    __shared__ __align__(16) ushort_t lA[2][128 * 64];
    __shared__ __align__(16) ushort_t lB[2][128 * 64];
    const int bb = blockIdx.x;
    int si = 0;
    #pragma unroll
    for (int s = 1; s < 5; ++s)
        if (s < tab.nseg && (int)blockIdx.z >= tab.mt0[s]) si = s;
    const int M = tab.M[si], K = tab.K[si];
    const long ldb = tab.ldb[si];
    const ushort_t* Ab = tab.A[si] + (long)bb * tab.sA[si];
    const ushort_t* Bb = tab.B[si] + (long)bb * tab.sB[si];
    const int row0 = (blockIdx.z - tab.mt0[si]) * 128, col0 = blockIdx.y * 128;
    const int t = threadIdx.x, lane = t & 63, w = t >> 6;
    const int wr = w >> 1, wc = w & 1;
    const int arl = lane >> 3;
    const int acs = ((lane & 7) ^ arl) * 8;
    int arow[2], brow[2];
    #pragma unroll
    for (int j = 0; j < 2; ++j) {
        int r = row0 + w * 16 + j * 8 + arl;
        arow[j] = r < M ? r : M - 1;
        brow[j] = col0 + w * 16 + j * 8 + arl;   // N=1024, always valid
    }

    f32x4 acc[2][4];
    #pragma unroll
    for (int m = 0; m < 2; ++m)
        #pragma unroll
        for (int n = 0; n < 4; ++n)
            acc[m][n] = (f32x4){0.f, 0.f, 0.f, 0.f};

    auto stage = [&](int buf, int k0) {
        #pragma unroll
        for (int j = 0; j < 2; ++j) {
            glds16(Ab + (long)arow[j] * K + k0 + acs, lA[buf] + (w * 16 + j * 8) * 64);
            glds16(Bb + (long)brow[j] * ldb + k0 + acs, lB[buf] + (w * 16 + j * 8) * 64);
        }
    };
    auto compute = [&](int buf) {
        __builtin_amdgcn_s_setprio(1);
        #pragma unroll
        for (int sub = 0; sub < 2; ++sub) {
            const int kc = (lane >> 4) + sub * 4;
            bf16x8 aF[2], bF[4];
            #pragma unroll
            for (int m = 0; m < 2; ++m) {
                int rl = wr * 32 + m * 16 + (lane & 15);
                aF[m] = *(const bf16x8*)(lA[buf] + rl * 64 + (kc ^ (rl & 7)) * 8);
            }
            #pragma unroll
            for (int n = 0; n < 4; ++n) {
                int rl = wc * 64 + n * 16 + (lane & 15);
                bF[n] = *(const bf16x8*)(lB[buf] + rl * 64 + (kc ^ (rl & 7)) * 8);
            }
            #pragma unroll
            for (int m = 0; m < 2; ++m)
                #pragma unroll
                for (int n = 0; n < 4; ++n)
                    acc[m][n] = __builtin_amdgcn_mfma_f32_16x16x32_bf16(aF[m], bF[n], acc[m][n], 0, 0, 0);
        }
        __builtin_amdgcn_s_setprio(0);
    };

    stage(0, 0);
    int cur = 0;
    for (int k0 = 64; k0 < K; k0 += 64) {
        stage(cur ^ 1, k0);
        asm volatile("s_waitcnt vmcnt(4)" ::: "memory");
        __builtin_amdgcn_sched_barrier(0);
        __builtin_amdgcn_s_barrier();
        compute(cur);
        __builtin_amdgcn_s_barrier();
        cur ^= 1;
    }
    asm volatile("s_waitcnt vmcnt(0)" ::: "memory");
    __builtin_amdgcn_sched_barrier(0);
    __builtin_amdgcn_s_barrier();
    compute(cur);

    const int cr0 = row0 + wr * 32 + (lane >> 4) * 4;
    const int cc0 = col0 + wc * 64 + (lane & 15);
    const int obf = tab.obf[si];
    ushort_t* Cb_b = (ushort_t*)tab.C[si] + (long)bb * tab.sC[si];
    float* Cb_f = (float*)tab.C[si] + (long)bb * tab.sC[si];
    #pragma unroll
    for (int m = 0; m < 2; ++m) {
        #pragma unroll
        for (int n = 0; n < 4; ++n) {
            int ccol = cc0 + n * 16;
            #pragma unroll
            for (int r = 0; r < 4; ++r) {
                int crow = cr0 + m * 16 + r;
                if (crow < M) {
                    float v = acc[m][n][r];
                    if (obf) Cb_b[(long)crow * 1024 + ccol] = f2bf(v);
                    else     Cb_f[(long)crow * 1024 + ccol] = v;
                }
            }
        }
    }
}

// ---------------------------------------------------------------------------
// Fused stencil launch: depthwise 3x3 on Q/K/V (l2norm on Q,K) + grouped
// 3x3 conv + l2norm for all branches.
// ---------------------------------------------------------------------------
__global__ __launch_bounds__(256)
void stencil_all(const ushort_t* __restrict__ Xqkv, const ushort_t* __restrict__ mh_x,
                 const float* __restrict__ w_qc, const float* __restrict__ w_kc,
                 const float* __restrict__ w_vc,
                 const float* __restrict__ wq1, const float* __restrict__ wq2,
                 const float* __restrict__ wq3, const float* __restrict__ wq4,
                 ushort_t* __restrict__ Qc, ushort_t* __restrict__ Kc,
                 ushort_t* __restrict__ Vc, ushort_t* __restrict__ q_all)
{
    __shared__ float p0[32 * 33];
    __shared__ float p1[32 * 33];
    __shared__ float red[5];
    const int bid = blockIdx.x;
    const int t = threadIdx.x;
    const int i0 = t * 4, y = i0 >> 5, x0 = i0 & 31;

    if (bid < 23040) {
        const int which = bid / 7680;
        const int p = bid - which * 7680;
        const int b = p / 960, c = p - b * 960;
        const ushort_t* ip = Xqkv + ((long)b * 2880 + which * 960 + c) * 1024;
        const float* wgt = (which == 0 ? w_qc : which == 1 ? w_kc : w_vc) + c * 9;
        ushort_t* op = (which == 0 ? Qc : which == 1 ? Kc : Vc) + (long)p * 1024;
        ushort4 u = *(const ushort4*)(ip + i0);
        float* rw = p0 + y * 33 + x0;
        rw[0] = bf2f(u.x); rw[1] = bf2f(u.y); rw[2] = bf2f(u.z); rw[3] = bf2f(u.w);
        __syncthreads();
        float W[9];
        #pragma unroll
        for (int q = 0; q < 9; ++q) W[q] = wgt[q];
        float r[3][6];
        #pragma unroll
        for (int dy = 0; dy < 3; ++dy) {
            int yy = y + dy - 1;
            bool vy = (unsigned)yy < 32u;
            #pragma unroll
            for (int j = 0; j < 6; ++j) {
                int xx = x0 - 1 + j;
                r[dy][j] = (vy && (unsigned)xx < 32u) ? p0[yy * 33 + xx] : 0.f;
            }
        }
        float o[4];
        #pragma unroll
        for (int q = 0; q < 4; ++q)
            o[q] = r[0][q] * W[0] + r[0][q + 1] * W[1] + r[0][q + 2] * W[2]
                 + r[1][q] * W[3] + r[1][q + 1] * W[4] + r[1][q + 2] * W[5]
                 + r[2][q] * W[6] + r[2][q + 1] * W[7] + r[2][q + 2] * W[8];
        float inv = 1.f;
        if (which < 2) {
            float s = o[0] * o[0] + o[1] * o[1] + o[2] * o[2] + o[3] * o[3];
            #pragma unroll
            for (int off = 32; off > 0; off >>= 1) s += __shfl_down(s, off);
            if ((t & 63) == 0) red[t >> 6] = s;
            __syncthreads();
            if (t == 0) red[4] = 1.0f / fmaxf(sqrtf(red[0] + red[1] + red[2] + red[3]), 1e-12f);
            __syncthreads();
            inv = red[4];
        }
        *(ushort4*)(op + i0) =
            make_ushort4(f2bf(o[0] * inv), f2bf(o[1] * inv), f2bf(o[2] * inv), f2bf(o[3] * inv));
        return;
    }
    const int po = bid - 23040;
    const int o = po & 1023, b = po >> 10;
    ushort_t* op = q_all + (long)po * 1024;
    int off; const float* wbase;
    if (o < 64)       { off = 0;   wbase = wq1; }
    else if (o < 128) { *(ushort4*)(op + i0) = make_ushort4(0, 0, 0, 0); return; }
    else if (o < 256) { off = 128; wbase = wq2; }
    else if (o < 512) { off = 256; wbase = wq3; }
    else              { off = 512; wbase = wq4; }
    const int ol = o - off;
    const int g2 = ol & ~1;
    const ushort_t* ip0 = mh_x + ((long)(b << 10) + off + g2) * 1024;
    const ushort_t* ip1 = ip0 + 1024;
    ushort4 u0 = *(const ushort4*)(ip0 + i0);
    ushort4 u1 = *(const ushort4*)(ip1 + i0);
    float* r0w = p0 + y * 33 + x0;
    float* r1w = p1 + y * 33 + x0;
    r0w[0] = bf2f(u0.x); r0w[1] = bf2f(u0.y); r0w[2] = bf2f(u0.z); r0w[3] = bf2f(u0.w);
    r1w[0] = bf2f(u1.x); r1w[1] = bf2f(u1.y); r1w[2] = bf2f(u1.z); r1w[3] = bf2f(u1.w);
    __syncthreads();
    const float* wp = wbase + ol * 18;
    float W[18];
    #pragma unroll
    for (int q = 0; q < 18; ++q) W[q] = wp[q];
    float o4[4] = {0.f, 0.f, 0.f, 0.f};
    #pragma unroll
    for (int pl = 0; pl < 2; ++pl) {
        const float* src = pl ? p1 : p0;
        const float* Wp = W + pl * 9;
        float r[3][6];
        #pragma unroll
        for (int dy = 0; dy < 3; ++dy) {
            int yy = y + dy - 1;
            bool vy = (unsigned)yy < 32u;
            #pragma unroll
            for (int j = 0; j < 6; ++j) {
                int xx = x0 - 1 + j;
                r[dy][j] = (vy && (unsigned)xx < 32u) ? src[yy * 33 + xx] : 0.f;
            }
        }
        #pragma unroll
        for (int q = 0; q < 4; ++q)
            o4[q] += r[0][q] * Wp[0] + r[0][q + 1] * Wp[1] + r[0][q + 2] * Wp[2]
                   + r[1][q] * Wp[3] + r[1][q + 1] * Wp[4] + r[1][q + 2] * Wp[5]
                   + r[2][q] * Wp[6] + r[2][q + 1] * Wp[7] + r[2][q + 2] * Wp[8];
    }
    float s = o4[0] * o4[0] + o4[1] * o4[1] + o4[2] * o4[2] + o4[3] * o4[3];
    #pragma unroll
    for (int off2 = 32; off2 > 0; off2 >>= 1) s += __shfl_down(s, off2);
    if ((t & 63) == 0) red[t >> 6] = s;
    __syncthreads();
    if (t == 0) red[4] = 1.0f / fmaxf(sqrtf(red[0] + red[1] + red[2] + red[3]), 1e-12f);
    __syncthreads();
    float inv = red[4];
    *(ushort4*)(op + i0) =
        make_ushort4(f2bf(o4[0] * inv), f2bf(o4[1] * inv), f2bf(o4[2] * inv), f2bf(o4[3] * inv));
}

// ---------------------------------------------------------------------------
// Stats reduces
// ---------------------------------------------------------------------------
__global__ void reduce_sim(const float2* __restrict__ part, float2* __restrict__ stats)
{
    float2 p = part[blockIdx.x * 64 + threadIdx.x];
    float s1 = p.x, s2 = p.y;
    #pragma unroll
    for (int off = 32; off > 0; off >>= 1) {
        s1 += __shfl_down(s1, off);
        s2 += __shfl_down(s2, off);
    }
    if (threadIdx.x == 0) stats[blockIdx.x] = make_float2(s1, s2);
}

__global__ void reduce_branch(const float2* __restrict__ part, float2* __restrict__ stats)
{
    const int br = blockIdx.x & 3, b = blockIdx.x >> 2;
    const int lo4[4] = {0, 1, 2, 4}, hi4[4] = {1, 2, 4, 8};
    float s1 = 0.f, s2 = 0.f;
    if (threadIdx.x < 8) {
        for (int my = lo4[br]; my < hi4[br]; ++my) {
            float2 p = part[(b * 8 + my) * 8 + threadIdx.x];
            s1 += p.x; s2 += p.y;
        }
    }
    #pragma unroll
    for (int off = 32; off > 0; off >>= 1) {
        s1 += __shfl_down(s1, off);
        s2 += __shfl_down(s2, off);
    }
    if (threadIdx.x == 0) stats[b * 4 + br] = make_float2(s1, s2);
}

// ---------------------------------------------------------------------------
// Instance-norm + softmax (row length 960), f32 in -> bf16 out (sim path).
// ---------------------------------------------------------------------------
__global__ __launch_bounds__(256)
void instnorm_softmax_bf16(const float* __restrict__ x, ushort_t* __restrict__ out,
                           const float2* __restrict__ stats, int rowsPerB, float invL)
{
    int row = blockIdx.x;
    int b = row / rowsPerB;
    float2 st = stats[b];
    float mean = st.x * invL;
    float var = st.y * invL - mean * mean;
    float rinv = rsqrtf(var + 1e-5f);
    const float* xr = x + (long)row * 960;
    ushort_t* orow = out + (long)row * 960;
    int t = threadIdx.x;
    float v[4];
    float mx = -1e30f;
    #pragma unroll
    for (int q = 0; q < 4; ++q) {
        int i = t + q * 256;
        if (i < 960) { v[q] = (xr[i] - mean) * rinv; mx = fmaxf(mx, v[q]); }
        else v[q] = -1e30f;
    }
    #pragma unroll
    for (int off = 32; off > 0; off >>= 1) mx = fmaxf(mx, __shfl_down(mx, off));
    __shared__ float rm[4];
    __shared__ float bmax, bsuminv;
    if ((t & 63) == 0) rm[t >> 6] = mx;
    __syncthreads();
    if (t == 0) bmax = fmaxf(fmaxf(rm[0], rm[1]), fmaxf(rm[2], rm[3]));
    __syncthreads();
    float mall = bmax;
    float s = 0.f;
    #pragma unroll
    for (int q = 0; q < 4; ++q) {
        int i = t + q * 256;
        if (i < 960) { v[q] = __expf(v[q] - mall); s += v[q]; }
    }
    #pragma unroll
    for (int off = 32; off > 0; off >>= 1) s += __shfl_down(s, off);
    if ((t & 63) == 0) rm[t >> 6] = s;
    __syncthreads();
    if (t == 0) bsuminv = 1.0f / (rm[0] + rm[1] + rm[2] + rm[3]);
    __syncthreads();
    float invS = bsuminv;
    #pragma unroll
    for (int q = 0; q < 4; ++q) {
        int i = t + q * 256;
        if (i < 960) orow[i] = f2bf(v[q] * invS);
    }
}

// ---------------------------------------------------------------------------
// Batched branch instnorm+softmax: rows [b][1024][960]; pad rows -> zeros.
// ---------------------------------------------------------------------------
__global__ __launch_bounds__(256)
void softmax_attn_kernel(const float* __restrict__ x, ushort_t* __restrict__ P,
                         const float2* __restrict__ stats)
{
    const int r = blockIdx.x & 1023, b = blockIdx.x >> 10;
    const int t = threadIdx.x;
    ushort_t* orow = P + ((long)(b << 10) + r) * 960;
    int br; float cnt;
    if (r < 64)       { br = 0; cnt = 64.f; }
    else if (r < 128) {
        #pragma unroll
        for (int q = 0; q < 4; ++q) {
            int i = t + q * 256;
            if (i < 960) orow[i] = 0;
        }
        return;
    }
    else if (r < 256) { br = 1; cnt = 128.f; }
    else if (r < 512) { br = 2; cnt = 256.f; }
    else              { br = 3; cnt = 512.f; }
    float invL = 1.0f / (cnt * 960.f);
    float2 st = stats[b * 4 + br];
    float mean = st.x * invL;
    float var = st.y * invL - mean * mean;
    float rinv = rsqrtf(var + 1e-5f);
    const float* xr = x + ((long)(b << 10) + r) * 960;
    float v[4];
    float mx = -1e30f;
    #pragma unroll
    for (int q = 0; q < 4; ++q) {
        int i = t + q * 256;
        if (i < 960) { v[q] = (xr[i] - mean) * rinv; mx = fmaxf(mx, v[q]); }
        else v[q] = -1e30f;
    }
    #pragma unroll
    for (int off = 32; off > 0; off >>= 1) mx = fmaxf(mx, __shfl_down(mx, off));
    __shared__ float rm[4];
    __shared__ float bmax, bsuminv;
    if ((t & 63) == 0) rm[t >> 6] = mx;
    __syncthreads();
    if (t == 0) bmax = fmaxf(fmaxf(rm[0], rm[1]), fmaxf(rm[2], rm[3]));
    __syncthreads();
    float mall = bmax;
    float s = 0.f;
    #pragma unroll
    for (int q = 0; q < 4; ++q) {
        int i = t + q * 256;
        if (i < 960) { v[q] = __expf(v[q] - mall); s += v[q]; }
    }
    #pragma unroll
    for (int off = 32; off > 0; off >>= 1) s += __shfl_down(s, off);
    if ((t & 63) == 0) rm[t >> 6] = s;
    __syncthreads();
    if (t == 0) bsuminv = 1.0f / (rm[0] + rm[1] + rm[2] + rm[3]);
    __syncthreads();
    float invS = bsuminv;
    #pragma unroll
    for (int q = 0; q < 4; ++q) {
        int i = t + q * 256;
        if (i < 960) orow[i] = f2bf(v[q] * invS);
    }
}

// ---------------------------------------------------------------------------

extern "C" void kernel_launch(void* const* d_in, const int* in_sizes, int n_in,
                              void* d_out, int out_size, void* d_ws, size_t ws_size,
                              hipStream_t stream)
{
    const float* emb[4]  = {(const float*)d_in[0], (const float*)d_in[1],
                            (const float*)d_in[2], (const float*)d_in[3]};
    const float* emb_all = (const float*)d_in[4];
    const float* w_mh[4] = {(const float*)d_in[5], (const float*)d_in[6],
                            (const float*)d_in[7], (const float*)d_in[8]};
    const float* w_mq = (const float*)d_in[9];
    const float* w_mk = (const float*)d_in[10];
    const float* w_mv = (const float*)d_in[11];
    const float* w_q[4] = {(const float*)d_in[12], (const float*)d_in[13],
                           (const float*)d_in[14], (const float*)d_in[15]};
    const float* w_qc = (const float*)d_in[16];
    const float* w_kc = (const float*)d_in[17];
    const float* w_vc = (const float*)d_in[18];
    const float* w_proj[4] = {(const float*)d_in[19], (const float*)d_in[20],
                              (const float*)d_in[21], (const float*)d_in[22]};
    float* out = (float*)d_out;

    // ---- arena (element offsets into ushort_t* U) ----
    ushort_t* U = (ushort_t*)d_ws;
    const long eWQKV = 0;          // 2,764,800  (WQ|WK|WV, k-contig rows)
    const long eWMH  = 2764800;    // 348,160
    const long eWPJ  = 3112960;    // 348,160
    const long eR1   = 3461120;    // embT_all -> Vc -> ctx       (7,864,320)
    const long eR2   = 11325440;   // embT_i  -> VcT -> ctxT      (7,864,320)
    const long eR3   = 19189760;   // Xqkv (23,592,960) -> S6 f32(15,728,640 us) + Pc -> oT
    const long ePc   = 34918400;   // Pc (7,372,800) ends 42,291,200
    const long eR4   = 42782720;   // mh_x -> P_all               (8,388,608)
    const long eQc   = 51171328;   // Qc (7,864,320)
    const long eKc   = 59035648;   // Kc (7,864,320)
    const long eQall = 66899968;   // q_all (8,388,608) ends 75,288,576
    float2* part  = (float2*)(U + 75288576);
    float2* stats = part + 512;

    ushort_t* WQKVb = U + eWQKV;
    ushort_t* WMHb  = U + eWMH;
    ushort_t* WPJb  = U + eWPJ;
    ushort_t* embT_all = U + eR1;
    ushort_t* Vc    = U + eR1;
    ushort_t* ctx   = U + eR1;
    ushort_t* VcT   = U + eR2;
    ushort_t* ctxT  = U + eR2;
    ushort_t* Xqkv  = U + eR3;
    float*    S6    = (float*)(U + eR3);
    ushort_t* oT    = U + eR3;
    ushort_t* Pc    = U + ePc;
    ushort_t* mh_x  = U + eR4;
    ushort_t* P_all = U + eR4;
    ushort_t* QcB   = U + eQc;
    ushort_t* KcB   = U + eKc;
    ushort_t* q_all = U + eQall;
    ushort_t* embT_i[4] = {U + eR2, U + eR2 + 524288, U + eR2 + 1572864, U + eR2 + 3670016};

    const float scale = 0.0322748612183951400f;   // 1/sqrt(960)
    const long SB = (long)KVC * HWN;              // 983040
    const long S1024 = 1024L * 1024;
    const int CH[4] = {64, 128, 256, 512};
    const int mhoff[4] = {0, 4096, 20480, 86016};
    const int rowOff[4] = {0, 128, 256, 512};
    const long outOff[4] = {0, 524288, 1572864, 3670016};
    dim3 blk(256);
    dim3 blk512(512);

    // ---- f2b weights (plain) ----
    {
        F2BTab tf;
        const float* fs[11] = {w_mq, w_mk, w_mv, w_mh[0], w_mh[1], w_mh[2], w_mh[3],
                               w_proj[0], w_proj[1], w_proj[2], w_proj[3]};
        long fd[11] = {eWQKV, eWQKV + 921600, eWQKV + 1843200,
                       eWMH + 0, eWMH + 4096, eWMH + 20480, eWMH + 86016,
                       eWPJ + 0, eWPJ + 4096, eWPJ + 20480, eWPJ + 86016};
        int fn[11] = {900, 900, 900, 4, 16, 64, 256, 4, 16, 64, 256};
        int ftot = 0;
        for (int i = 0; i < 11; ++i) { tf.src[i] = fs[i]; tf.dstOff[i] = fd[i]; tf.nblk[i] = fn[i]; ftot += fn[i]; }
        tf.nseg = 11;
        f2b_batched<<<ftot, blk, 0, stream>>>(tf, U);
    }
    // ---- f2bT embeddings (transpose-convert) ----
    {
        F2TTab tt;
        const float* ts[5] = {emb_all, emb[0], emb[1], emb[2], emb[3]};
        long td[5] = {eR1, eR2, eR2 + 524288, eR2 + 1572864, eR2 + 3670016};
        int tR[5] = {960, 64, 128, 256, 512};
        int tn[5];
        long tsi[5], tso[5];
        int ttot = 0;
        for (int i = 0; i < 5; ++i) {
            tsi[i] = (long)tR[i] * 1024; tso[i] = tsi[i];
            tn[i] = NB * (tR[i] / 64) * 16; ttot += tn[i];
            tt.src[i] = ts[i]; tt.dstOff[i] = td[i]; tt.R[i] = tR[i];
            tt.sIn[i] = tsi[i]; tt.sOut[i] = tso[i]; tt.nblk[i] = tn[i];
        }
        tt.nseg = 5;
        f2bt_batched<<<ttot, blk, 0, stream>>>(tt, U);
    }

    auto nt1 = [&](const ushort_t* A, long sA, const ushort_t* B, long sB, long ldb,
                   void* C, long sC, int M, int K, int obf) {
        NTTab tb;
        for (int s = 0; s < 5; ++s) {
            tb.A[s] = A; tb.B[s] = B; tb.C[s] = C;
            tb.sA[s] = sA; tb.sB[s] = sB; tb.sC[s] = sC; tb.ldb[s] = ldb;
            tb.M[s] = M; tb.K[s] = K; tb.obf[s] = obf; tb.mt0[s] = (s == 0) ? 0 : (1 << 30);
        }
        tb.nseg = 1;
        dim3 g(NB, 8, (M + 127) / 128);
        mfma_gemm_nt_tab<<<g, blk512, 0, stream>>>(tb);
    };

    // ---- stage 1: QKV (M=2880) + 4x mhead conv1x1, one NT launch ----
    {
        NTTab tb;
        tb.A[0] = WQKVb; tb.B[0] = embT_all; tb.C[0] = Xqkv;
        tb.sA[0] = 0; tb.sB[0] = SB; tb.sC[0] = 2880L * 1024; tb.ldb[0] = 960;
        tb.M[0] = 2880; tb.K[0] = 960; tb.obf[0] = 1; tb.mt0[0] = 0;
        int mt = 23;
        for (int i = 0; i < 4; ++i) {
            tb.A[1 + i] = WMHb + mhoff[i]; tb.B[1 + i] = embT_i[i];
            tb.C[1 + i] = mh_x + (long)rowOff[i] * 1024;
            tb.sA[1 + i] = 0; tb.sB[1 + i] = (long)CH[i] * 1024; tb.sC[1 + i] = S1024;
            tb.ldb[1 + i] = CH[i];
            tb.M[1 + i] = CH[i]; tb.K[1 + i] = CH[i]; tb.obf[1 + i] = 1; tb.mt0[1 + i] = mt;
            mt += (CH[i] + 127) / 128;
        }
        tb.nseg = 5;
        dim3 g(NB, 8, mt);   // (8, 8, 31): x = batch -> XCD, y = N-tile inner
        mfma_gemm_nt_tab<<<g, blk512, 0, stream>>>(tb);
    }

    // ---- stencils: dw(Q,K,V) + gconv, one launch ----
    stencil_all<<<31232, blk, 0, stream>>>(Xqkv, mh_x, w_qc, w_kc, w_vc,
                                           w_q[0], w_q[1], w_q[2], w_q[3],
                                           QcB, KcB, Vc, q_all);

    // ---- Vc -> VcT ----
    trb_kernel<<<dim3(16, 15, NB), blk, 0, stream>>>(Vc, VcT);

    // ---- sim = Qc @ Kc^T * scale + stats ----
    mfma_gemm_nt_stats<<<dim3(NB, 8, 8), blk512, 0, stream>>>(
        QcB, KcB, S6, part, KVC, KVC, HWN, SB, SB, (long)KVC * KVC, scale);
    reduce_sim<<<NB, 64, 0, stream>>>(part, stats);
    instnorm_softmax_bf16<<<NB * KVC, blk, 0, stream>>>(S6, Pc, stats, KVC,
                                                        1.f / ((float)KVC * (float)KVC));

    // ---- ctx = NT(Pc, VcT) -> [960][1024] bf16 ----
    nt1(Pc, (long)KVC * KVC, VcT, SB, 960, ctx, SB, KVC, KVC, 1);

    // ---- ctx -> ctxT ----
    trb_kernel<<<dim3(16, 15, NB), blk, 0, stream>>>(ctx, ctxT);

    // ---- attn = q_all @ ctx^T * scale + stats ----
    mfma_gemm_nt_stats<<<dim3(NB, 8, 8), blk512, 0, stream>>>(
        q_all, ctx, S6, part, 1024, KVC, HWN, S1024, SB, SB, scale);
    reduce_branch<<<32, 64, 0, stream>>>(part, stats);
    softmax_attn_kernel<<<NB * 1024, blk, 0, stream>>>(S6, P_all, stats);

    // ---- oT = NT(ctxT, P_all) -> [1024 hw][1024 ch] bf16 ----
    nt1(ctxT, SB, P_all, SB, 960, oT, S1024, 1024, KVC, 1);

    // ---- proj: 4 branches, one NT table launch (f32 out) ----
    {
        NTTab tb;
        int mt = 0;
        for (int i = 0; i < 4; ++i) {
            tb.A[i] = WPJb + mhoff[i]; tb.B[i] = oT + rowOff[i];
            tb.C[i] = out + outOff[i];
            tb.sA[i] = 0; tb.sB[i] = S1024; tb.sC[i] = (long)CH[i] * 1024;
            tb.ldb[i] = 1024;
            tb.M[i] = CH[i]; tb.K[i] = CH[i]; tb.obf[i] = 0; tb.mt0[i] = mt;
            mt += (CH[i] + 127) / 128;
        }
        tb.A[4] = tb.A[3]; tb.B[4] = tb.B[3]; tb.C[4] = tb.C[3];
        tb.sA[4] = 0; tb.sB[4] = 0; tb.sC[4] = 0; tb.ldb[4] = 1024;
        tb.M[4] = 1; tb.K[4] = 64; tb.obf[4] = 0; tb.mt0[4] = 1 << 30;
        tb.nseg = 4;
        dim3 g(NB, 8, mt);   // (8, 8, 8)
        mfma_gemm_nt_tab<<<g, blk512, 0, stream>>>(tb);
    }

    (void)in_sizes; (void)n_in; (void)out_size; (void)ws_size;
}